// Round 8
// baseline (2332.981 us; speedup 1.0000x reference)
//
#include <hip/hip_runtime.h>
#include <cstdint>

#define L_LAYERS 6

typedef __attribute__((ext_vector_type(8))) short bf16x8;
typedef __attribute__((ext_vector_type(4))) float f32x4;

__device__ __forceinline__ float gelu1(float v) {
    return 0.5f * v * (1.0f + erff(v * 0.7071067811865475f));
}

__device__ __forceinline__ unsigned int f2bf2(float a, float b) {
    union { float f; unsigned u; } x, y;
    x.f = a; y.f = b;
    unsigned lo = (x.u + 0x7FFFu + ((x.u >> 16) & 1u)) >> 16;
    unsigned hi = (y.u + 0x7FFFu + ((y.u >> 16) & 1u)) & 0xFFFF0000u;
    return lo | hi;
}

__device__ __forceinline__ unsigned short f2bf1(float a) {
    union { float f; unsigned u; } x;
    x.f = a;
    return (unsigned short)((x.u + 0x7FFFu + ((x.u >> 16) & 1u)) >> 16);
}

__device__ __forceinline__ float2 bfp2(unsigned u) {
    union { unsigned u; float f; } a, b;
    a.u = u << 16;
    b.u = u & 0xFFFF0000u;
    return make_float2(a.f, b.f);
}

// async global->LDS, 16 bytes per lane (dest = wave-uniform base + lane*16)
__device__ __forceinline__ void gload16(const void* g, void* l) {
    __builtin_amdgcn_global_load_lds(
        (const __attribute__((address_space(1))) void*)g,
        (__attribute__((address_space(3))) void*)l, 16, 0, 0);
}

// ---------------- utility ----------------

__global__ void k_zero(int* __restrict__ p, int n) {
    int i = blockIdx.x * 256 + threadIdx.x;
    if (i < n) p[i] = 0;
}

// ---------------- edge sorting (counting sort by dst) ----------------

__global__ void k_hist(const int* __restrict__ dst, int* __restrict__ hist, int E) {
    int e = blockIdx.x * 256 + threadIdx.x;
    if (e < E) atomicAdd(&hist[dst[e]], 1);
}

__global__ __launch_bounds__(1024) void k_scan(const int* __restrict__ hist,
                                               int* __restrict__ off, int n) {
    __shared__ int buf[1024];
    __shared__ int carry;
    int tid = threadIdx.x;
    if (tid == 0) carry = 0;
    __syncthreads();
    for (int base = 0; base < n; base += 1024) {
        int v = (base + tid < n) ? hist[base + tid] : 0;
        buf[tid] = v;
        __syncthreads();
        int x = v;
        for (int o = 1; o < 1024; o <<= 1) {
            int t = (tid >= o) ? buf[tid - o] : 0;
            __syncthreads();
            x += t;
            buf[tid] = x;
            __syncthreads();
        }
        int c = carry;
        if (base + tid < n) off[base + tid] = c + x - v;   // exclusive
        __syncthreads();
        if (tid == 1023) carry = c + buf[1023];
        __syncthreads();
    }
    if (tid == 0) off[n] = carry;
}

__global__ void k_scatter(const int* __restrict__ src, const int* __restrict__ dst,
                          const int* __restrict__ off, int* __restrict__ cursor,
                          int* __restrict__ srcS, int E) {
    int e = blockIdx.x * 256 + threadIdx.x;
    if (e < E) {
        int d = dst[e];
        int pos = off[d] + atomicAdd(&cursor[d], 1);
        srcS[pos] = src[e];
    }
}

// ---------------- weight prep (transpose + cvt to bf16) ----------------

__global__ void k_wcat(const float* __restrict__ Wq, const float* __restrict__ Wk,
                       const float* __restrict__ Wv, const float* __restrict__ Ws,
                       short* __restrict__ Wt) {
    int idx = blockIdx.x * 256 + threadIdx.x;   // l*2^20 + n*512 + k
    int k = idx & 511;
    int nf = (idx >> 9) & 2047;
    int l = idx >> 20;
    int sel = nf >> 9, nn = nf & 511;
    const float* W = (sel == 0) ? Wq : (sel == 1) ? Wk : (sel == 2) ? Wv : Ws;
    float v = W[((size_t)l * 512 + k) * 512 + nn];
    Wt[idx] = (short)f2bf1(v);
}

__global__ void k_tr(const float* __restrict__ W, short* __restrict__ Wt, int K, int N) {
    int k = blockIdx.x * 256 + threadIdx.x;
    int n = blockIdx.y;
    if (k < K) Wt[(size_t)n * K + k] = (short)f2bf1(W[(size_t)k * N + n]);
}

__global__ void k_bcat(const float* __restrict__ bq, const float* __restrict__ bk,
                       const float* __restrict__ bv, const float* __restrict__ bs,
                       float* __restrict__ bcat) {
    int idx = blockIdx.x * 256 + threadIdx.x;
    if (idx >= L_LAYERS * 2048) return;
    int l = idx >> 11, n = idx & 2047;
    int sel = n >> 9, nn = n & 511;
    const float* b = (sel == 0) ? bq : (sel == 1) ? bk : (sel == 2) ? bv : bs;
    bcat[idx] = b[l * 512 + nn];
}

__global__ void k_bdual(const float* __restrict__ sb, const float* __restrict__ ab,
                        float* __restrict__ bd) {
    int idx = blockIdx.x * 256 + threadIdx.x;
    if (idx < 1024) bd[idx] = (idx < 512) ? sb[idx] : ab[idx - 512];
}

// ---------------- GEMM: A fp32 (mixer only) ----------------

__global__ __launch_bounds__(256) void gemm_a32(
    const float* __restrict__ A, int lda,
    const short* __restrict__ Bt,
    const float* __restrict__ bias,
    float* __restrict__ Cf, short* __restrict__ Cbf, int ldc,
    int M, int N, int K, int act) {
    __shared__ __align__(16) short As[128][40];
    __shared__ __align__(16) short Bs[128][40];
    const int tid = threadIdx.x;
    const int lane = tid & 63;
    const int wave = tid >> 6;
    const int wr = (wave >> 1) * 64;
    const int wc = (wave & 1) * 64;
    const int l16 = lane & 15;
    const int quad = lane >> 4;
    const int row0 = blockIdx.x * 128;
    const int col0 = blockIdx.y * 128;
    const int sr = tid >> 2;
    const int sk = (tid & 3) * 8;

    f32x4 acc[4][4];
#pragma unroll
    for (int i = 0; i < 4; ++i)
#pragma unroll
        for (int j = 0; j < 4; ++j)
            acc[i][j] = f32x4{0.f, 0.f, 0.f, 0.f};

    for (int kb = 0; kb < K; kb += 32) {
#pragma unroll
        for (int hh = 0; hh < 2; ++hh) {
            int r = sr + hh * 64;
            int gr = row0 + r;
            float4 a0, a1;
            if (gr < M) {
                const float* p = A + (size_t)gr * lda + kb + sk;
                a0 = *(const float4*)p;
                a1 = *(const float4*)(p + 4);
            } else {
                a0 = make_float4(0.f, 0.f, 0.f, 0.f);
                a1 = make_float4(0.f, 0.f, 0.f, 0.f);
            }
            uint4 av;
            av.x = f2bf2(a0.x, a0.y);
            av.y = f2bf2(a0.z, a0.w);
            av.z = f2bf2(a1.x, a1.y);
            av.w = f2bf2(a1.z, a1.w);
            *(uint4*)&As[r][sk] = av;
            const short* bp = Bt + (size_t)(col0 + r) * K + kb + sk;
            *(uint4*)&Bs[r][sk] = *(const uint4*)bp;
        }
        __syncthreads();
        bf16x8 af[4], bfr[4];
#pragma unroll
        for (int i = 0; i < 4; ++i)
            af[i] = *(const bf16x8*)&As[wr + i * 16 + l16][quad * 8];
#pragma unroll
        for (int j = 0; j < 4; ++j)
            bfr[j] = *(const bf16x8*)&Bs[wc + j * 16 + l16][quad * 8];
#pragma unroll
        for (int i = 0; i < 4; ++i)
#pragma unroll
            for (int j = 0; j < 4; ++j)
                acc[i][j] = __builtin_amdgcn_mfma_f32_16x16x32_bf16(af[i], bfr[j], acc[i][j], 0, 0, 0);
        __syncthreads();
    }
#pragma unroll
    for (int i = 0; i < 4; ++i) {
        int rbase = row0 + wr + i * 16 + quad * 4;
#pragma unroll
        for (int j = 0; j < 4; ++j) {
            int c = col0 + wc + j * 16 + l16;
            float bv = bias ? bias[c] : 0.0f;
#pragma unroll
            for (int rg = 0; rg < 4; ++rg) {
                int gr = rbase + rg;
                if (gr < M) {
                    float v = acc[i][j][rg] + bv;
                    if (act) v = gelu1(v);
                    Cf[(size_t)gr * ldc + c] = v;
                    if (Cbf) Cbf[(size_t)gr * ldc + c] = (short)f2bf1(v);
                }
            }
        }
    }
}

// ---------------- GEMM: A bf16, B bf16, m97-style global_load_lds staging ----------------

__global__ __launch_bounds__(256) void gemm_bb(
    const short* __restrict__ A, int lda,
    const short* __restrict__ Bt,
    const float* __restrict__ bias,
    short* __restrict__ C, int ldc,
    int M, int N, int K, int act) {
    __shared__ __align__(16) short As[128 * 32];
    __shared__ __align__(16) short Bs[128 * 32];
    const int tid = threadIdx.x;
    const int lane = tid & 63;
    const int wave = tid >> 6;
    const int wr = (wave >> 1) * 64;
    const int wc = (wave & 1) * 64;
    const int l16 = lane & 15;
    const int quad = lane >> 4;
    const int row0 = blockIdx.x * 128;
    const int col0 = blockIdx.y * 128;
    const int c0 = tid, c1 = tid + 256;
    const int r0 = c0 >> 2, kq0 = (c0 & 3) * 8;
    const int r1 = c1 >> 2, kq1 = (c1 & 3) * 8;
    int ga0 = row0 + r0; if (ga0 >= M) ga0 = M - 1;
    int ga1 = row0 + r1; if (ga1 >= M) ga1 = M - 1;
    const short* Ap0 = A + (size_t)ga0 * lda + kq0;
    const short* Ap1 = A + (size_t)ga1 * lda + kq1;
    const short* Bp0 = Bt + (size_t)(col0 + r0) * K + kq0;
    const short* Bp1 = Bt + (size_t)(col0 + r1) * K + kq1;

    f32x4 acc[4][4];
#pragma unroll
    for (int i = 0; i < 4; ++i)
#pragma unroll
        for (int j = 0; j < 4; ++j)
            acc[i][j] = f32x4{0.f, 0.f, 0.f, 0.f};

    for (int kb = 0; kb < K; kb += 32) {
        gload16(Ap0 + kb, &As[c0 * 8]);
        gload16(Ap1 + kb, &As[c1 * 8]);
        gload16(Bp0 + kb, &Bs[c0 * 8]);
        gload16(Bp1 + kb, &Bs[c1 * 8]);
        __syncthreads();
        bf16x8 af[4], bfr[4];
#pragma unroll
        for (int i = 0; i < 4; ++i)
            af[i] = *(const bf16x8*)&As[(wr + i * 16 + l16) * 32 + quad * 8];
#pragma unroll
        for (int j = 0; j < 4; ++j)
            bfr[j] = *(const bf16x8*)&Bs[(wc + j * 16 + l16) * 32 + quad * 8];
#pragma unroll
        for (int i = 0; i < 4; ++i)
#pragma unroll
            for (int j = 0; j < 4; ++j)
                acc[i][j] = __builtin_amdgcn_mfma_f32_16x16x32_bf16(af[i], bfr[j], acc[i][j], 0, 0, 0);
        __syncthreads();
    }
#pragma unroll
    for (int i = 0; i < 4; ++i) {
        int rbase = row0 + wr + i * 16 + quad * 4;
#pragma unroll
        for (int j = 0; j < 4; ++j) {
            int c = col0 + wc + j * 16 + l16;
            float bv = bias ? bias[c] : 0.0f;
#pragma unroll
            for (int rg = 0; rg < 4; ++rg) {
                int gr = rbase + rg;
                if (gr < M) {
                    float v = acc[i][j][rg] + bv;
                    if (act) v = gelu1(v);
                    C[(size_t)gr * ldc + c] = (short)f2bf1(v);
                }
            }
        }
    }
}

// ---------------- fully-fused gate: pair features -> gW1 -> gelu -> .gW2 -> sigmoid
//                  + bilinear scores (t_i . z_j) -> final combine -> out ----------------
// 512 threads, 64 pairs/block, ALL 512 hidden cols (grid.y=1: z gathered once per pair).
// Waves 0..7 each own 64 cols. Pairscore fused into the A-build (z_j already in regs).

__global__ __launch_bounds__(512, 2) void gemm_gate(
    const short* __restrict__ z,
    const short* __restrict__ t,
    const int* __restrict__ pi, const int* __restrict__ pj, int P,
    const short* __restrict__ Bt,    // gW1^T [512][2048]
    const float* __restrict__ gb1,
    const float* __restrict__ gW2,
    const float* __restrict__ gb2,
    float* __restrict__ out) {
    __shared__ __align__(16) short Aab[64 * 32];
    __shared__ __align__(16) short Amu[64 * 32];
    __shared__ __align__(16) short Bab[512 * 32];
    __shared__ __align__(16) short Bmu[512 * 32];
    __shared__ int iArr[64];
    __shared__ int jArr[64];
    __shared__ float rowsum[64];
    __shared__ float dsynS[64];
    __shared__ float dantS[64];
    const int tid = threadIdx.x;
    const int lane = tid & 63;
    const int wave = tid >> 6;      // 0..7
    const int wc = wave * 64;       // col group
    const int l16 = lane & 15;
    const int quad = lane >> 4;
    const int row0 = blockIdx.x * 64;
    const int sr = (tid < 256) ? (tid >> 2) : 0;   // A row (threads 0..255)
    const int sk = (tid & 3) * 8;
    // B staging ids (all 512 threads): row = (tid>>2) + hh*128, k-offset sk
    const int br = tid >> 2;        // 0..127

    if (tid < 64) {
        int p = row0 + tid;
        int ok = (p < P);
        iArr[tid] = ok ? pi[p] : 0;
        jArr[tid] = ok ? pj[p] : 0;
        rowsum[tid] = 0.0f;
    }
    __syncthreads();
    const short* zi = z + (size_t)iArr[sr] * 1024 + sk;
    const short* zj = z + (size_t)jArr[sr] * 1024 + sk;
    const short* ti = t + (size_t)iArr[sr] * 1024 + sk;
    const short* bp0 = Bt + (size_t)br * 2048 + sk;

    f32x4 acc[4][4];
#pragma unroll
    for (int i = 0; i < 4; ++i)
#pragma unroll
        for (int j = 0; j < 4; ++j)
            acc[i][j] = f32x4{0.f, 0.f, 0.f, 0.f};
    float dsyn = 0.f, dant = 0.f;

    for (int part = 0; part < 2; ++part) {
        float dloc = 0.f;
        for (int c = 0; c < 512; c += 32) {
            // B async staging (all threads; DMA overlaps the A-build VALU below)
            const short* bp = bp0 + part * 1024 + c;
#pragma unroll
            for (int hh = 0; hh < 4; ++hh) {
                const short* q = bp + (size_t)hh * 128 * 2048;
                gload16(q, &Bab[(br + hh * 128) * 32 + sk]);
                gload16(q + 512, &Bmu[(br + hh * 128) * 32 + sk]);
            }
            if (tid < 256) {
                uint4 xu = *(const uint4*)(zi + part * 512 + c);
                uint4 yu = *(const uint4*)(zj + part * 512 + c);
                uint4 tu = *(const uint4*)(ti + part * 512 + c);
                float2 x0 = bfp2(xu.x), x1 = bfp2(xu.y), x2 = bfp2(xu.z), x3 = bfp2(xu.w);
                float2 y0 = bfp2(yu.x), y1 = bfp2(yu.y), y2 = bfp2(yu.z), y3 = bfp2(yu.w);
                float2 t0 = bfp2(tu.x), t1 = bfp2(tu.y), t2 = bfp2(tu.z), t3 = bfp2(tu.w);
                uint4 aa, am;
                aa.x = f2bf2(fabsf(x0.x - y0.x), fabsf(x0.y - y0.y));
                aa.y = f2bf2(fabsf(x1.x - y1.x), fabsf(x1.y - y1.y));
                aa.z = f2bf2(fabsf(x2.x - y2.x), fabsf(x2.y - y2.y));
                aa.w = f2bf2(fabsf(x3.x - y3.x), fabsf(x3.y - y3.y));
                am.x = f2bf2(x0.x * y0.x, x0.y * y0.y);
                am.y = f2bf2(x1.x * y1.x, x1.y * y1.y);
                am.z = f2bf2(x2.x * y2.x, x2.y * y2.y);
                am.w = f2bf2(x3.x * y3.x, x3.y * y3.y);
                *(uint4*)&Aab[tid * 8] = aa;
                *(uint4*)&Amu[tid * 8] = am;
                // fused bilinear partial: t_i . z_j over these 8 channels
                dloc += t0.x * y0.x + t0.y * y0.y + t1.x * y1.x + t1.y * y1.y +
                        t2.x * y2.x + t2.y * y2.y + t3.x * y3.x + t3.y * y3.y;
            }
            __syncthreads();
            bf16x8 af[4];
#pragma unroll
            for (int i = 0; i < 4; ++i)
                af[i] = *(const bf16x8*)&Aab[(i * 16 + l16) * 32 + quad * 8];
#pragma unroll
            for (int j = 0; j < 4; ++j) {
                bf16x8 bf = *(const bf16x8*)&Bab[(wc + j * 16 + l16) * 32 + quad * 8];
#pragma unroll
                for (int i = 0; i < 4; ++i)
                    acc[i][j] = __builtin_amdgcn_mfma_f32_16x16x32_bf16(af[i], bf, acc[i][j], 0, 0, 0);
            }
#pragma unroll
            for (int i = 0; i < 4; ++i)
                af[i] = *(const bf16x8*)&Amu[(i * 16 + l16) * 32 + quad * 8];
#pragma unroll
            for (int j = 0; j < 4; ++j) {
                bf16x8 bf = *(const bf16x8*)&Bmu[(wc + j * 16 + l16) * 32 + quad * 8];
#pragma unroll
                for (int i = 0; i < 4; ++i)
                    acc[i][j] = __builtin_amdgcn_mfma_f32_16x16x32_bf16(af[i], bf, acc[i][j], 0, 0, 0);
            }
            __syncthreads();
        }
        if (part == 0) dsyn = dloc; else dant = dloc;
    }
    // bilinear score reduction: 4 consecutive lanes per row
    if (tid < 256) {
        dsyn += __shfl_xor(dsyn, 1);
        dsyn += __shfl_xor(dsyn, 2);
        dant += __shfl_xor(dant, 1);
        dant += __shfl_xor(dant, 2);
        if ((tid & 3) == 0) { dsynS[sr] = dsyn; dantS[sr] = dant; }
    }
    // hidden.gW2 rowwise reduction over this wave's 64 cols
#pragma unroll
    for (int i = 0; i < 4; ++i) {
#pragma unroll
        for (int rg = 0; rg < 4; ++rg) {
            float partial = 0.f;
#pragma unroll
            for (int j = 0; j < 4; ++j) {
                int cc = wc + j * 16 + l16;
                partial += gelu1(acc[i][j][rg] + gb1[cc]) * gW2[cc];
            }
            partial += __shfl_xor(partial, 1);
            partial += __shfl_xor(partial, 2);
            partial += __shfl_xor(partial, 4);
            partial += __shfl_xor(partial, 8);
            if (l16 == 0)
                atomicAdd(&rowsum[i * 16 + quad * 4 + rg], partial);
        }
    }
    __syncthreads();
    if (tid < 64) {
        int p = row0 + tid;
        if (p < P) {
            float s = 1.0f / (1.0f + __expf(-(rowsum[tid] + gb2[0])));
            out[p] = s * dantS[tid] - (1.0f - s) * dsynS[tid];
        }
    }
}

// ---------------- fused per-layer attention: wave-per-node, barrier-free ----------------

__global__ __launch_bounds__(256) void k_attn(const short* __restrict__ qkvs,
                                              const int* __restrict__ srcS,
                                              const int* __restrict__ offs,
                                              float* __restrict__ h,
                                              short* __restrict__ h_bf,
                                              const float* __restrict__ lng,
                                              const float* __restrict__ lnb, int Nn) {
    __shared__ float Llog[4][64][4];
    const int tid = threadIdx.x;
    const int lane = tid & 63;
    const int wv = tid >> 6;
    const int n = blockIdx.x * 4 + wv;
    if (n >= Nn) return;
    const int g = lane >> 4;
    const int li = lane & 15;
    const int st = offs[n], en = offs[n + 1];

    float q[4][8];
#pragma unroll
    for (int hh = 0; hh < 4; ++hh) {
        uint4 qv = *(const uint4*)(qkvs + (size_t)n * 2048 + hh * 128 + li * 8);
        float2 t0 = bfp2(qv.x), t1 = bfp2(qv.y), t2 = bfp2(qv.z), t3 = bfp2(qv.w);
        q[hh][0] = t0.x; q[hh][1] = t0.y; q[hh][2] = t1.x; q[hh][3] = t1.y;
        q[hh][4] = t2.x; q[hh][5] = t2.y; q[hh][6] = t3.x; q[hh][7] = t3.y;
    }
    float acc[8];
#pragma unroll
    for (int i = 0; i < 8; ++i) acc[i] = 0.f;
    float m_l = -3.4e38f, l_l = 0.f;

    for (int e0 = st; e0 < en; e0 += 64) {
        int cnt = min(64, en - e0);
        int myS = (lane < cnt) ? srcS[e0 + lane] : 0;
        for (int ei = g; ei < cnt; ei += 4) {
            int s = __shfl(myS, ei);
            const short* kp = qkvs + (size_t)s * 2048 + 512 + li * 8;
            float lg[4];
#pragma unroll
            for (int hh = 0; hh < 4; ++hh) {
                uint4 kv = *(const uint4*)(kp + hh * 128);
                float2 k0 = bfp2(kv.x), k1 = bfp2(kv.y), k2 = bfp2(kv.z), k3 = bfp2(kv.w);
                float d = q[hh][0] * k0.x + q[hh][1] * k0.y + q[hh][2] * k1.x + q[hh][3] * k1.y +
                          q[hh][4] * k2.x + q[hh][5] * k2.y + q[hh][6] * k3.x + q[hh][7] * k3.y;
                d += __shfl_xor(d, 1);
                d += __shfl_xor(d, 2);
                d += __shfl_xor(d, 4);
                d += __shfl_xor(d, 8);
                lg[hh] = d * 0.08838834764831845f;
            }
            if (li == 0)
                *(float4*)&Llog[wv][ei][0] = make_float4(lg[0], lg[1], lg[2], lg[3]);
        }
        float mc = -3.4e38f;
        for (int i = li; i < cnt; i += 16) mc = fmaxf(mc, Llog[wv][i][g]);
        mc = fmaxf(mc, __shfl_xor(mc, 1));
        mc = fmaxf(mc, __shfl_xor(mc, 2));
        mc = fmaxf(mc, __shfl_xor(mc, 4));
        mc = fmaxf(mc, __shfl_xor(mc, 8));
        float m_new = fmaxf(m_l, mc);
        float sum = 0.f;
        for (int i = li; i < cnt; i += 16) {
            float p = __expf(Llog[wv][i][g] - m_new);
            Llog[wv][i][g] = p;
            sum += p;
        }
        sum += __shfl_xor(sum, 1);
        sum += __shfl_xor(sum, 2);
        sum += __shfl_xor(sum, 4);
        sum += __shfl_xor(sum, 8);
        float sc = __expf(m_l - m_new);
        l_l = l_l * sc + sum;
        m_l = m_new;
#pragma unroll
        for (int i = 0; i < 8; ++i) acc[i] *= sc;
        for (int ei = 0; ei < cnt; ++ei) {
            float a = Llog[wv][ei][g];
            int s = __shfl(myS, ei);
            uint4 vv = *(const uint4*)(qkvs + (size_t)s * 2048 + 1024 + lane * 8);
            float2 v0 = bfp2(vv.x), v1 = bfp2(vv.y), v2 = bfp2(vv.z), v3 = bfp2(vv.w);
            acc[0] += a * v0.x; acc[1] += a * v0.y; acc[2] += a * v1.x; acc[3] += a * v1.y;
            acc[4] += a * v2.x; acc[5] += a * v2.y; acc[6] += a * v3.x; acc[7] += a * v3.y;
        }
    }
    float rinv = (en > st) ? 1.0f / l_l : 0.f;
    uint4 su = *(const uint4*)(qkvs + (size_t)n * 2048 + 1536 + lane * 8);
    float2 s0 = bfp2(su.x), s1 = bfp2(su.y), s2 = bfp2(su.z), s3 = bfp2(su.w);
    float sv[8] = {s0.x, s0.y, s1.x, s1.y, s2.x, s2.y, s3.x, s3.y};
    const float* hp = h + (size_t)n * 512 + lane * 8;
    float4 h0 = *(const float4*)hp;
    float4 h1 = *(const float4*)(hp + 4);
    float hv[8] = {h0.x, h0.y, h0.z, h0.w, h1.x, h1.y, h1.z, h1.w};
    float r[8];
    float sum = 0.f, ssq = 0.f;
#pragma unroll
    for (int i = 0; i < 8; ++i) {
        r[i] = hv[i] + gelu1(acc[i] * rinv + sv[i]);
        sum += r[i];
        ssq += r[i] * r[i];
    }
    for (int o = 32; o; o >>= 1) {
        sum += __shfl_xor(sum, o);
        ssq += __shfl_xor(ssq, o);
    }
    float mean = sum * (1.0f / 512.0f);
    float var = ssq * (1.0f / 512.0f) - mean * mean;
    float inv = rsqrtf(var + 1e-5f);
    const float* gp = lng + lane * 8;
    const float* bp = lnb + lane * 8;
    float4 g0 = *(const float4*)gp, g1 = *(const float4*)(gp + 4);
    float4 b0 = *(const float4*)bp, b1 = *(const float4*)(bp + 4);
    float ga[8] = {g0.x, g0.y, g0.z, g0.w, g1.x, g1.y, g1.z, g1.w};
    float ba[8] = {b0.x, b0.y, b0.z, b0.w, b1.x, b1.y, b1.z, b1.w};
    float o8[8];
#pragma unroll
    for (int i = 0; i < 8; ++i) o8[i] = (r[i] - mean) * inv * ga[i] + ba[i];
    float* hw = h + (size_t)n * 512 + lane * 8;
    *(float4*)hw = make_float4(o8[0], o8[1], o8[2], o8[3]);
    *(float4*)(hw + 4) = make_float4(o8[4], o8[5], o8[6], o8[7]);
    uint4 ob;
    ob.x = f2bf2(o8[0], o8[1]);
    ob.y = f2bf2(o8[2], o8[3]);
    ob.z = f2bf2(o8[4], o8[5]);
    ob.w = f2bf2(o8[6], o8[7]);
    *(uint4*)(h_bf + (size_t)n * 512 + lane * 8) = ob;
}

// ---------------- host ----------------

extern "C" void kernel_launch(void* const* d_in, const int* in_sizes, int n_in,
                              void* d_out, int out_size, void* d_ws, size_t ws_size,
                              hipStream_t stream) {
    const float* x = (const float*)d_in[0];
    const int* ei = (const int*)d_in[1];
    const int* pe = (const int*)d_in[2];
    const float* mixer_W = (const float*)d_in[3];
    const float* mixer_b = (const float*)d_in[4];
    const float* Wq = (const float*)d_in[5];
    const float* bq = (const float*)d_in[6];
    const float* Wk = (const float*)d_in[7];
    const float* bk = (const float*)d_in[8];
    const float* Wv = (const float*)d_in[9];
    const float* bv = (const float*)d_in[10];
    const float* Ws = (const float*)d_in[11];
    const float* bs = (const float*)d_in[12];
    const float* ln_g = (const float*)d_in[13];
    const float* ln_b = (const float*)d_in[14];
    const float* syn_W = (const float*)d_in[15];
    const float* syn_b = (const float*)d_in[16];
    const float* ant_W = (const float*)d_in[17];
    const float* ant_b = (const float*)d_in[18];
    const float* W_syn = (const float*)d_in[19];
    const float* W_ant = (const float*)d_in[20];
    const float* gW1 = (const float*)d_in[21];
    const float* gb1 = (const float*)d_in[22];
    const float* gW2 = (const float*)d_in[23];
    const float* gb2 = (const float*)d_in[24];
    float* out = (float*)d_out;

    const int Nn = in_sizes[0] / 768;  // 20000
    const int E = in_sizes[1] / 2;     // 320000
    const int P = in_sizes[2] / 2;     // 100000

    char* w = (char*)d_ws;
    auto alloc = [&](size_t bytes) -> char* {
        char* p = w;
        w += (bytes + 255) & ~(size_t)255;
        return p;
    };
    float* h = (float*)alloc((size_t)Nn * 512 * 4);
    short* h_bf = (short*)alloc((size_t)Nn * 512 * 2);
    short* qkvs = (short*)alloc((size_t)Nn * 2048 * 2);
    short* zB = qkvs;
    short* tB = qkvs + (size_t)Nn * 1024;
    int* srcS = (int*)alloc((size_t)E * 4);
    int* hist = (int*)alloc((size_t)Nn * 2 * 4);
    int* cursor = hist + Nn;
    int* offs = (int*)alloc((size_t)(Nn + 1) * 4);
    short* mixWt = (short*)alloc((size_t)512 * 768 * 2);
    short* wcat = (short*)alloc((size_t)L_LAYERS * 2048 * 512 * 2);
    short* dualWt = (short*)alloc((size_t)1024 * 512 * 2);
    short* bilWt = (short*)alloc((size_t)1024 * 512 * 2);
    short* gw1t = (short*)alloc((size_t)512 * 2048 * 2);
    float* bcat = (float*)alloc((size_t)L_LAYERS * 2048 * 4);
    float* bdual = (float*)alloc((size_t)1024 * 4);

    k_zero<<<(2 * Nn + 255) / 256, 256, 0, stream>>>(hist, 2 * Nn);
    k_hist<<<(E + 255) / 256, 256, 0, stream>>>(ei + E, hist, E);
    k_scan<<<1, 1024, 0, stream>>>(hist, offs, Nn);
    k_scatter<<<(E + 255) / 256, 256, 0, stream>>>(ei, ei + E, offs, cursor, srcS, E);

    k_wcat<<<(L_LAYERS * 2048 * 512) / 256, 256, 0, stream>>>(Wq, Wk, Wv, Ws, wcat);
    k_tr<<<dim3(3, 512), 256, 0, stream>>>(mixer_W, mixWt, 768, 512);
    k_tr<<<dim3(2, 512), 256, 0, stream>>>(syn_W, dualWt, 512, 512);
    k_tr<<<dim3(2, 512), 256, 0, stream>>>(ant_W, dualWt + 512 * 512, 512, 512);
    k_tr<<<dim3(2, 512), 256, 0, stream>>>(W_syn, bilWt, 512, 512);
    k_tr<<<dim3(2, 512), 256, 0, stream>>>(W_ant, bilWt + 512 * 512, 512, 512);
    k_tr<<<dim3(8, 512), 256, 0, stream>>>(gW1, gw1t, 2048, 512);
    k_bcat<<<48, 256, 0, stream>>>(bq, bk, bv, bs, bcat);
    k_bdual<<<4, 256, 0, stream>>>(syn_b, ant_b, bdual);

    const int mtiles = (Nn + 127) / 128;  // 157
    gemm_a32<<<dim3(mtiles, 4), 256, 0, stream>>>(x, 768, mixWt, mixer_b, h, h_bf, 512,
                                                  Nn, 512, 768, 1);

    for (int l = 0; l < L_LAYERS; ++l) {
        gemm_bb<<<dim3(mtiles, 16), 256, 0, stream>>>(h_bf, 512, wcat + (size_t)l * 2048 * 512,
                                                      bcat + l * 2048, qkvs, 2048,
                                                      Nn, 2048, 512, 0);
        k_attn<<<(Nn + 3) / 4, 256, 0, stream>>>(qkvs, srcS, offs, h, h_bf,
                                                 ln_g + l * 512, ln_b + l * 512, Nn);
    }

    gemm_bb<<<dim3(mtiles, 8), 256, 0, stream>>>(h_bf, 512, dualWt, bdual, zB, 1024,
                                                 Nn, 1024, 512, 1);
    gemm_bb<<<dim3(mtiles, 4), 256, 0, stream>>>(zB, 1024, bilWt, nullptr, tB, 1024,
                                                 Nn, 512, 512, 0);
    gemm_bb<<<dim3(mtiles, 4), 256, 0, stream>>>(zB + 512, 1024, bilWt + 512 * 512, nullptr,
                                                 tB + 512, 1024, Nn, 512, 512, 0);

    // fully-fused gate MLP + bilinear scores + final combine
    gemm_gate<<<(P + 63) / 64, 512, 0, stream>>>(zB, tB, pe, pe + P, P,
                                                 gw1t, gb1, gW2, gb2, out);
}

// Round 9
// 2100.252 us; speedup vs baseline: 1.1108x; 1.1108x over previous
//
#include <hip/hip_runtime.h>
#include <cstdint>

#define L_LAYERS 6

typedef __attribute__((ext_vector_type(8))) short bf16x8;
typedef __attribute__((ext_vector_type(4))) float f32x4;

__device__ __forceinline__ float gelu1(float v) {
    return 0.5f * v * (1.0f + erff(v * 0.7071067811865475f));
}

__device__ __forceinline__ unsigned int f2bf2(float a, float b) {
    union { float f; unsigned u; } x, y;
    x.f = a; y.f = b;
    unsigned lo = (x.u + 0x7FFFu + ((x.u >> 16) & 1u)) >> 16;
    unsigned hi = (y.u + 0x7FFFu + ((y.u >> 16) & 1u)) & 0xFFFF0000u;
    return lo | hi;
}

__device__ __forceinline__ unsigned short f2bf1(float a) {
    union { float f; unsigned u; } x;
    x.f = a;
    return (unsigned short)((x.u + 0x7FFFu + ((x.u >> 16) & 1u)) >> 16);
}

__device__ __forceinline__ float2 bfp2(unsigned u) {
    union { unsigned u; float f; } a, b;
    a.u = u << 16;
    b.u = u & 0xFFFF0000u;
    return make_float2(a.f, b.f);
}

// async global->LDS, 16 bytes per lane (dest = wave-uniform base + lane*16)
__device__ __forceinline__ void gload16(const void* g, void* l) {
    __builtin_amdgcn_global_load_lds(
        (const __attribute__((address_space(1))) void*)g,
        (__attribute__((address_space(3))) void*)l, 16, 0, 0);
}

// ---------------- utility ----------------

__global__ void k_zero(int* __restrict__ p, int n) {
    int i = blockIdx.x * 256 + threadIdx.x;
    if (i < n) p[i] = 0;
}

// ---------------- edge sorting (counting sort by dst) ----------------

__global__ void k_hist(const int* __restrict__ dst, int* __restrict__ hist, int E) {
    int e = blockIdx.x * 256 + threadIdx.x;
    if (e < E) atomicAdd(&hist[dst[e]], 1);
}

__global__ __launch_bounds__(1024) void k_scan(const int* __restrict__ hist,
                                               int* __restrict__ off, int n) {
    __shared__ int buf[1024];
    __shared__ int carry;
    int tid = threadIdx.x;
    if (tid == 0) carry = 0;
    __syncthreads();
    for (int base = 0; base < n; base += 1024) {
        int v = (base + tid < n) ? hist[base + tid] : 0;
        buf[tid] = v;
        __syncthreads();
        int x = v;
        for (int o = 1; o < 1024; o <<= 1) {
            int t = (tid >= o) ? buf[tid - o] : 0;
            __syncthreads();
            x += t;
            buf[tid] = x;
            __syncthreads();
        }
        int c = carry;
        if (base + tid < n) off[base + tid] = c + x - v;   // exclusive
        __syncthreads();
        if (tid == 1023) carry = c + buf[1023];
        __syncthreads();
    }
    if (tid == 0) off[n] = carry;
}

__global__ void k_scatter(const int* __restrict__ src, const int* __restrict__ dst,
                          const int* __restrict__ off, int* __restrict__ cursor,
                          int* __restrict__ srcS, int E) {
    int e = blockIdx.x * 256 + threadIdx.x;
    if (e < E) {
        int d = dst[e];
        int pos = off[d] + atomicAdd(&cursor[d], 1);
        srcS[pos] = src[e];
    }
}

// ---------------- weight prep (transpose + cvt to bf16) ----------------

__global__ void k_wcat(const float* __restrict__ Wq, const float* __restrict__ Wk,
                       const float* __restrict__ Wv, const float* __restrict__ Ws,
                       short* __restrict__ Wt) {
    int idx = blockIdx.x * 256 + threadIdx.x;   // l*2^20 + n*512 + k
    int k = idx & 511;
    int nf = (idx >> 9) & 2047;
    int l = idx >> 20;
    int sel = nf >> 9, nn = nf & 511;
    const float* W = (sel == 0) ? Wq : (sel == 1) ? Wk : (sel == 2) ? Wv : Ws;
    float v = W[((size_t)l * 512 + k) * 512 + nn];
    Wt[idx] = (short)f2bf1(v);
}

__global__ void k_tr(const float* __restrict__ W, short* __restrict__ Wt, int K, int N) {
    int k = blockIdx.x * 256 + threadIdx.x;
    int n = blockIdx.y;
    if (k < K) Wt[(size_t)n * K + k] = (short)f2bf1(W[(size_t)k * N + n]);
}

__global__ void k_bcat(const float* __restrict__ bq, const float* __restrict__ bk,
                       const float* __restrict__ bv, const float* __restrict__ bs,
                       float* __restrict__ bcat) {
    int idx = blockIdx.x * 256 + threadIdx.x;
    if (idx >= L_LAYERS * 2048) return;
    int l = idx >> 11, n = idx & 2047;
    int sel = n >> 9, nn = n & 511;
    const float* b = (sel == 0) ? bq : (sel == 1) ? bk : (sel == 2) ? bv : bs;
    bcat[idx] = b[l * 512 + nn];
}

__global__ void k_bdual(const float* __restrict__ sb, const float* __restrict__ ab,
                        float* __restrict__ bd) {
    int idx = blockIdx.x * 256 + threadIdx.x;
    if (idx < 1024) bd[idx] = (idx < 512) ? sb[idx] : ab[idx - 512];
}

// ---------------- GEMM: A fp32 (mixer only) ----------------

__global__ __launch_bounds__(256) void gemm_a32(
    const float* __restrict__ A, int lda,
    const short* __restrict__ Bt,
    const float* __restrict__ bias,
    float* __restrict__ Cf, short* __restrict__ Cbf, int ldc,
    int M, int N, int K, int act) {
    __shared__ __align__(16) short As[128][40];
    __shared__ __align__(16) short Bs[128][40];
    const int tid = threadIdx.x;
    const int lane = tid & 63;
    const int wave = tid >> 6;
    const int wr = (wave >> 1) * 64;
    const int wc = (wave & 1) * 64;
    const int l16 = lane & 15;
    const int quad = lane >> 4;
    const int row0 = blockIdx.x * 128;
    const int col0 = blockIdx.y * 128;
    const int sr = tid >> 2;
    const int sk = (tid & 3) * 8;

    f32x4 acc[4][4];
#pragma unroll
    for (int i = 0; i < 4; ++i)
#pragma unroll
        for (int j = 0; j < 4; ++j)
            acc[i][j] = f32x4{0.f, 0.f, 0.f, 0.f};

    for (int kb = 0; kb < K; kb += 32) {
#pragma unroll
        for (int hh = 0; hh < 2; ++hh) {
            int r = sr + hh * 64;
            int gr = row0 + r;
            float4 a0, a1;
            if (gr < M) {
                const float* p = A + (size_t)gr * lda + kb + sk;
                a0 = *(const float4*)p;
                a1 = *(const float4*)(p + 4);
            } else {
                a0 = make_float4(0.f, 0.f, 0.f, 0.f);
                a1 = make_float4(0.f, 0.f, 0.f, 0.f);
            }
            uint4 av;
            av.x = f2bf2(a0.x, a0.y);
            av.y = f2bf2(a0.z, a0.w);
            av.z = f2bf2(a1.x, a1.y);
            av.w = f2bf2(a1.z, a1.w);
            *(uint4*)&As[r][sk] = av;
            const short* bp = Bt + (size_t)(col0 + r) * K + kb + sk;
            *(uint4*)&Bs[r][sk] = *(const uint4*)bp;
        }
        __syncthreads();
        bf16x8 af[4], bfr[4];
#pragma unroll
        for (int i = 0; i < 4; ++i)
            af[i] = *(const bf16x8*)&As[wr + i * 16 + l16][quad * 8];
#pragma unroll
        for (int j = 0; j < 4; ++j)
            bfr[j] = *(const bf16x8*)&Bs[wc + j * 16 + l16][quad * 8];
#pragma unroll
        for (int i = 0; i < 4; ++i)
#pragma unroll
            for (int j = 0; j < 4; ++j)
                acc[i][j] = __builtin_amdgcn_mfma_f32_16x16x32_bf16(af[i], bfr[j], acc[i][j], 0, 0, 0);
        __syncthreads();
    }
#pragma unroll
    for (int i = 0; i < 4; ++i) {
        int rbase = row0 + wr + i * 16 + quad * 4;
#pragma unroll
        for (int j = 0; j < 4; ++j) {
            int c = col0 + wc + j * 16 + l16;
            float bv = bias ? bias[c] : 0.0f;
#pragma unroll
            for (int rg = 0; rg < 4; ++rg) {
                int gr = rbase + rg;
                if (gr < M) {
                    float v = acc[i][j][rg] + bv;
                    if (act) v = gelu1(v);
                    Cf[(size_t)gr * ldc + c] = v;
                    if (Cbf) Cbf[(size_t)gr * ldc + c] = (short)f2bf1(v);
                }
            }
        }
    }
}

// ---------------- GEMM: A bf16, B bf16, m97-style global_load_lds staging ----------------

__global__ __launch_bounds__(256) void gemm_bb(
    const short* __restrict__ A, int lda,
    const short* __restrict__ Bt,
    const float* __restrict__ bias,
    short* __restrict__ C, int ldc,
    int M, int N, int K, int act) {
    __shared__ __align__(16) short As[128 * 32];
    __shared__ __align__(16) short Bs[128 * 32];
    const int tid = threadIdx.x;
    const int lane = tid & 63;
    const int wave = tid >> 6;
    const int wr = (wave >> 1) * 64;
    const int wc = (wave & 1) * 64;
    const int l16 = lane & 15;
    const int quad = lane >> 4;
    const int row0 = blockIdx.x * 128;
    const int col0 = blockIdx.y * 128;
    const int c0 = tid, c1 = tid + 256;
    const int r0 = c0 >> 2, kq0 = (c0 & 3) * 8;
    const int r1 = c1 >> 2, kq1 = (c1 & 3) * 8;
    int ga0 = row0 + r0; if (ga0 >= M) ga0 = M - 1;
    int ga1 = row0 + r1; if (ga1 >= M) ga1 = M - 1;
    const short* Ap0 = A + (size_t)ga0 * lda + kq0;
    const short* Ap1 = A + (size_t)ga1 * lda + kq1;
    const short* Bp0 = Bt + (size_t)(col0 + r0) * K + kq0;
    const short* Bp1 = Bt + (size_t)(col0 + r1) * K + kq1;

    f32x4 acc[4][4];
#pragma unroll
    for (int i = 0; i < 4; ++i)
#pragma unroll
        for (int j = 0; j < 4; ++j)
            acc[i][j] = f32x4{0.f, 0.f, 0.f, 0.f};

    for (int kb = 0; kb < K; kb += 32) {
        gload16(Ap0 + kb, &As[c0 * 8]);
        gload16(Ap1 + kb, &As[c1 * 8]);
        gload16(Bp0 + kb, &Bs[c0 * 8]);
        gload16(Bp1 + kb, &Bs[c1 * 8]);
        __syncthreads();
        bf16x8 af[4], bfr[4];
#pragma unroll
        for (int i = 0; i < 4; ++i)
            af[i] = *(const bf16x8*)&As[(wr + i * 16 + l16) * 32 + quad * 8];
#pragma unroll
        for (int j = 0; j < 4; ++j)
            bfr[j] = *(const bf16x8*)&Bs[(wc + j * 16 + l16) * 32 + quad * 8];
#pragma unroll
        for (int i = 0; i < 4; ++i)
#pragma unroll
            for (int j = 0; j < 4; ++j)
                acc[i][j] = __builtin_amdgcn_mfma_f32_16x16x32_bf16(af[i], bfr[j], acc[i][j], 0, 0, 0);
        __syncthreads();
    }
#pragma unroll
    for (int i = 0; i < 4; ++i) {
        int rbase = row0 + wr + i * 16 + quad * 4;
#pragma unroll
        for (int j = 0; j < 4; ++j) {
            int c = col0 + wc + j * 16 + l16;
            float bv = bias ? bias[c] : 0.0f;
#pragma unroll
            for (int rg = 0; rg < 4; ++rg) {
                int gr = rbase + rg;
                if (gr < M) {
                    float v = acc[i][j][rg] + bv;
                    if (act) v = gelu1(v);
                    C[(size_t)gr * ldc + c] = (short)f2bf1(v);
                }
            }
        }
    }
}

// ---------------- fused gate GEMM (R7 version: pairing trick, unpadded LDS, async B) ----

__global__ __launch_bounds__(256, 3) void gemm_gate(
    const short* __restrict__ z,
    const int* __restrict__ pi, const int* __restrict__ pj, int P,
    const short* __restrict__ Bt,    // gW1^T [512][2048]
    const float* __restrict__ gb1,
    const float* __restrict__ gW2,
    float* __restrict__ gpart) {
    __shared__ __align__(16) short Aab[64 * 32];
    __shared__ __align__(16) short Amu[64 * 32];
    __shared__ __align__(16) short Bab[256 * 32];
    __shared__ __align__(16) short Bmu[256 * 32];
    __shared__ int iArr[64];
    __shared__ int jArr[64];
    __shared__ float rowsum[64];
    const int tid = threadIdx.x;
    const int lane = tid & 63;
    const int wave = tid >> 6;
    const int wc = wave * 64;
    const int l16 = lane & 15;
    const int quad = lane >> 4;
    const int row0 = blockIdx.x * 64;
    const int col0 = blockIdx.y * 256;
    const int sr = tid >> 2;        // 0..63
    const int sk = (tid & 3) * 8;

    if (tid < 64) {
        int p = row0 + tid;
        int ok = (p < P);
        iArr[tid] = ok ? pi[p] : 0;
        jArr[tid] = ok ? pj[p] : 0;
        rowsum[tid] = 0.0f;
    }
    __syncthreads();
    const short* zi = z + (size_t)iArr[sr] * 1024 + sk;
    const short* zj = z + (size_t)jArr[sr] * 1024 + sk;
    const short* bp0 = Bt + (size_t)(col0 + sr) * 2048 + sk;

    f32x4 acc[4][4];
#pragma unroll
    for (int i = 0; i < 4; ++i)
#pragma unroll
        for (int j = 0; j < 4; ++j)
            acc[i][j] = f32x4{0.f, 0.f, 0.f, 0.f};

    for (int part = 0; part < 2; ++part) {
        for (int c = 0; c < 512; c += 32) {
            const short* bp = bp0 + part * 1024 + c;
#pragma unroll
            for (int hh = 0; hh < 4; ++hh) {
                const short* q = bp + (size_t)hh * 64 * 2048;
                gload16(q, &Bab[hh * 2048 + tid * 8]);
                gload16(q + 512, &Bmu[hh * 2048 + tid * 8]);
            }
            uint4 xu = *(const uint4*)(zi + part * 512 + c);
            uint4 yu = *(const uint4*)(zj + part * 512 + c);
            float2 x0 = bfp2(xu.x), x1 = bfp2(xu.y), x2 = bfp2(xu.z), x3 = bfp2(xu.w);
            float2 y0 = bfp2(yu.x), y1 = bfp2(yu.y), y2 = bfp2(yu.z), y3 = bfp2(yu.w);
            uint4 aa, am;
            aa.x = f2bf2(fabsf(x0.x - y0.x), fabsf(x0.y - y0.y));
            aa.y = f2bf2(fabsf(x1.x - y1.x), fabsf(x1.y - y1.y));
            aa.z = f2bf2(fabsf(x2.x - y2.x), fabsf(x2.y - y2.y));
            aa.w = f2bf2(fabsf(x3.x - y3.x), fabsf(x3.y - y3.y));
            am.x = f2bf2(x0.x * y0.x, x0.y * y0.y);
            am.y = f2bf2(x1.x * y1.x, x1.y * y1.y);
            am.z = f2bf2(x2.x * y2.x, x2.y * y2.y);
            am.w = f2bf2(x3.x * y3.x, x3.y * y3.y);
            *(uint4*)&Aab[tid * 8] = aa;
            *(uint4*)&Amu[tid * 8] = am;
            __syncthreads();
            bf16x8 af[4];
#pragma unroll
            for (int i = 0; i < 4; ++i)
                af[i] = *(const bf16x8*)&Aab[(i * 16 + l16) * 32 + quad * 8];
#pragma unroll
            for (int j = 0; j < 4; ++j) {
                bf16x8 bf = *(const bf16x8*)&Bab[(wc + j * 16 + l16) * 32 + quad * 8];
#pragma unroll
                for (int i = 0; i < 4; ++i)
                    acc[i][j] = __builtin_amdgcn_mfma_f32_16x16x32_bf16(af[i], bf, acc[i][j], 0, 0, 0);
            }
#pragma unroll
            for (int i = 0; i < 4; ++i)
                af[i] = *(const bf16x8*)&Amu[(i * 16 + l16) * 32 + quad * 8];
#pragma unroll
            for (int j = 0; j < 4; ++j) {
                bf16x8 bf = *(const bf16x8*)&Bmu[(wc + j * 16 + l16) * 32 + quad * 8];
#pragma unroll
                for (int i = 0; i < 4; ++i)
                    acc[i][j] = __builtin_amdgcn_mfma_f32_16x16x32_bf16(af[i], bf, acc[i][j], 0, 0, 0);
            }
            __syncthreads();
        }
    }
#pragma unroll
    for (int i = 0; i < 4; ++i) {
#pragma unroll
        for (int rg = 0; rg < 4; ++rg) {
            float partial = 0.f;
#pragma unroll
            for (int j = 0; j < 4; ++j) {
                int cc = col0 + wc + j * 16 + l16;
                partial += gelu1(acc[i][j][rg] + gb1[cc]) * gW2[cc];
            }
            partial += __shfl_xor(partial, 1);
            partial += __shfl_xor(partial, 2);
            partial += __shfl_xor(partial, 4);
            partial += __shfl_xor(partial, 8);
            if (l16 == 0)
                atomicAdd(&rowsum[i * 16 + quad * 4 + rg], partial);
        }
    }
    __syncthreads();
    if (tid < 64 && (row0 + tid) < P)
        atomicAdd(&gpart[row0 + tid], rowsum[tid]);
}

// ---------------- fused per-layer attention: single-pass online softmax -------------
// Wave per node; 16-lane group g owns head g's 128 channels for ALL edges. Per edge:
// load own k-slice (16B/lane), reduce logit in-group, online m/l update, immediately
// aggregate own v-slice. No LDS, no multi-phase, one pass over edges.

__global__ __launch_bounds__(256) void k_attn(const short* __restrict__ qkvs,
                                              const int* __restrict__ srcS,
                                              const int* __restrict__ offs,
                                              float* __restrict__ h,
                                              short* __restrict__ h_bf,
                                              const float* __restrict__ lng,
                                              const float* __restrict__ lnb, int Nn) {
    const int tid = threadIdx.x;
    const int lane = tid & 63;
    const int wv = tid >> 6;
    const int n = blockIdx.x * 4 + wv;
    if (n >= Nn) return;
    const int st = offs[n], en = offs[n + 1];
    // lane covers channels [lane*8, lane*8+8) == head (lane>>4), slice (lane&15)*8
    const size_t chOff = (size_t)lane * 8;

    // q slice for own head
    uint4 qv = *(const uint4*)(qkvs + (size_t)n * 2048 + chOff);
    float2 q0 = bfp2(qv.x), q1 = bfp2(qv.y), q2 = bfp2(qv.z), q3 = bfp2(qv.w);
    float acc[8];
#pragma unroll
    for (int i = 0; i < 8; ++i) acc[i] = 0.f;
    float m_l = -3.4e38f, l_l = 0.f;

    for (int e0 = st; e0 < en; e0 += 64) {
        int cnt = min(64, en - e0);
        int myS = (lane < cnt) ? srcS[e0 + lane] : 0;
        for (int ei = 0; ei < cnt; ++ei) {
            int s = __shfl(myS, ei);
            const short* srow = qkvs + (size_t)s * 2048 + chOff;
            uint4 kv = *(const uint4*)(srow + 512);
            uint4 vv = *(const uint4*)(srow + 1024);
            float2 k0 = bfp2(kv.x), k1 = bfp2(kv.y), k2 = bfp2(kv.z), k3 = bfp2(kv.w);
            float d = q0.x * k0.x + q0.y * k0.y + q1.x * k1.x + q1.y * k1.y +
                      q2.x * k2.x + q2.y * k2.y + q3.x * k3.x + q3.y * k3.y;
            d += __shfl_xor(d, 1);
            d += __shfl_xor(d, 2);
            d += __shfl_xor(d, 4);
            d += __shfl_xor(d, 8);
            float lg = d * 0.08838834764831845f;
            float m_new = fmaxf(m_l, lg);
            float sc = __expf(m_l - m_new);
            float p = __expf(lg - m_new);
            l_l = l_l * sc + p;
            m_l = m_new;
            float2 v0 = bfp2(vv.x), v1 = bfp2(vv.y), v2 = bfp2(vv.z), v3 = bfp2(vv.w);
            acc[0] = acc[0] * sc + p * v0.x; acc[1] = acc[1] * sc + p * v0.y;
            acc[2] = acc[2] * sc + p * v1.x; acc[3] = acc[3] * sc + p * v1.y;
            acc[4] = acc[4] * sc + p * v2.x; acc[5] = acc[5] * sc + p * v2.y;
            acc[6] = acc[6] * sc + p * v3.x; acc[7] = acc[7] * sc + p * v3.y;
        }
    }
    float rinv = (en > st) ? 1.0f / l_l : 0.f;
    // epilogue: + skip, gelu, residual, LN — pure wave shuffles
    uint4 su = *(const uint4*)(qkvs + (size_t)n * 2048 + 1536 + chOff);
    float2 s0 = bfp2(su.x), s1 = bfp2(su.y), s2 = bfp2(su.z), s3 = bfp2(su.w);
    float sv[8] = {s0.x, s0.y, s1.x, s1.y, s2.x, s2.y, s3.x, s3.y};
    const float* hp = h + (size_t)n * 512 + chOff;
    float4 h0 = *(const float4*)hp;
    float4 h1 = *(const float4*)(hp + 4);
    float hv[8] = {h0.x, h0.y, h0.z, h0.w, h1.x, h1.y, h1.z, h1.w};
    float r[8];
    float sum = 0.f, ssq = 0.f;
#pragma unroll
    for (int i = 0; i < 8; ++i) {
        r[i] = hv[i] + gelu1(acc[i] * rinv + sv[i]);
        sum += r[i];
        ssq += r[i] * r[i];
    }
    for (int o = 32; o; o >>= 1) {
        sum += __shfl_xor(sum, o);
        ssq += __shfl_xor(ssq, o);
    }
    float mean = sum * (1.0f / 512.0f);
    float var = ssq * (1.0f / 512.0f) - mean * mean;
    float inv = rsqrtf(var + 1e-5f);
    const float* gp = lng + chOff;
    const float* bp = lnb + chOff;
    float4 g0 = *(const float4*)gp, g1 = *(const float4*)(gp + 4);
    float4 b0 = *(const float4*)bp, b1 = *(const float4*)(bp + 4);
    float ga[8] = {g0.x, g0.y, g0.z, g0.w, g1.x, g1.y, g1.z, g1.w};
    float ba[8] = {b0.x, b0.y, b0.z, b0.w, b1.x, b1.y, b1.z, b1.w};
    float o8[8];
#pragma unroll
    for (int i = 0; i < 8; ++i) o8[i] = (r[i] - mean) * inv * ga[i] + ba[i];
    float* hw = h + (size_t)n * 512 + chOff;
    *(float4*)hw = make_float4(o8[0], o8[1], o8[2], o8[3]);
    *(float4*)(hw + 4) = make_float4(o8[4], o8[5], o8[6], o8[7]);
    uint4 ob;
    ob.x = f2bf2(o8[0], o8[1]);
    ob.y = f2bf2(o8[2], o8[3]);
    ob.z = f2bf2(o8[4], o8[5]);
    ob.w = f2bf2(o8[6], o8[7]);
    *(uint4*)(h_bf + (size_t)n * 512 + chOff) = ob;
}

// ---------------- pair bilinear scores (bf16 z,t) ----------------

__global__ __launch_bounds__(256) void k_pairscore(const short* __restrict__ z,
                                                   const short* __restrict__ t,
                                                   const int* __restrict__ pi,
                                                   const int* __restrict__ pj,
                                                   float* __restrict__ ssyn,
                                                   float* __restrict__ sant, int P) {
    int p = blockIdx.x * 4 + (threadIdx.x >> 6);
    if (p >= P) return;
    int lane = threadIdx.x & 63;
    int i = pi[p], j = pj[p];
    uint4 a = *(const uint4*)(t + (size_t)i * 1024 + lane * 8);
    uint4 b = *(const uint4*)(z + (size_t)j * 1024 + lane * 8);
    float2 a0 = bfp2(a.x), a1 = bfp2(a.y), a2 = bfp2(a.z), a3 = bfp2(a.w);
    float2 b0 = bfp2(b.x), b1 = bfp2(b.y), b2 = bfp2(b.z), b3 = bfp2(b.w);
    float ds = a0.x * b0.x + a0.y * b0.y + a1.x * b1.x + a1.y * b1.y +
               a2.x * b2.x + a2.y * b2.y + a3.x * b3.x + a3.y * b3.y;
    uint4 c = *(const uint4*)(t + (size_t)i * 1024 + 512 + lane * 8);
    uint4 d = *(const uint4*)(z + (size_t)j * 1024 + 512 + lane * 8);
    float2 c0 = bfp2(c.x), c1 = bfp2(c.y), c2 = bfp2(c.z), c3 = bfp2(c.w);
    float2 d0 = bfp2(d.x), d1 = bfp2(d.y), d2 = bfp2(d.z), d3 = bfp2(d.w);
    float da = c0.x * d0.x + c0.y * d0.y + c1.x * d1.x + c1.y * d1.y +
               c2.x * d2.x + c2.y * d2.y + c3.x * d3.x + c3.y * d3.y;
    for (int o = 32; o; o >>= 1) {
        ds += __shfl_xor(ds, o);
        da += __shfl_xor(da, o);
    }
    if (lane == 0) { ssyn[p] = ds; sant[p] = da; }
}

// ---------------- final elementwise combine ----------------

__global__ void k_final(const float* __restrict__ gpart, const float* __restrict__ gb2,
                        const float* __restrict__ ssyn, const float* __restrict__ sant,
                        float* __restrict__ out, int P) {
    int p = blockIdx.x * 256 + threadIdx.x;
    if (p < P) {
        float s = 1.0f / (1.0f + __expf(-(gpart[p] + gb2[0])));
        out[p] = s * sant[p] - (1.0f - s) * ssyn[p];
    }
}

// ---------------- host ----------------

extern "C" void kernel_launch(void* const* d_in, const int* in_sizes, int n_in,
                              void* d_out, int out_size, void* d_ws, size_t ws_size,
                              hipStream_t stream) {
    const float* x = (const float*)d_in[0];
    const int* ei = (const int*)d_in[1];
    const int* pe = (const int*)d_in[2];
    const float* mixer_W = (const float*)d_in[3];
    const float* mixer_b = (const float*)d_in[4];
    const float* Wq = (const float*)d_in[5];
    const float* bq = (const float*)d_in[6];
    const float* Wk = (const float*)d_in[7];
    const float* bk = (const float*)d_in[8];
    const float* Wv = (const float*)d_in[9];
    const float* bv = (const float*)d_in[10];
    const float* Ws = (const float*)d_in[11];
    const float* bs = (const float*)d_in[12];
    const float* ln_g = (const float*)d_in[13];
    const float* ln_b = (const float*)d_in[14];
    const float* syn_W = (const float*)d_in[15];
    const float* syn_b = (const float*)d_in[16];
    const float* ant_W = (const float*)d_in[17];
    const float* ant_b = (const float*)d_in[18];
    const float* W_syn = (const float*)d_in[19];
    const float* W_ant = (const float*)d_in[20];
    const float* gW1 = (const float*)d_in[21];
    const float* gb1 = (const float*)d_in[22];
    const float* gW2 = (const float*)d_in[23];
    const float* gb2 = (const float*)d_in[24];
    float* out = (float*)d_out;

    const int Nn = in_sizes[0] / 768;  // 20000
    const int E = in_sizes[1] / 2;     // 320000
    const int P = in_sizes[2] / 2;     // 100000

    char* w = (char*)d_ws;
    auto alloc = [&](size_t bytes) -> char* {
        char* p = w;
        w += (bytes + 255) & ~(size_t)255;
        return p;
    };
    float* h = (float*)alloc((size_t)Nn * 512 * 4);
    short* h_bf = (short*)alloc((size_t)Nn * 512 * 2);
    short* qkvs = (short*)alloc((size_t)Nn * 2048 * 2);
    short* zB = qkvs;
    short* tB = qkvs + (size_t)Nn * 1024;
    float* ssyn = (float*)alloc((size_t)P * 3 * 4);
    float* sant = ssyn + P;
    float* gpart = ssyn + 2 * P;
    int* srcS = (int*)alloc((size_t)E * 4);
    int* hist = (int*)alloc((size_t)Nn * 2 * 4);
    int* cursor = hist + Nn;
    int* offs = (int*)alloc((size_t)(Nn + 1) * 4);
    short* mixWt = (short*)alloc((size_t)512 * 768 * 2);
    short* wcat = (short*)alloc((size_t)L_LAYERS * 2048 * 512 * 2);
    short* dualWt = (short*)alloc((size_t)1024 * 512 * 2);
    short* bilWt = (short*)alloc((size_t)1024 * 512 * 2);
    short* gw1t = (short*)alloc((size_t)512 * 2048 * 2);
    float* bcat = (float*)alloc((size_t)L_LAYERS * 2048 * 4);
    float* bdual = (float*)alloc((size_t)1024 * 4);

    k_zero<<<(2 * Nn + 255) / 256, 256, 0, stream>>>(hist, 2 * Nn);
    k_hist<<<(E + 255) / 256, 256, 0, stream>>>(ei + E, hist, E);
    k_scan<<<1, 1024, 0, stream>>>(hist, offs, Nn);
    k_scatter<<<(E + 255) / 256, 256, 0, stream>>>(ei, ei + E, offs, cursor, srcS, E);

    k_wcat<<<(L_LAYERS * 2048 * 512) / 256, 256, 0, stream>>>(Wq, Wk, Wv, Ws, wcat);
    k_tr<<<dim3(3, 512), 256, 0, stream>>>(mixer_W, mixWt, 768, 512);
    k_tr<<<dim3(2, 512), 256, 0, stream>>>(syn_W, dualWt, 512, 512);
    k_tr<<<dim3(2, 512), 256, 0, stream>>>(ant_W, dualWt + 512 * 512, 512, 512);
    k_tr<<<dim3(2, 512), 256, 0, stream>>>(W_syn, bilWt, 512, 512);
    k_tr<<<dim3(2, 512), 256, 0, stream>>>(W_ant, bilWt + 512 * 512, 512, 512);
    k_tr<<<dim3(8, 512), 256, 0, stream>>>(gW1, gw1t, 2048, 512);
    k_bcat<<<48, 256, 0, stream>>>(bq, bk, bv, bs, bcat);
    k_bdual<<<4, 256, 0, stream>>>(syn_b, ant_b, bdual);

    const int mtiles = (Nn + 127) / 128;  // 157
    gemm_a32<<<dim3(mtiles, 4), 256, 0, stream>>>(x, 768, mixWt, mixer_b, h, h_bf, 512,
                                                  Nn, 512, 768, 1);

    for (int l = 0; l < L_LAYERS; ++l) {
        gemm_bb<<<dim3(mtiles, 16), 256, 0, stream>>>(h_bf, 512, wcat + (size_t)l * 2048 * 512,
                                                      bcat + l * 2048, qkvs, 2048,
                                                      Nn, 2048, 512, 0);
        k_attn<<<(Nn + 3) / 4, 256, 0, stream>>>(qkvs, srcS, offs, h, h_bf,
                                                 ln_g + l * 512, ln_b + l * 512, Nn);
    }

    gemm_bb<<<dim3(mtiles, 8), 256, 0, stream>>>(h_bf, 512, dualWt, bdual, zB, 1024,
                                                 Nn, 1024, 512, 1);
    gemm_bb<<<dim3(mtiles, 4), 256, 0, stream>>>(zB, 1024, bilWt, nullptr, tB, 1024,
                                                 Nn, 512, 512, 0);
    gemm_bb<<<dim3(mtiles, 4), 256, 0, stream>>>(zB + 512, 1024, bilWt + 512 * 512, nullptr,
                                                 tB + 512, 1024, Nn, 512, 512, 0);

    k_pairscore<<<(P + 3) / 4, 256, 0, stream>>>(zB, tB, pe, pe + P, ssyn, sant, P);

    k_zero<<<(P + 255) / 256, 256, 0, stream>>>((int*)gpart, P);
    gemm_gate<<<dim3((P + 63) / 64, 2), 256, 0, stream>>>(zB, pe, pe + P, P,
                                                          gw1t, gb1, gW2, gpart);
    k_final<<<(P + 255) / 256, 256, 0, stream>>>(gpart, gb2, ssyn, sant, out, P);
}

// Round 10
// 1888.053 us; speedup vs baseline: 1.2357x; 1.1124x over previous
//
#include <hip/hip_runtime.h>
#include <cstdint>

#define L_LAYERS 6

typedef __attribute__((ext_vector_type(8))) short bf16x8;
typedef __attribute__((ext_vector_type(4))) float f32x4;
typedef __attribute__((ext_vector_type(2))) float f32x2;

__device__ __forceinline__ float gelu1(float v) {
    return 0.5f * v * (1.0f + erff(v * 0.7071067811865475f));
}

__device__ __forceinline__ unsigned int f2bf2(float a, float b) {
    union { float f; unsigned u; } x, y;
    x.f = a; y.f = b;
    unsigned lo = (x.u + 0x7FFFu + ((x.u >> 16) & 1u)) >> 16;
    unsigned hi = (y.u + 0x7FFFu + ((y.u >> 16) & 1u)) & 0xFFFF0000u;
    return lo | hi;
}

__device__ __forceinline__ unsigned short f2bf1(float a) {
    union { float f; unsigned u; } x;
    x.f = a;
    return (unsigned short)((x.u + 0x7FFFu + ((x.u >> 16) & 1u)) >> 16);
}

__device__ __forceinline__ float2 bfp2(unsigned u) {
    union { unsigned u; float f; } a, b;
    a.u = u << 16;
    b.u = u & 0xFFFF0000u;
    return make_float2(a.f, b.f);
}

// async global->LDS, 16 bytes per lane (dest = wave-uniform base + lane*16)
__device__ __forceinline__ void gload16(const void* g, void* l) {
    __builtin_amdgcn_global_load_lds(
        (const __attribute__((address_space(1))) void*)g,
        (__attribute__((address_space(3))) void*)l, 16, 0, 0);
}

// ---------------- utility ----------------

__global__ void k_zero(int* __restrict__ p, int n) {
    int i = blockIdx.x * 256 + threadIdx.x;
    if (i < n) p[i] = 0;
}

// ---------------- edge sorting (counting sort by dst) ----------------

__global__ void k_hist(const int* __restrict__ dst, int* __restrict__ hist, int E) {
    int e = blockIdx.x * 256 + threadIdx.x;
    if (e < E) atomicAdd(&hist[dst[e]], 1);
}

__global__ __launch_bounds__(1024) void k_scan(const int* __restrict__ hist,
                                               int* __restrict__ off, int n) {
    __shared__ int buf[1024];
    __shared__ int carry;
    int tid = threadIdx.x;
    if (tid == 0) carry = 0;
    __syncthreads();
    for (int base = 0; base < n; base += 1024) {
        int v = (base + tid < n) ? hist[base + tid] : 0;
        buf[tid] = v;
        __syncthreads();
        int x = v;
        for (int o = 1; o < 1024; o <<= 1) {
            int t = (tid >= o) ? buf[tid - o] : 0;
            __syncthreads();
            x += t;
            buf[tid] = x;
            __syncthreads();
        }
        int c = carry;
        if (base + tid < n) off[base + tid] = c + x - v;   // exclusive
        __syncthreads();
        if (tid == 1023) carry = c + buf[1023];
        __syncthreads();
    }
    if (tid == 0) off[n] = carry;
}

__global__ void k_scatter(const int* __restrict__ src, const int* __restrict__ dst,
                          const int* __restrict__ off, int* __restrict__ cursor,
                          int* __restrict__ srcS, int E) {
    int e = blockIdx.x * 256 + threadIdx.x;
    if (e < E) {
        int d = dst[e];
        int pos = off[d] + atomicAdd(&cursor[d], 1);
        srcS[pos] = src[e];
    }
}

// ---------------- weight prep (transpose + cvt to bf16) ----------------

__global__ void k_wcat(const float* __restrict__ Wq, const float* __restrict__ Wk,
                       const float* __restrict__ Wv, const float* __restrict__ Ws,
                       short* __restrict__ Wt) {
    int idx = blockIdx.x * 256 + threadIdx.x;   // l*2^20 + n*512 + k
    int k = idx & 511;
    int nf = (idx >> 9) & 2047;
    int l = idx >> 20;
    int sel = nf >> 9, nn = nf & 511;
    const float* W = (sel == 0) ? Wq : (sel == 1) ? Wk : (sel == 2) ? Wv : Ws;
    float v = W[((size_t)l * 512 + k) * 512 + nn];
    Wt[idx] = (short)f2bf1(v);
}

__global__ void k_tr(const float* __restrict__ W, short* __restrict__ Wt, int K, int N) {
    int k = blockIdx.x * 256 + threadIdx.x;
    int n = blockIdx.y;
    if (k < K) Wt[(size_t)n * K + k] = (short)f2bf1(W[(size_t)k * N + n]);
}

__global__ void k_bcat(const float* __restrict__ bq, const float* __restrict__ bk,
                       const float* __restrict__ bv, const float* __restrict__ bs,
                       float* __restrict__ bcat) {
    int idx = blockIdx.x * 256 + threadIdx.x;
    if (idx >= L_LAYERS * 2048) return;
    int l = idx >> 11, n = idx & 2047;
    int sel = n >> 9, nn = n & 511;
    const float* b = (sel == 0) ? bq : (sel == 1) ? bk : (sel == 2) ? bv : bs;
    bcat[idx] = b[l * 512 + nn];
}

__global__ void k_bdual(const float* __restrict__ sb, const float* __restrict__ ab,
                        float* __restrict__ bd) {
    int idx = blockIdx.x * 256 + threadIdx.x;
    if (idx < 1024) bd[idx] = (idx < 512) ? sb[idx] : ab[idx - 512];
}

// ---------------- GEMM: A fp32 (mixer only) ----------------

__global__ __launch_bounds__(256) void gemm_a32(
    const float* __restrict__ A, int lda,
    const short* __restrict__ Bt,
    const float* __restrict__ bias,
    float* __restrict__ Cf, short* __restrict__ Cbf, int ldc,
    int M, int N, int K, int act) {
    __shared__ __align__(16) short As[128][40];
    __shared__ __align__(16) short Bs[128][40];
    const int tid = threadIdx.x;
    const int lane = tid & 63;
    const int wave = tid >> 6;
    const int wr = (wave >> 1) * 64;
    const int wc = (wave & 1) * 64;
    const int l16 = lane & 15;
    const int quad = lane >> 4;
    const int row0 = blockIdx.x * 128;
    const int col0 = blockIdx.y * 128;
    const int sr = tid >> 2;
    const int sk = (tid & 3) * 8;

    f32x4 acc[4][4];
#pragma unroll
    for (int i = 0; i < 4; ++i)
#pragma unroll
        for (int j = 0; j < 4; ++j)
            acc[i][j] = f32x4{0.f, 0.f, 0.f, 0.f};

    for (int kb = 0; kb < K; kb += 32) {
#pragma unroll
        for (int hh = 0; hh < 2; ++hh) {
            int r = sr + hh * 64;
            int gr = row0 + r;
            float4 a0, a1;
            if (gr < M) {
                const float* p = A + (size_t)gr * lda + kb + sk;
                a0 = *(const float4*)p;
                a1 = *(const float4*)(p + 4);
            } else {
                a0 = make_float4(0.f, 0.f, 0.f, 0.f);
                a1 = make_float4(0.f, 0.f, 0.f, 0.f);
            }
            uint4 av;
            av.x = f2bf2(a0.x, a0.y);
            av.y = f2bf2(a0.z, a0.w);
            av.z = f2bf2(a1.x, a1.y);
            av.w = f2bf2(a1.z, a1.w);
            *(uint4*)&As[r][sk] = av;
            const short* bp = Bt + (size_t)(col0 + r) * K + kb + sk;
            *(uint4*)&Bs[r][sk] = *(const uint4*)bp;
        }
        __syncthreads();
        bf16x8 af[4], bfr[4];
#pragma unroll
        for (int i = 0; i < 4; ++i)
            af[i] = *(const bf16x8*)&As[wr + i * 16 + l16][quad * 8];
#pragma unroll
        for (int j = 0; j < 4; ++j)
            bfr[j] = *(const bf16x8*)&Bs[wc + j * 16 + l16][quad * 8];
#pragma unroll
        for (int i = 0; i < 4; ++i)
#pragma unroll
            for (int j = 0; j < 4; ++j)
                acc[i][j] = __builtin_amdgcn_mfma_f32_16x16x32_bf16(af[i], bfr[j], acc[i][j], 0, 0, 0);
        __syncthreads();
    }
#pragma unroll
    for (int i = 0; i < 4; ++i) {
        int rbase = row0 + wr + i * 16 + quad * 4;
#pragma unroll
        for (int j = 0; j < 4; ++j) {
            int c = col0 + wc + j * 16 + l16;
            float bv = bias ? bias[c] : 0.0f;
#pragma unroll
            for (int rg = 0; rg < 4; ++rg) {
                int gr = rbase + rg;
                if (gr < M) {
                    float v = acc[i][j][rg] + bv;
                    if (act) v = gelu1(v);
                    Cf[(size_t)gr * ldc + c] = v;
                    if (Cbf) Cbf[(size_t)gr * ldc + c] = (short)f2bf1(v);
                }
            }
        }
    }
}

// ---------------- GEMM: A bf16, B bf16, m97-style global_load_lds staging ----------------

__global__ __launch_bounds__(256) void gemm_bb(
    const short* __restrict__ A, int lda,
    const short* __restrict__ Bt,
    const float* __restrict__ bias,
    short* __restrict__ C, int ldc,
    int M, int N, int K, int act) {
    __shared__ __align__(16) short As[128 * 32];
    __shared__ __align__(16) short Bs[128 * 32];
    const int tid = threadIdx.x;
    const int lane = tid & 63;
    const int wave = tid >> 6;
    const int wr = (wave >> 1) * 64;
    const int wc = (wave & 1) * 64;
    const int l16 = lane & 15;
    const int quad = lane >> 4;
    const int row0 = blockIdx.x * 128;
    const int col0 = blockIdx.y * 128;
    const int c0 = tid, c1 = tid + 256;
    const int r0 = c0 >> 2, kq0 = (c0 & 3) * 8;
    const int r1 = c1 >> 2, kq1 = (c1 & 3) * 8;
    int ga0 = row0 + r0; if (ga0 >= M) ga0 = M - 1;
    int ga1 = row0 + r1; if (ga1 >= M) ga1 = M - 1;
    const short* Ap0 = A + (size_t)ga0 * lda + kq0;
    const short* Ap1 = A + (size_t)ga1 * lda + kq1;
    const short* Bp0 = Bt + (size_t)(col0 + r0) * K + kq0;
    const short* Bp1 = Bt + (size_t)(col0 + r1) * K + kq1;

    f32x4 acc[4][4];
#pragma unroll
    for (int i = 0; i < 4; ++i)
#pragma unroll
        for (int j = 0; j < 4; ++j)
            acc[i][j] = f32x4{0.f, 0.f, 0.f, 0.f};

    for (int kb = 0; kb < K; kb += 32) {
        gload16(Ap0 + kb, &As[c0 * 8]);
        gload16(Ap1 + kb, &As[c1 * 8]);
        gload16(Bp0 + kb, &Bs[c0 * 8]);
        gload16(Bp1 + kb, &Bs[c1 * 8]);
        __syncthreads();
        bf16x8 af[4], bfr[4];
#pragma unroll
        for (int i = 0; i < 4; ++i)
            af[i] = *(const bf16x8*)&As[(wr + i * 16 + l16) * 32 + quad * 8];
#pragma unroll
        for (int j = 0; j < 4; ++j)
            bfr[j] = *(const bf16x8*)&Bs[(wc + j * 16 + l16) * 32 + quad * 8];
#pragma unroll
        for (int i = 0; i < 4; ++i)
#pragma unroll
            for (int j = 0; j < 4; ++j)
                acc[i][j] = __builtin_amdgcn_mfma_f32_16x16x32_bf16(af[i], bfr[j], acc[i][j], 0, 0, 0);
        __syncthreads();
    }
#pragma unroll
    for (int i = 0; i < 4; ++i) {
        int rbase = row0 + wr + i * 16 + quad * 4;
#pragma unroll
        for (int j = 0; j < 4; ++j) {
            int c = col0 + wc + j * 16 + l16;
            float bv = bias ? bias[c] : 0.0f;
#pragma unroll
            for (int rg = 0; rg < 4; ++rg) {
                int gr = rbase + rg;
                if (gr < M) {
                    float v = acc[i][j][rg] + bv;
                    if (act) v = gelu1(v);
                    C[(size_t)gr * ldc + c] = (short)f2bf1(v);
                }
            }
        }
    }
}

// ---------------- qkv GEMM with split-layout epilogue ----------------
// Output cols: [0,512) q -> qvs+0 ; [512,1024) k -> k8 (fp8 e4m3) ;
// [1024,1536) v -> qvs+512 ; [1536,2048) s -> qvs+1024. qvs row stride 1536.

__global__ __launch_bounds__(256) void gemm_qkvs(
    const short* __restrict__ A,      // h_bf [M][512]
    const short* __restrict__ Bt,     // layer weights [2048][512]
    const float* __restrict__ bias,   // [2048]
    short* __restrict__ qvs,          // [M][1536] bf16
    unsigned char* __restrict__ k8,   // [M][512] fp8
    int M) {
    const int K = 512;
    __shared__ __align__(16) short As[128 * 32];
    __shared__ __align__(16) short Bs[128 * 32];
    const int tid = threadIdx.x;
    const int lane = tid & 63;
    const int wave = tid >> 6;
    const int wr = (wave >> 1) * 64;
    const int wc = (wave & 1) * 64;
    const int l16 = lane & 15;
    const int quad = lane >> 4;
    const int row0 = blockIdx.x * 128;
    const int col0 = blockIdx.y * 128;
    const int c0 = tid, c1 = tid + 256;
    const int r0 = c0 >> 2, kq0 = (c0 & 3) * 8;
    const int r1 = c1 >> 2, kq1 = (c1 & 3) * 8;
    int ga0 = row0 + r0; if (ga0 >= M) ga0 = M - 1;
    int ga1 = row0 + r1; if (ga1 >= M) ga1 = M - 1;
    const short* Ap0 = A + (size_t)ga0 * K + kq0;
    const short* Ap1 = A + (size_t)ga1 * K + kq1;
    const short* Bp0 = Bt + (size_t)(col0 + r0) * K + kq0;
    const short* Bp1 = Bt + (size_t)(col0 + r1) * K + kq1;

    f32x4 acc[4][4];
#pragma unroll
    for (int i = 0; i < 4; ++i)
#pragma unroll
        for (int j = 0; j < 4; ++j)
            acc[i][j] = f32x4{0.f, 0.f, 0.f, 0.f};

    for (int kb = 0; kb < K; kb += 32) {
        gload16(Ap0 + kb, &As[c0 * 8]);
        gload16(Ap1 + kb, &As[c1 * 8]);
        gload16(Bp0 + kb, &Bs[c0 * 8]);
        gload16(Bp1 + kb, &Bs[c1 * 8]);
        __syncthreads();
        bf16x8 af[4], bfr[4];
#pragma unroll
        for (int i = 0; i < 4; ++i)
            af[i] = *(const bf16x8*)&As[(wr + i * 16 + l16) * 32 + quad * 8];
#pragma unroll
        for (int j = 0; j < 4; ++j)
            bfr[j] = *(const bf16x8*)&Bs[(wc + j * 16 + l16) * 32 + quad * 8];
#pragma unroll
        for (int i = 0; i < 4; ++i)
#pragma unroll
            for (int j = 0; j < 4; ++j)
                acc[i][j] = __builtin_amdgcn_mfma_f32_16x16x32_bf16(af[i], bfr[j], acc[i][j], 0, 0, 0);
        __syncthreads();
    }
#pragma unroll
    for (int i = 0; i < 4; ++i) {
        int rbase = row0 + wr + i * 16 + quad * 4;
#pragma unroll
        for (int j = 0; j < 4; ++j) {
            int c = col0 + wc + j * 16 + l16;
            int sec = c >> 9;           // uniform within a 64-col wave tile
            int cc = c & 511;
            float bv = bias[c];
#pragma unroll
            for (int rg = 0; rg < 4; ++rg) {
                int gr = rbase + rg;
                if (gr < M) {
                    float v = acc[i][j][rg] + bv;
                    if (sec == 1) {
                        int r8 = __builtin_amdgcn_cvt_pk_fp8_f32(v, v, 0, false);
                        k8[(size_t)gr * 512 + cc] = (unsigned char)(r8 & 0xFF);
                    } else {
                        int off = (sec == 0) ? cc : ((sec == 2) ? 512 + cc : 1024 + cc);
                        qvs[(size_t)gr * 1536 + off] = (short)f2bf1(v);
                    }
                }
            }
        }
    }
}

// ---------------- fused gate GEMM (R7 version: pairing trick, unpadded LDS, async B) ----

__global__ __launch_bounds__(256, 3) void gemm_gate(
    const short* __restrict__ z,
    const int* __restrict__ pi, const int* __restrict__ pj, int P,
    const short* __restrict__ Bt,    // gW1^T [512][2048]
    const float* __restrict__ gb1,
    const float* __restrict__ gW2,
    float* __restrict__ gpart) {
    __shared__ __align__(16) short Aab[64 * 32];
    __shared__ __align__(16) short Amu[64 * 32];
    __shared__ __align__(16) short Bab[256 * 32];
    __shared__ __align__(16) short Bmu[256 * 32];
    __shared__ int iArr[64];
    __shared__ int jArr[64];
    __shared__ float rowsum[64];
    const int tid = threadIdx.x;
    const int lane = tid & 63;
    const int wave = tid >> 6;
    const int wc = wave * 64;
    const int l16 = lane & 15;
    const int quad = lane >> 4;
    const int row0 = blockIdx.x * 64;
    const int col0 = blockIdx.y * 256;
    const int sr = tid >> 2;        // 0..63
    const int sk = (tid & 3) * 8;

    if (tid < 64) {
        int p = row0 + tid;
        int ok = (p < P);
        iArr[tid] = ok ? pi[p] : 0;
        jArr[tid] = ok ? pj[p] : 0;
        rowsum[tid] = 0.0f;
    }
    __syncthreads();
    const short* zi = z + (size_t)iArr[sr] * 1024 + sk;
    const short* zj = z + (size_t)jArr[sr] * 1024 + sk;
    const short* bp0 = Bt + (size_t)(col0 + sr) * 2048 + sk;

    f32x4 acc[4][4];
#pragma unroll
    for (int i = 0; i < 4; ++i)
#pragma unroll
        for (int j = 0; j < 4; ++j)
            acc[i][j] = f32x4{0.f, 0.f, 0.f, 0.f};

    for (int part = 0; part < 2; ++part) {
        for (int c = 0; c < 512; c += 32) {
            const short* bp = bp0 + part * 1024 + c;
#pragma unroll
            for (int hh = 0; hh < 4; ++hh) {
                const short* q = bp + (size_t)hh * 64 * 2048;
                gload16(q, &Bab[hh * 2048 + tid * 8]);
                gload16(q + 512, &Bmu[hh * 2048 + tid * 8]);
            }
            uint4 xu = *(const uint4*)(zi + part * 512 + c);
            uint4 yu = *(const uint4*)(zj + part * 512 + c);
            float2 x0 = bfp2(xu.x), x1 = bfp2(xu.y), x2 = bfp2(xu.z), x3 = bfp2(xu.w);
            float2 y0 = bfp2(yu.x), y1 = bfp2(yu.y), y2 = bfp2(yu.z), y3 = bfp2(yu.w);
            uint4 aa, am;
            aa.x = f2bf2(fabsf(x0.x - y0.x), fabsf(x0.y - y0.y));
            aa.y = f2bf2(fabsf(x1.x - y1.x), fabsf(x1.y - y1.y));
            aa.z = f2bf2(fabsf(x2.x - y2.x), fabsf(x2.y - y2.y));
            aa.w = f2bf2(fabsf(x3.x - y3.x), fabsf(x3.y - y3.y));
            am.x = f2bf2(x0.x * y0.x, x0.y * y0.y);
            am.y = f2bf2(x1.x * y1.x, x1.y * y1.y);
            am.z = f2bf2(x2.x * y2.x, x2.y * y2.y);
            am.w = f2bf2(x3.x * y3.x, x3.y * y3.y);
            *(uint4*)&Aab[tid * 8] = aa;
            *(uint4*)&Amu[tid * 8] = am;
            __syncthreads();
            bf16x8 af[4];
#pragma unroll
            for (int i = 0; i < 4; ++i)
                af[i] = *(const bf16x8*)&Aab[(i * 16 + l16) * 32 + quad * 8];
#pragma unroll
            for (int j = 0; j < 4; ++j) {
                bf16x8 bf = *(const bf16x8*)&Bab[(wc + j * 16 + l16) * 32 + quad * 8];
#pragma unroll
                for (int i = 0; i < 4; ++i)
                    acc[i][j] = __builtin_amdgcn_mfma_f32_16x16x32_bf16(af[i], bf, acc[i][j], 0, 0, 0);
            }
#pragma unroll
            for (int i = 0; i < 4; ++i)
                af[i] = *(const bf16x8*)&Amu[(i * 16 + l16) * 32 + quad * 8];
#pragma unroll
            for (int j = 0; j < 4; ++j) {
                bf16x8 bf = *(const bf16x8*)&Bmu[(wc + j * 16 + l16) * 32 + quad * 8];
#pragma unroll
                for (int i = 0; i < 4; ++i)
                    acc[i][j] = __builtin_amdgcn_mfma_f32_16x16x32_bf16(af[i], bf, acc[i][j], 0, 0, 0);
            }
            __syncthreads();
        }
    }
#pragma unroll
    for (int i = 0; i < 4; ++i) {
#pragma unroll
        for (int rg = 0; rg < 4; ++rg) {
            float partial = 0.f;
#pragma unroll
            for (int j = 0; j < 4; ++j) {
                int cc = col0 + wc + j * 16 + l16;
                partial += gelu1(acc[i][j][rg] + gb1[cc]) * gW2[cc];
            }
            partial += __shfl_xor(partial, 1);
            partial += __shfl_xor(partial, 2);
            partial += __shfl_xor(partial, 4);
            partial += __shfl_xor(partial, 8);
            if (l16 == 0)
                atomicAdd(&rowsum[i * 16 + quad * 4 + rg], partial);
        }
    }
    __syncthreads();
    if (tid < 64 && (row0 + tid) < P)
        atomicAdd(&gpart[row0 + tid], rowsum[tid]);
}

// ---------------- fused per-layer attention: single-pass, fp8 k gather -------------
// qvs bf16 [Nn][1536] (q|v|s), k8 fp8 [Nn][512]. Wave per node; lane owns 8 channels.
// Per edge: 8B k8 load + 16B v load (1.5 KB/edge/wave vs 2 KB with bf16 k).

__global__ __launch_bounds__(256) void k_attn(const short* __restrict__ qvs,
                                              const unsigned char* __restrict__ k8,
                                              const int* __restrict__ srcS,
                                              const int* __restrict__ offs,
                                              float* __restrict__ h,
                                              short* __restrict__ h_bf,
                                              const float* __restrict__ lng,
                                              const float* __restrict__ lnb, int Nn) {
    const int tid = threadIdx.x;
    const int lane = tid & 63;
    const int wv = tid >> 6;
    const int n = blockIdx.x * 4 + wv;
    if (n >= Nn) return;
    const int st = offs[n], en = offs[n + 1];
    const size_t chOff = (size_t)lane * 8;

    // q slice for own head (bf16)
    uint4 qv = *(const uint4*)(qvs + (size_t)n * 1536 + chOff);
    float2 q0 = bfp2(qv.x), q1 = bfp2(qv.y), q2 = bfp2(qv.z), q3 = bfp2(qv.w);
    float acc[8];
#pragma unroll
    for (int i = 0; i < 8; ++i) acc[i] = 0.f;
    float m_l = -3.4e38f, l_l = 0.f;

    for (int e0 = st; e0 < en; e0 += 64) {
        int cnt = min(64, en - e0);
        int myS = (lane < cnt) ? srcS[e0 + lane] : 0;
        for (int ei = 0; ei < cnt; ++ei) {
            int s = __shfl(myS, ei);
            uint2 kq = *(const uint2*)(k8 + (size_t)s * 512 + chOff);
            uint4 vv = *(const uint4*)(qvs + (size_t)s * 1536 + 512 + chOff);
            f32x2 k0 = __builtin_amdgcn_cvt_pk_f32_fp8((int)kq.x, false);
            f32x2 k1 = __builtin_amdgcn_cvt_pk_f32_fp8((int)kq.x, true);
            f32x2 k2 = __builtin_amdgcn_cvt_pk_f32_fp8((int)kq.y, false);
            f32x2 k3 = __builtin_amdgcn_cvt_pk_f32_fp8((int)kq.y, true);
            float d = q0.x * k0.x + q0.y * k0.y + q1.x * k1.x + q1.y * k1.y +
                      q2.x * k2.x + q2.y * k2.y + q3.x * k3.x + q3.y * k3.y;
            d += __shfl_xor(d, 1);
            d += __shfl_xor(d, 2);
            d += __shfl_xor(d, 4);
            d += __shfl_xor(d, 8);
            float lg = d * 0.08838834764831845f;
            float m_new = fmaxf(m_l, lg);
            float sc = __expf(m_l - m_new);
            float p = __expf(lg - m_new);
            l_l = l_l * sc + p;
            m_l = m_new;
            float2 v0 = bfp2(vv.x), v1 = bfp2(vv.y), v2 = bfp2(vv.z), v3 = bfp2(vv.w);
            acc[0] = acc[0] * sc + p * v0.x; acc[1] = acc[1] * sc + p * v0.y;
            acc[2] = acc[2] * sc + p * v1.x; acc[3] = acc[3] * sc + p * v1.y;
            acc[4] = acc[4] * sc + p * v2.x; acc[5] = acc[5] * sc + p * v2.y;
            acc[6] = acc[6] * sc + p * v3.x; acc[7] = acc[7] * sc + p * v3.y;
        }
    }
    float rinv = (en > st) ? 1.0f / l_l : 0.f;
    // epilogue: + skip, gelu, residual, LN — pure wave shuffles
    uint4 su = *(const uint4*)(qvs + (size_t)n * 1536 + 1024 + chOff);
    float2 s0 = bfp2(su.x), s1 = bfp2(su.y), s2 = bfp2(su.z), s3 = bfp2(su.w);
    float sv[8] = {s0.x, s0.y, s1.x, s1.y, s2.x, s2.y, s3.x, s3.y};
    const float* hp = h + (size_t)n * 512 + chOff;
    float4 h0 = *(const float4*)hp;
    float4 h1 = *(const float4*)(hp + 4);
    float hv[8] = {h0.x, h0.y, h0.z, h0.w, h1.x, h1.y, h1.z, h1.w};
    float r[8];
    float sum = 0.f, ssq = 0.f;
#pragma unroll
    for (int i = 0; i < 8; ++i) {
        r[i] = hv[i] + gelu1(acc[i] * rinv + sv[i]);
        sum += r[i];
        ssq += r[i] * r[i];
    }
    for (int o = 32; o; o >>= 1) {
        sum += __shfl_xor(sum, o);
        ssq += __shfl_xor(ssq, o);
    }
    float mean = sum * (1.0f / 512.0f);
    float var = ssq * (1.0f / 512.0f) - mean * mean;
    float inv = rsqrtf(var + 1e-5f);
    const float* gp = lng + chOff;
    const float* bp = lnb + chOff;
    float4 g0 = *(const float4*)gp, g1 = *(const float4*)(gp + 4);
    float4 b0 = *(const float4*)bp, b1 = *(const float4*)(bp + 4);
    float ga[8] = {g0.x, g0.y, g0.z, g0.w, g1.x, g1.y, g1.z, g1.w};
    float ba[8] = {b0.x, b0.y, b0.z, b0.w, b1.x, b1.y, b1.z, b1.w};
    float o8[8];
#pragma unroll
    for (int i = 0; i < 8; ++i) o8[i] = (r[i] - mean) * inv * ga[i] + ba[i];
    float* hw = h + (size_t)n * 512 + chOff;
    *(float4*)hw = make_float4(o8[0], o8[1], o8[2], o8[3]);
    *(float4*)(hw + 4) = make_float4(o8[4], o8[5], o8[6], o8[7]);
    uint4 ob;
    ob.x = f2bf2(o8[0], o8[1]);
    ob.y = f2bf2(o8[2], o8[3]);
    ob.z = f2bf2(o8[4], o8[5]);
    ob.w = f2bf2(o8[6], o8[7]);
    *(uint4*)(h_bf + (size_t)n * 512 + chOff) = ob;
}

// ---------------- pair bilinear scores (bf16 z,t) ----------------

__global__ __launch_bounds__(256) void k_pairscore(const short* __restrict__ z,
                                                   const short* __restrict__ t,
                                                   const int* __restrict__ pi,
                                                   const int* __restrict__ pj,
                                                   float* __restrict__ ssyn,
                                                   float* __restrict__ sant, int P) {
    int p = blockIdx.x * 4 + (threadIdx.x >> 6);
    if (p >= P) return;
    int lane = threadIdx.x & 63;
    int i = pi[p], j = pj[p];
    uint4 a = *(const uint4*)(t + (size_t)i * 1024 + lane * 8);
    uint4 b = *(const uint4*)(z + (size_t)j * 1024 + lane * 8);
    float2 a0 = bfp2(a.x), a1 = bfp2(a.y), a2 = bfp2(a.z), a3 = bfp2(a.w);
    float2 b0 = bfp2(b.x), b1 = bfp2(b.y), b2 = bfp2(b.z), b3 = bfp2(b.w);
    float ds = a0.x * b0.x + a0.y * b0.y + a1.x * b1.x + a1.y * b1.y +
               a2.x * b2.x + a2.y * b2.y + a3.x * b3.x + a3.y * b3.y;
    uint4 c = *(const uint4*)(t + (size_t)i * 1024 + 512 + lane * 8);
    uint4 d = *(const uint4*)(z + (size_t)j * 1024 + 512 + lane * 8);
    float2 c0 = bfp2(c.x), c1 = bfp2(c.y), c2 = bfp2(c.z), c3 = bfp2(c.w);
    float2 d0 = bfp2(d.x), d1 = bfp2(d.y), d2 = bfp2(d.z), d3 = bfp2(d.w);
    float da = c0.x * d0.x + c0.y * d0.y + c1.x * d1.x + c1.y * d1.y +
               c2.x * d2.x + c2.y * d2.y + c3.x * d3.x + c3.y * d3.y;
    for (int o = 32; o; o >>= 1) {
        ds += __shfl_xor(ds, o);
        da += __shfl_xor(da, o);
    }
    if (lane == 0) { ssyn[p] = ds; sant[p] = da; }
}

// ---------------- final elementwise combine ----------------

__global__ void k_final(const float* __restrict__ gpart, const float* __restrict__ gb2,
                        const float* __restrict__ ssyn, const float* __restrict__ sant,
                        float* __restrict__ out, int P) {
    int p = blockIdx.x * 256 + threadIdx.x;
    if (p < P) {
        float s = 1.0f / (1.0f + __expf(-(gpart[p] + gb2[0])));
        out[p] = s * sant[p] - (1.0f - s) * ssyn[p];
    }
}

// ---------------- host ----------------

extern "C" void kernel_launch(void* const* d_in, const int* in_sizes, int n_in,
                              void* d_out, int out_size, void* d_ws, size_t ws_size,
                              hipStream_t stream) {
    const float* x = (const float*)d_in[0];
    const int* ei = (const int*)d_in[1];
    const int* pe = (const int*)d_in[2];
    const float* mixer_W = (const float*)d_in[3];
    const float* mixer_b = (const float*)d_in[4];
    const float* Wq = (const float*)d_in[5];
    const float* bq = (const float*)d_in[6];
    const float* Wk = (const float*)d_in[7];
    const float* bk = (const float*)d_in[8];
    const float* Wv = (const float*)d_in[9];
    const float* bv = (const float*)d_in[10];
    const float* Ws = (const float*)d_in[11];
    const float* bs = (const float*)d_in[12];
    const float* ln_g = (const float*)d_in[13];
    const float* ln_b = (const float*)d_in[14];
    const float* syn_W = (const float*)d_in[15];
    const float* syn_b = (const float*)d_in[16];
    const float* ant_W = (const float*)d_in[17];
    const float* ant_b = (const float*)d_in[18];
    const float* W_syn = (const float*)d_in[19];
    const float* W_ant = (const float*)d_in[20];
    const float* gW1 = (const float*)d_in[21];
    const float* gb1 = (const float*)d_in[22];
    const float* gW2 = (const float*)d_in[23];
    const float* gb2 = (const float*)d_in[24];
    float* out = (float*)d_out;

    const int Nn = in_sizes[0] / 768;  // 20000
    const int E = in_sizes[1] / 2;     // 320000
    const int P = in_sizes[2] / 2;     // 100000

    char* w = (char*)d_ws;
    auto alloc = [&](size_t bytes) -> char* {
        char* p = w;
        w += (bytes + 255) & ~(size_t)255;
        return p;
    };
    float* h = (float*)alloc((size_t)Nn * 512 * 4);
    short* h_bf = (short*)alloc((size_t)Nn * 512 * 2);
    // union region U: during layers = qvs [Nn][1536] bf16 + k8 [Nn][512] fp8;
    // after layers = zB [Nn][1024] bf16 | tB [Nn][1024] bf16
    char* U = alloc((size_t)Nn * 2048 * 2);
    short* qvs = (short*)U;
    unsigned char* k8 = (unsigned char*)(U + (size_t)Nn * 1536 * 2);
    short* zB = (short*)U;
    short* tB = (short*)(U + (size_t)Nn * 1024 * 2);
    float* ssyn = (float*)alloc((size_t)P * 3 * 4);
    float* sant = ssyn + P;
    float* gpart = ssyn + 2 * P;
    int* srcS = (int*)alloc((size_t)E * 4);
    int* hist = (int*)alloc((size_t)Nn * 2 * 4);
    int* cursor = hist + Nn;
    int* offs = (int*)alloc((size_t)(Nn + 1) * 4);
    short* mixWt = (short*)alloc((size_t)512 * 768 * 2);
    short* wcat = (short*)alloc((size_t)L_LAYERS * 2048 * 512 * 2);
    short* dualWt = (short*)alloc((size_t)1024 * 512 * 2);
    short* bilWt = (short*)alloc((size_t)1024 * 512 * 2);
    short* gw1t = (short*)alloc((size_t)512 * 2048 * 2);
    float* bcat = (float*)alloc((size_t)L_LAYERS * 2048 * 4);
    float* bdual = (float*)alloc((size_t)1024 * 4);

    k_zero<<<(2 * Nn + 255) / 256, 256, 0, stream>>>(hist, 2 * Nn);
    k_hist<<<(E + 255) / 256, 256, 0, stream>>>(ei + E, hist, E);
    k_scan<<<1, 1024, 0, stream>>>(hist, offs, Nn);
    k_scatter<<<(E + 255) / 256, 256, 0, stream>>>(ei, ei + E, offs, cursor, srcS, E);

    k_wcat<<<(L_LAYERS * 2048 * 512) / 256, 256, 0, stream>>>(Wq, Wk, Wv, Ws, wcat);
    k_tr<<<dim3(3, 512), 256, 0, stream>>>(mixer_W, mixWt, 768, 512);
    k_tr<<<dim3(2, 512), 256, 0, stream>>>(syn_W, dualWt, 512, 512);
    k_tr<<<dim3(2, 512), 256, 0, stream>>>(ant_W, dualWt + 512 * 512, 512, 512);
    k_tr<<<dim3(2, 512), 256, 0, stream>>>(W_syn, bilWt, 512, 512);
    k_tr<<<dim3(2, 512), 256, 0, stream>>>(W_ant, bilWt + 512 * 512, 512, 512);
    k_tr<<<dim3(8, 512), 256, 0, stream>>>(gW1, gw1t, 2048, 512);
    k_bcat<<<48, 256, 0, stream>>>(bq, bk, bv, bs, bcat);
    k_bdual<<<4, 256, 0, stream>>>(syn_b, ant_b, bdual);

    const int mtiles = (Nn + 127) / 128;  // 157
    gemm_a32<<<dim3(mtiles, 4), 256, 0, stream>>>(x, 768, mixWt, mixer_b, h, h_bf, 512,
                                                  Nn, 512, 768, 1);

    for (int l = 0; l < L_LAYERS; ++l) {
        gemm_qkvs<<<dim3(mtiles, 16), 256, 0, stream>>>(h_bf, wcat + (size_t)l * 2048 * 512,
                                                        bcat + l * 2048, qvs, k8, Nn);
        k_attn<<<(Nn + 3) / 4, 256, 0, stream>>>(qvs, k8, srcS, offs, h, h_bf,
                                                 ln_g + l * 512, ln_b + l * 512, Nn);
    }

    gemm_bb<<<dim3(mtiles, 8), 256, 0, stream>>>(h_bf, 512, dualWt, bdual, zB, 1024,
                                                 Nn, 1024, 512, 1);
    gemm_bb<<<dim3(mtiles, 4), 256, 0, stream>>>(zB, 1024, bilWt, nullptr, tB, 1024,
                                                 Nn, 512, 512, 0);
    gemm_bb<<<dim3(mtiles, 4), 256, 0, stream>>>(zB + 512, 1024, bilWt + 512 * 512, nullptr,
                                                 tB + 512, 1024, Nn, 512, 512, 0);

    k_pairscore<<<(P + 3) / 4, 256, 0, stream>>>(zB, tB, pe, pe + P, ssyn, sant, P);

    k_zero<<<(P + 255) / 256, 256, 0, stream>>>((int*)gpart, P);
    gemm_gate<<<dim3((P + 63) / 64, 2), 256, 0, stream>>>(zB, pe, pe + P, P,
                                                          gw1t, gb1, gW2, gpart);
    k_final<<<(P + 255) / 256, 256, 0, stream>>>(gpart, gb2, ssyn, sant, out, P);
}

// Round 11
// 1875.083 us; speedup vs baseline: 1.2442x; 1.0069x over previous
//
#include <hip/hip_runtime.h>
#include <cstdint>

#define L_LAYERS 6

typedef __attribute__((ext_vector_type(8))) short bf16x8;
typedef __attribute__((ext_vector_type(4))) float f32x4;
typedef __attribute__((ext_vector_type(2))) float f32x2;

__device__ __forceinline__ float gelu1(float v) {
    return 0.5f * v * (1.0f + erff(v * 0.7071067811865475f));
}

__device__ __forceinline__ unsigned int f2bf2(float a, float b) {
    union { float f; unsigned u; } x, y;
    x.f = a; y.f = b;
    unsigned lo = (x.u + 0x7FFFu + ((x.u >> 16) & 1u)) >> 16;
    unsigned hi = (y.u + 0x7FFFu + ((y.u >> 16) & 1u)) & 0xFFFF0000u;
    return lo | hi;
}

__device__ __forceinline__ unsigned short f2bf1(float a) {
    union { float f; unsigned u; } x;
    x.f = a;
    return (unsigned short)((x.u + 0x7FFFu + ((x.u >> 16) & 1u)) >> 16);
}

__device__ __forceinline__ float2 bfp2(unsigned u) {
    union { unsigned u; float f; } a, b;
    a.u = u << 16;
    b.u = u & 0xFFFF0000u;
    return make_float2(a.f, b.f);
}

// async global->LDS, 16 bytes per lane (dest = wave-uniform base + lane*16)
__device__ __forceinline__ void gload16(const void* g, void* l) {
    __builtin_amdgcn_global_load_lds(
        (const __attribute__((address_space(1))) void*)g,
        (__attribute__((address_space(3))) void*)l, 16, 0, 0);
}

// ---------------- utility ----------------

__global__ void k_zero(int* __restrict__ p, int n) {
    int i = blockIdx.x * 256 + threadIdx.x;
    if (i < n) p[i] = 0;
}

// ---------------- edge sorting (counting sort by dst) ----------------

__global__ void k_hist(const int* __restrict__ dst, int* __restrict__ hist, int E) {
    int e = blockIdx.x * 256 + threadIdx.x;
    if (e < E) atomicAdd(&hist[dst[e]], 1);
}

__global__ __launch_bounds__(1024) void k_scan(const int* __restrict__ hist,
                                               int* __restrict__ off, int n) {
    __shared__ int buf[1024];
    __shared__ int carry;
    int tid = threadIdx.x;
    if (tid == 0) carry = 0;
    __syncthreads();
    for (int base = 0; base < n; base += 1024) {
        int v = (base + tid < n) ? hist[base + tid] : 0;
        buf[tid] = v;
        __syncthreads();
        int x = v;
        for (int o = 1; o < 1024; o <<= 1) {
            int t = (tid >= o) ? buf[tid - o] : 0;
            __syncthreads();
            x += t;
            buf[tid] = x;
            __syncthreads();
        }
        int c = carry;
        if (base + tid < n) off[base + tid] = c + x - v;   // exclusive
        __syncthreads();
        if (tid == 1023) carry = c + buf[1023];
        __syncthreads();
    }
    if (tid == 0) off[n] = carry;
}

__global__ void k_scatter(const int* __restrict__ src, const int* __restrict__ dst,
                          const int* __restrict__ off, int* __restrict__ cursor,
                          int* __restrict__ srcS, int E) {
    int e = blockIdx.x * 256 + threadIdx.x;
    if (e < E) {
        int d = dst[e];
        int pos = off[d] + atomicAdd(&cursor[d], 1);
        srcS[pos] = src[e];
    }
}

// ---------------- weight prep (transpose + cvt to bf16) ----------------

__global__ void k_wcat(const float* __restrict__ Wq, const float* __restrict__ Wk,
                       const float* __restrict__ Wv, const float* __restrict__ Ws,
                       short* __restrict__ Wt) {
    int idx = blockIdx.x * 256 + threadIdx.x;   // l*2^20 + n*512 + k
    int k = idx & 511;
    int nf = (idx >> 9) & 2047;
    int l = idx >> 20;
    int sel = nf >> 9, nn = nf & 511;
    const float* W = (sel == 0) ? Wq : (sel == 1) ? Wk : (sel == 2) ? Wv : Ws;
    float v = W[((size_t)l * 512 + k) * 512 + nn];
    Wt[idx] = (short)f2bf1(v);
}

__global__ void k_tr(const float* __restrict__ W, short* __restrict__ Wt, int K, int N) {
    int k = blockIdx.x * 256 + threadIdx.x;
    int n = blockIdx.y;
    if (k < K) Wt[(size_t)n * K + k] = (short)f2bf1(W[(size_t)k * N + n]);
}

__global__ void k_bcat(const float* __restrict__ bq, const float* __restrict__ bk,
                       const float* __restrict__ bv, const float* __restrict__ bs,
                       float* __restrict__ bcat) {
    int idx = blockIdx.x * 256 + threadIdx.x;
    if (idx >= L_LAYERS * 2048) return;
    int l = idx >> 11, n = idx & 2047;
    int sel = n >> 9, nn = n & 511;
    const float* b = (sel == 0) ? bq : (sel == 1) ? bk : (sel == 2) ? bv : bs;
    bcat[idx] = b[l * 512 + nn];
}

__global__ void k_bdual(const float* __restrict__ sb, const float* __restrict__ ab,
                        float* __restrict__ bd) {
    int idx = blockIdx.x * 256 + threadIdx.x;
    if (idx < 1024) bd[idx] = (idx < 512) ? sb[idx] : ab[idx - 512];
}

// ---------------- GEMM: A fp32 (mixer only) ----------------

__global__ __launch_bounds__(256) void gemm_a32(
    const float* __restrict__ A, int lda,
    const short* __restrict__ Bt,
    const float* __restrict__ bias,
    float* __restrict__ Cf, short* __restrict__ Cbf, int ldc,
    int M, int N, int K, int act) {
    __shared__ __align__(16) short As[128][40];
    __shared__ __align__(16) short Bs[128][40];
    const int tid = threadIdx.x;
    const int lane = tid & 63;
    const int wave = tid >> 6;
    const int wr = (wave >> 1) * 64;
    const int wc = (wave & 1) * 64;
    const int l16 = lane & 15;
    const int quad = lane >> 4;
    const int row0 = blockIdx.x * 128;
    const int col0 = blockIdx.y * 128;
    const int sr = tid >> 2;
    const int sk = (tid & 3) * 8;

    f32x4 acc[4][4];
#pragma unroll
    for (int i = 0; i < 4; ++i)
#pragma unroll
        for (int j = 0; j < 4; ++j)
            acc[i][j] = f32x4{0.f, 0.f, 0.f, 0.f};

    for (int kb = 0; kb < K; kb += 32) {
#pragma unroll
        for (int hh = 0; hh < 2; ++hh) {
            int r = sr + hh * 64;
            int gr = row0 + r;
            float4 a0, a1;
            if (gr < M) {
                const float* p = A + (size_t)gr * lda + kb + sk;
                a0 = *(const float4*)p;
                a1 = *(const float4*)(p + 4);
            } else {
                a0 = make_float4(0.f, 0.f, 0.f, 0.f);
                a1 = make_float4(0.f, 0.f, 0.f, 0.f);
            }
            uint4 av;
            av.x = f2bf2(a0.x, a0.y);
            av.y = f2bf2(a0.z, a0.w);
            av.z = f2bf2(a1.x, a1.y);
            av.w = f2bf2(a1.z, a1.w);
            *(uint4*)&As[r][sk] = av;
            const short* bp = Bt + (size_t)(col0 + r) * K + kb + sk;
            *(uint4*)&Bs[r][sk] = *(const uint4*)bp;
        }
        __syncthreads();
        bf16x8 af[4], bfr[4];
#pragma unroll
        for (int i = 0; i < 4; ++i)
            af[i] = *(const bf16x8*)&As[wr + i * 16 + l16][quad * 8];
#pragma unroll
        for (int j = 0; j < 4; ++j)
            bfr[j] = *(const bf16x8*)&Bs[wc + j * 16 + l16][quad * 8];
#pragma unroll
        for (int i = 0; i < 4; ++i)
#pragma unroll
            for (int j = 0; j < 4; ++j)
                acc[i][j] = __builtin_amdgcn_mfma_f32_16x16x32_bf16(af[i], bfr[j], acc[i][j], 0, 0, 0);
        __syncthreads();
    }
#pragma unroll
    for (int i = 0; i < 4; ++i) {
        int rbase = row0 + wr + i * 16 + quad * 4;
#pragma unroll
        for (int j = 0; j < 4; ++j) {
            int c = col0 + wc + j * 16 + l16;
            float bv = bias ? bias[c] : 0.0f;
#pragma unroll
            for (int rg = 0; rg < 4; ++rg) {
                int gr = rbase + rg;
                if (gr < M) {
                    float v = acc[i][j][rg] + bv;
                    if (act) v = gelu1(v);
                    Cf[(size_t)gr * ldc + c] = v;
                    if (Cbf) Cbf[(size_t)gr * ldc + c] = (short)f2bf1(v);
                }
            }
        }
    }
}

// ---------------- GEMM: A bf16, B bf16, m97-style global_load_lds staging ----------------
// Optional C8: also write fp8 e4m3 copy (row stride ldc).

__global__ __launch_bounds__(256) void gemm_bb(
    const short* __restrict__ A, int lda,
    const short* __restrict__ Bt,
    const float* __restrict__ bias,
    short* __restrict__ C, unsigned char* __restrict__ C8, int ldc,
    int M, int N, int K, int act) {
    __shared__ __align__(16) short As[128 * 32];
    __shared__ __align__(16) short Bs[128 * 32];
    const int tid = threadIdx.x;
    const int lane = tid & 63;
    const int wave = tid >> 6;
    const int wr = (wave >> 1) * 64;
    const int wc = (wave & 1) * 64;
    const int l16 = lane & 15;
    const int quad = lane >> 4;
    const int row0 = blockIdx.x * 128;
    const int col0 = blockIdx.y * 128;
    const int c0 = tid, c1 = tid + 256;
    const int r0 = c0 >> 2, kq0 = (c0 & 3) * 8;
    const int r1 = c1 >> 2, kq1 = (c1 & 3) * 8;
    int ga0 = row0 + r0; if (ga0 >= M) ga0 = M - 1;
    int ga1 = row0 + r1; if (ga1 >= M) ga1 = M - 1;
    const short* Ap0 = A + (size_t)ga0 * lda + kq0;
    const short* Ap1 = A + (size_t)ga1 * lda + kq1;
    const short* Bp0 = Bt + (size_t)(col0 + r0) * K + kq0;
    const short* Bp1 = Bt + (size_t)(col0 + r1) * K + kq1;

    f32x4 acc[4][4];
#pragma unroll
    for (int i = 0; i < 4; ++i)
#pragma unroll
        for (int j = 0; j < 4; ++j)
            acc[i][j] = f32x4{0.f, 0.f, 0.f, 0.f};

    for (int kb = 0; kb < K; kb += 32) {
        gload16(Ap0 + kb, &As[c0 * 8]);
        gload16(Ap1 + kb, &As[c1 * 8]);
        gload16(Bp0 + kb, &Bs[c0 * 8]);
        gload16(Bp1 + kb, &Bs[c1 * 8]);
        __syncthreads();
        bf16x8 af[4], bfr[4];
#pragma unroll
        for (int i = 0; i < 4; ++i)
            af[i] = *(const bf16x8*)&As[(wr + i * 16 + l16) * 32 + quad * 8];
#pragma unroll
        for (int j = 0; j < 4; ++j)
            bfr[j] = *(const bf16x8*)&Bs[(wc + j * 16 + l16) * 32 + quad * 8];
#pragma unroll
        for (int i = 0; i < 4; ++i)
#pragma unroll
            for (int j = 0; j < 4; ++j)
                acc[i][j] = __builtin_amdgcn_mfma_f32_16x16x32_bf16(af[i], bfr[j], acc[i][j], 0, 0, 0);
        __syncthreads();
    }
#pragma unroll
    for (int i = 0; i < 4; ++i) {
        int rbase = row0 + wr + i * 16 + quad * 4;
#pragma unroll
        for (int j = 0; j < 4; ++j) {
            int c = col0 + wc + j * 16 + l16;
            float bv = bias ? bias[c] : 0.0f;
#pragma unroll
            for (int rg = 0; rg < 4; ++rg) {
                int gr = rbase + rg;
                if (gr < M) {
                    float v = acc[i][j][rg] + bv;
                    if (act) v = gelu1(v);
                    C[(size_t)gr * ldc + c] = (short)f2bf1(v);
                    if (C8) {
                        int r8 = __builtin_amdgcn_cvt_pk_fp8_f32(v, v, 0, false);
                        C8[(size_t)gr * ldc + c] = (unsigned char)(r8 & 0xFF);
                    }
                }
            }
        }
    }
}

// ---------------- qkv GEMM with split-layout epilogue ----------------
// Output cols: [0,512) q -> qvs+0 ; [512,1024) k -> k8 (fp8 e4m3) ;
// [1024,1536) v -> qvs+512 ; [1536,2048) s -> qvs+1024. qvs row stride 1536.

__global__ __launch_bounds__(256) void gemm_qkvs(
    const short* __restrict__ A,      // h_bf [M][512]
    const short* __restrict__ Bt,     // layer weights [2048][512]
    const float* __restrict__ bias,   // [2048]
    short* __restrict__ qvs,          // [M][1536] bf16
    unsigned char* __restrict__ k8,   // [M][512] fp8
    int M) {
    const int K = 512;
    __shared__ __align__(16) short As[128 * 32];
    __shared__ __align__(16) short Bs[128 * 32];
    const int tid = threadIdx.x;
    const int lane = tid & 63;
    const int wave = tid >> 6;
    const int wr = (wave >> 1) * 64;
    const int wc = (wave & 1) * 64;
    const int l16 = lane & 15;
    const int quad = lane >> 4;
    const int row0 = blockIdx.x * 128;
    const int col0 = blockIdx.y * 128;
    const int c0 = tid, c1 = tid + 256;
    const int r0 = c0 >> 2, kq0 = (c0 & 3) * 8;
    const int r1 = c1 >> 2, kq1 = (c1 & 3) * 8;
    int ga0 = row0 + r0; if (ga0 >= M) ga0 = M - 1;
    int ga1 = row0 + r1; if (ga1 >= M) ga1 = M - 1;
    const short* Ap0 = A + (size_t)ga0 * K + kq0;
    const short* Ap1 = A + (size_t)ga1 * K + kq1;
    const short* Bp0 = Bt + (size_t)(col0 + r0) * K + kq0;
    const short* Bp1 = Bt + (size_t)(col0 + r1) * K + kq1;

    f32x4 acc[4][4];
#pragma unroll
    for (int i = 0; i < 4; ++i)
#pragma unroll
        for (int j = 0; j < 4; ++j)
            acc[i][j] = f32x4{0.f, 0.f, 0.f, 0.f};

    for (int kb = 0; kb < K; kb += 32) {
        gload16(Ap0 + kb, &As[c0 * 8]);
        gload16(Ap1 + kb, &As[c1 * 8]);
        gload16(Bp0 + kb, &Bs[c0 * 8]);
        gload16(Bp1 + kb, &Bs[c1 * 8]);
        __syncthreads();
        bf16x8 af[4], bfr[4];
#pragma unroll
        for (int i = 0; i < 4; ++i)
            af[i] = *(const bf16x8*)&As[(wr + i * 16 + l16) * 32 + quad * 8];
#pragma unroll
        for (int j = 0; j < 4; ++j)
            bfr[j] = *(const bf16x8*)&Bs[(wc + j * 16 + l16) * 32 + quad * 8];
#pragma unroll
        for (int i = 0; i < 4; ++i)
#pragma unroll
            for (int j = 0; j < 4; ++j)
                acc[i][j] = __builtin_amdgcn_mfma_f32_16x16x32_bf16(af[i], bfr[j], acc[i][j], 0, 0, 0);
        __syncthreads();
    }
#pragma unroll
    for (int i = 0; i < 4; ++i) {
        int rbase = row0 + wr + i * 16 + quad * 4;
#pragma unroll
        for (int j = 0; j < 4; ++j) {
            int c = col0 + wc + j * 16 + l16;
            int sec = c >> 9;           // uniform within a 64-col wave tile
            int cc = c & 511;
            float bv = bias[c];
#pragma unroll
            for (int rg = 0; rg < 4; ++rg) {
                int gr = rbase + rg;
                if (gr < M) {
                    float v = acc[i][j][rg] + bv;
                    if (sec == 1) {
                        int r8 = __builtin_amdgcn_cvt_pk_fp8_f32(v, v, 0, false);
                        k8[(size_t)gr * 512 + cc] = (unsigned char)(r8 & 0xFF);
                    } else {
                        int off = (sec == 0) ? cc : ((sec == 2) ? 512 + cc : 1024 + cc);
                        qvs[(size_t)gr * 1536 + off] = (short)f2bf1(v);
                    }
                }
            }
        }
    }
}

// ---------------- fused gate GEMM: fp8 z gather (pairing trick, async B) ----------------

__global__ __launch_bounds__(256, 3) void gemm_gate(
    const unsigned char* __restrict__ z8,   // [Nn][1024] fp8
    const int* __restrict__ pi, const int* __restrict__ pj, int P,
    const short* __restrict__ Bt,    // gW1^T [512][2048]
    const float* __restrict__ gb1,
    const float* __restrict__ gW2,
    float* __restrict__ gpart) {
    __shared__ __align__(16) short Aab[64 * 32];
    __shared__ __align__(16) short Amu[64 * 32];
    __shared__ __align__(16) short Bab[256 * 32];
    __shared__ __align__(16) short Bmu[256 * 32];
    __shared__ int iArr[64];
    __shared__ int jArr[64];
    __shared__ float rowsum[64];
    const int tid = threadIdx.x;
    const int lane = tid & 63;
    const int wave = tid >> 6;
    const int wc = wave * 64;
    const int l16 = lane & 15;
    const int quad = lane >> 4;
    const int row0 = blockIdx.x * 64;
    const int col0 = blockIdx.y * 256;
    const int sr = tid >> 2;        // 0..63
    const int sk = (tid & 3) * 8;   // channel == byte offset for fp8

    if (tid < 64) {
        int p = row0 + tid;
        int ok = (p < P);
        iArr[tid] = ok ? pi[p] : 0;
        jArr[tid] = ok ? pj[p] : 0;
        rowsum[tid] = 0.0f;
    }
    __syncthreads();
    const unsigned char* zi = z8 + (size_t)iArr[sr] * 1024 + sk;
    const unsigned char* zj = z8 + (size_t)jArr[sr] * 1024 + sk;
    const short* bp0 = Bt + (size_t)(col0 + sr) * 2048 + sk;

    f32x4 acc[4][4];
#pragma unroll
    for (int i = 0; i < 4; ++i)
#pragma unroll
        for (int j = 0; j < 4; ++j)
            acc[i][j] = f32x4{0.f, 0.f, 0.f, 0.f};

    for (int part = 0; part < 2; ++part) {
        for (int c = 0; c < 512; c += 32) {
            const short* bp = bp0 + part * 1024 + c;
#pragma unroll
            for (int hh = 0; hh < 4; ++hh) {
                const short* q = bp + (size_t)hh * 64 * 2048;
                gload16(q, &Bab[hh * 2048 + tid * 8]);
                gload16(q + 512, &Bmu[hh * 2048 + tid * 8]);
            }
            uint2 xu = *(const uint2*)(zi + part * 512 + c);
            uint2 yu = *(const uint2*)(zj + part * 512 + c);
            f32x2 x0 = __builtin_amdgcn_cvt_pk_f32_fp8((int)xu.x, false);
            f32x2 x1 = __builtin_amdgcn_cvt_pk_f32_fp8((int)xu.x, true);
            f32x2 x2 = __builtin_amdgcn_cvt_pk_f32_fp8((int)xu.y, false);
            f32x2 x3 = __builtin_amdgcn_cvt_pk_f32_fp8((int)xu.y, true);
            f32x2 y0 = __builtin_amdgcn_cvt_pk_f32_fp8((int)yu.x, false);
            f32x2 y1 = __builtin_amdgcn_cvt_pk_f32_fp8((int)yu.x, true);
            f32x2 y2 = __builtin_amdgcn_cvt_pk_f32_fp8((int)yu.y, false);
            f32x2 y3 = __builtin_amdgcn_cvt_pk_f32_fp8((int)yu.y, true);
            uint4 aa, am;
            aa.x = f2bf2(fabsf(x0.x - y0.x), fabsf(x0.y - y0.y));
            aa.y = f2bf2(fabsf(x1.x - y1.x), fabsf(x1.y - y1.y));
            aa.z = f2bf2(fabsf(x2.x - y2.x), fabsf(x2.y - y2.y));
            aa.w = f2bf2(fabsf(x3.x - y3.x), fabsf(x3.y - y3.y));
            am.x = f2bf2(x0.x * y0.x, x0.y * y0.y);
            am.y = f2bf2(x1.x * y1.x, x1.y * y1.y);
            am.z = f2bf2(x2.x * y2.x, x2.y * y2.y);
            am.w = f2bf2(x3.x * y3.x, x3.y * y3.y);
            *(uint4*)&Aab[tid * 8] = aa;
            *(uint4*)&Amu[tid * 8] = am;
            __syncthreads();
            bf16x8 af[4];
#pragma unroll
            for (int i = 0; i < 4; ++i)
                af[i] = *(const bf16x8*)&Aab[(i * 16 + l16) * 32 + quad * 8];
#pragma unroll
            for (int j = 0; j < 4; ++j) {
                bf16x8 bf = *(const bf16x8*)&Bab[(wc + j * 16 + l16) * 32 + quad * 8];
#pragma unroll
                for (int i = 0; i < 4; ++i)
                    acc[i][j] = __builtin_amdgcn_mfma_f32_16x16x32_bf16(af[i], bf, acc[i][j], 0, 0, 0);
            }
#pragma unroll
            for (int i = 0; i < 4; ++i)
                af[i] = *(const bf16x8*)&Amu[(i * 16 + l16) * 32 + quad * 8];
#pragma unroll
            for (int j = 0; j < 4; ++j) {
                bf16x8 bf = *(const bf16x8*)&Bmu[(wc + j * 16 + l16) * 32 + quad * 8];
#pragma unroll
                for (int i = 0; i < 4; ++i)
                    acc[i][j] = __builtin_amdgcn_mfma_f32_16x16x32_bf16(af[i], bf, acc[i][j], 0, 0, 0);
            }
            __syncthreads();
        }
    }
#pragma unroll
    for (int i = 0; i < 4; ++i) {
#pragma unroll
        for (int rg = 0; rg < 4; ++rg) {
            float partial = 0.f;
#pragma unroll
            for (int j = 0; j < 4; ++j) {
                int cc = col0 + wc + j * 16 + l16;
                partial += gelu1(acc[i][j][rg] + gb1[cc]) * gW2[cc];
            }
            partial += __shfl_xor(partial, 1);
            partial += __shfl_xor(partial, 2);
            partial += __shfl_xor(partial, 4);
            partial += __shfl_xor(partial, 8);
            if (l16 == 0)
                atomicAdd(&rowsum[i * 16 + quad * 4 + rg], partial);
        }
    }
    __syncthreads();
    if (tid < 64 && (row0 + tid) < P)
        atomicAdd(&gpart[row0 + tid], rowsum[tid]);
}

// ---------------- fused per-layer attention: single-pass, fp8 k gather -------------

__global__ __launch_bounds__(256) void k_attn(const short* __restrict__ qvs,
                                              const unsigned char* __restrict__ k8,
                                              const int* __restrict__ srcS,
                                              const int* __restrict__ offs,
                                              float* __restrict__ h,
                                              short* __restrict__ h_bf,
                                              const float* __restrict__ lng,
                                              const float* __restrict__ lnb, int Nn) {
    const int tid = threadIdx.x;
    const int lane = tid & 63;
    const int wv = tid >> 6;
    const int n = blockIdx.x * 4 + wv;
    if (n >= Nn) return;
    const int st = offs[n], en = offs[n + 1];
    const size_t chOff = (size_t)lane * 8;

    uint4 qv = *(const uint4*)(qvs + (size_t)n * 1536 + chOff);
    float2 q0 = bfp2(qv.x), q1 = bfp2(qv.y), q2 = bfp2(qv.z), q3 = bfp2(qv.w);
    float acc[8];
#pragma unroll
    for (int i = 0; i < 8; ++i) acc[i] = 0.f;
    float m_l = -3.4e38f, l_l = 0.f;

    for (int e0 = st; e0 < en; e0 += 64) {
        int cnt = min(64, en - e0);
        int myS = (lane < cnt) ? srcS[e0 + lane] : 0;
        for (int ei = 0; ei < cnt; ++ei) {
            int s = __shfl(myS, ei);
            uint2 kq = *(const uint2*)(k8 + (size_t)s * 512 + chOff);
            uint4 vv = *(const uint4*)(qvs + (size_t)s * 1536 + 512 + chOff);
            f32x2 k0 = __builtin_amdgcn_cvt_pk_f32_fp8((int)kq.x, false);
            f32x2 k1 = __builtin_amdgcn_cvt_pk_f32_fp8((int)kq.x, true);
            f32x2 k2 = __builtin_amdgcn_cvt_pk_f32_fp8((int)kq.y, false);
            f32x2 k3 = __builtin_amdgcn_cvt_pk_f32_fp8((int)kq.y, true);
            float d = q0.x * k0.x + q0.y * k0.y + q1.x * k1.x + q1.y * k1.y +
                      q2.x * k2.x + q2.y * k2.y + q3.x * k3.x + q3.y * k3.y;
            d += __shfl_xor(d, 1);
            d += __shfl_xor(d, 2);
            d += __shfl_xor(d, 4);
            d += __shfl_xor(d, 8);
            float lg = d * 0.08838834764831845f;
            float m_new = fmaxf(m_l, lg);
            float sc = __expf(m_l - m_new);
            float p = __expf(lg - m_new);
            l_l = l_l * sc + p;
            m_l = m_new;
            float2 v0 = bfp2(vv.x), v1 = bfp2(vv.y), v2 = bfp2(vv.z), v3 = bfp2(vv.w);
            acc[0] = acc[0] * sc + p * v0.x; acc[1] = acc[1] * sc + p * v0.y;
            acc[2] = acc[2] * sc + p * v1.x; acc[3] = acc[3] * sc + p * v1.y;
            acc[4] = acc[4] * sc + p * v2.x; acc[5] = acc[5] * sc + p * v2.y;
            acc[6] = acc[6] * sc + p * v3.x; acc[7] = acc[7] * sc + p * v3.y;
        }
    }
    float rinv = (en > st) ? 1.0f / l_l : 0.f;
    uint4 su = *(const uint4*)(qvs + (size_t)n * 1536 + 1024 + chOff);
    float2 s0 = bfp2(su.x), s1 = bfp2(su.y), s2 = bfp2(su.z), s3 = bfp2(su.w);
    float sv[8] = {s0.x, s0.y, s1.x, s1.y, s2.x, s2.y, s3.x, s3.y};
    const float* hp = h + (size_t)n * 512 + chOff;
    float4 h0 = *(const float4*)hp;
    float4 h1 = *(const float4*)(hp + 4);
    float hv[8] = {h0.x, h0.y, h0.z, h0.w, h1.x, h1.y, h1.z, h1.w};
    float r[8];
    float sum = 0.f, ssq = 0.f;
#pragma unroll
    for (int i = 0; i < 8; ++i) {
        r[i] = hv[i] + gelu1(acc[i] * rinv + sv[i]);
        sum += r[i];
        ssq += r[i] * r[i];
    }
    for (int o = 32; o; o >>= 1) {
        sum += __shfl_xor(sum, o);
        ssq += __shfl_xor(ssq, o);
    }
    float mean = sum * (1.0f / 512.0f);
    float var = ssq * (1.0f / 512.0f) - mean * mean;
    float inv = rsqrtf(var + 1e-5f);
    const float* gp = lng + chOff;
    const float* bp = lnb + chOff;
    float4 g0 = *(const float4*)gp, g1 = *(const float4*)(gp + 4);
    float4 b0 = *(const float4*)bp, b1 = *(const float4*)(bp + 4);
    float ga[8] = {g0.x, g0.y, g0.z, g0.w, g1.x, g1.y, g1.z, g1.w};
    float ba[8] = {b0.x, b0.y, b0.z, b0.w, b1.x, b1.y, b1.z, b1.w};
    float o8[8];
#pragma unroll
    for (int i = 0; i < 8; ++i) o8[i] = (r[i] - mean) * inv * ga[i] + ba[i];
    float* hw = h + (size_t)n * 512 + chOff;
    *(float4*)hw = make_float4(o8[0], o8[1], o8[2], o8[3]);
    *(float4*)(hw + 4) = make_float4(o8[4], o8[5], o8[6], o8[7]);
    uint4 ob;
    ob.x = f2bf2(o8[0], o8[1]);
    ob.y = f2bf2(o8[2], o8[3]);
    ob.z = f2bf2(o8[4], o8[5]);
    ob.w = f2bf2(o8[6], o8[7]);
    *(uint4*)(h_bf + (size_t)n * 512 + chOff) = ob;
}

// ---------------- pair bilinear scores (bf16 z,t) ----------------

__global__ __launch_bounds__(256) void k_pairscore(const short* __restrict__ z,
                                                   const short* __restrict__ t,
                                                   const int* __restrict__ pi,
                                                   const int* __restrict__ pj,
                                                   float* __restrict__ ssyn,
                                                   float* __restrict__ sant, int P) {
    int p = blockIdx.x * 4 + (threadIdx.x >> 6);
    if (p >= P) return;
    int lane = threadIdx.x & 63;
    int i = pi[p], j = pj[p];
    uint4 a = *(const uint4*)(t + (size_t)i * 1024 + lane * 8);
    uint4 b = *(const uint4*)(z + (size_t)j * 1024 + lane * 8);
    float2 a0 = bfp2(a.x), a1 = bfp2(a.y), a2 = bfp2(a.z), a3 = bfp2(a.w);
    float2 b0 = bfp2(b.x), b1 = bfp2(b.y), b2 = bfp2(b.z), b3 = bfp2(b.w);
    float ds = a0.x * b0.x + a0.y * b0.y + a1.x * b1.x + a1.y * b1.y +
               a2.x * b2.x + a2.y * b2.y + a3.x * b3.x + a3.y * b3.y;
    uint4 c = *(const uint4*)(t + (size_t)i * 1024 + 512 + lane * 8);
    uint4 d = *(const uint4*)(z + (size_t)j * 1024 + 512 + lane * 8);
    float2 c0 = bfp2(c.x), c1 = bfp2(c.y), c2 = bfp2(c.z), c3 = bfp2(c.w);
    float2 d0 = bfp2(d.x), d1 = bfp2(d.y), d2 = bfp2(d.z), d3 = bfp2(d.w);
    float da = c0.x * d0.x + c0.y * d0.y + c1.x * d1.x + c1.y * d1.y +
               c2.x * d2.x + c2.y * d2.y + c3.x * d3.x + c3.y * d3.y;
    for (int o = 32; o; o >>= 1) {
        ds += __shfl_xor(ds, o);
        da += __shfl_xor(da, o);
    }
    if (lane == 0) { ssyn[p] = ds; sant[p] = da; }
}

// ---------------- final elementwise combine ----------------

__global__ void k_final(const float* __restrict__ gpart, const float* __restrict__ gb2,
                        const float* __restrict__ ssyn, const float* __restrict__ sant,
                        float* __restrict__ out, int P) {
    int p = blockIdx.x * 256 + threadIdx.x;
    if (p < P) {
        float s = 1.0f / (1.0f + __expf(-(gpart[p] + gb2[0])));
        out[p] = s * sant[p] - (1.0f - s) * ssyn[p];
    }
}

// ---------------- host ----------------

extern "C" void kernel_launch(void* const* d_in, const int* in_sizes, int n_in,
                              void* d_out, int out_size, void* d_ws, size_t ws_size,
                              hipStream_t stream) {
    const float* x = (const float*)d_in[0];
    const int* ei = (const int*)d_in[1];
    const int* pe = (const int*)d_in[2];
    const float* mixer_W = (const float*)d_in[3];
    const float* mixer_b = (const float*)d_in[4];
    const float* Wq = (const float*)d_in[5];
    const float* bq = (const float*)d_in[6];
    const float* Wk = (const float*)d_in[7];
    const float* bk = (const float*)d_in[8];
    const float* Wv = (const float*)d_in[9];
    const float* bv = (const float*)d_in[10];
    const float* Ws = (const float*)d_in[11];
    const float* bs = (const float*)d_in[12];
    const float* ln_g = (const float*)d_in[13];
    const float* ln_b = (const float*)d_in[14];
    const float* syn_W = (const float*)d_in[15];
    const float* syn_b = (const float*)d_in[16];
    const float* ant_W = (const float*)d_in[17];
    const float* ant_b = (const float*)d_in[18];
    const float* W_syn = (const float*)d_in[19];
    const float* W_ant = (const float*)d_in[20];
    const float* gW1 = (const float*)d_in[21];
    const float* gb1 = (const float*)d_in[22];
    const float* gW2 = (const float*)d_in[23];
    const float* gb2 = (const float*)d_in[24];
    float* out = (float*)d_out;

    const int Nn = in_sizes[0] / 768;  // 20000
    const int E = in_sizes[1] / 2;     // 320000
    const int P = in_sizes[2] / 2;     // 100000

    char* w = (char*)d_ws;
    auto alloc = [&](size_t bytes) -> char* {
        char* p = w;
        w += (bytes + 255) & ~(size_t)255;
        return p;
    };
    float* h = (float*)alloc((size_t)Nn * 512 * 4);
    short* h_bf = (short*)alloc((size_t)Nn * 512 * 2);
    // union region U: during layers = qvs [Nn][1536] bf16 + k8 [Nn][512] fp8;
    // after layers = zB [Nn][1024] bf16 | tB [Nn][1024] bf16
    char* U = alloc((size_t)Nn * 2048 * 2);
    short* qvs = (short*)U;
    unsigned char* k8 = (unsigned char*)(U + (size_t)Nn * 1536 * 2);
    short* zB = (short*)U;
    short* tB = (short*)(U + (size_t)Nn * 1024 * 2);
    unsigned char* z8 = (unsigned char*)alloc((size_t)Nn * 1024);   // fp8 z copy, 20 MB
    float* ssyn = (float*)alloc((size_t)P * 3 * 4);
    float* sant = ssyn + P;
    float* gpart = ssyn + 2 * P;
    int* srcS = (int*)alloc((size_t)E * 4);
    int* hist = (int*)alloc((size_t)Nn * 2 * 4);
    int* cursor = hist + Nn;
    int* offs = (int*)alloc((size_t)(Nn + 1) * 4);
    short* mixWt = (short*)alloc((size_t)512 * 768 * 2);
    short* wcat = (short*)alloc((size_t)L_LAYERS * 2048 * 512 * 2);
    short* dualWt = (short*)alloc((size_t)1024 * 512 * 2);
    short* bilWt = (short*)alloc((size_t)1024 * 512 * 2);
    short* gw1t = (short*)alloc((size_t)512 * 2048 * 2);
    float* bcat = (float*)alloc((size_t)L_LAYERS * 2048 * 4);
    float* bdual = (float*)alloc((size_t)1024 * 4);

    k_zero<<<(2 * Nn + 255) / 256, 256, 0, stream>>>(hist, 2 * Nn);
    k_hist<<<(E + 255) / 256, 256, 0, stream>>>(ei + E, hist, E);
    k_scan<<<1, 1024, 0, stream>>>(hist, offs, Nn);
    k_scatter<<<(E + 255) / 256, 256, 0, stream>>>(ei, ei + E, offs, cursor, srcS, E);

    k_wcat<<<(L_LAYERS * 2048 * 512) / 256, 256, 0, stream>>>(Wq, Wk, Wv, Ws, wcat);
    k_tr<<<dim3(3, 512), 256, 0, stream>>>(mixer_W, mixWt, 768, 512);
    k_tr<<<dim3(2, 512), 256, 0, stream>>>(syn_W, dualWt, 512, 512);
    k_tr<<<dim3(2, 512), 256, 0, stream>>>(ant_W, dualWt + 512 * 512, 512, 512);
    k_tr<<<dim3(2, 512), 256, 0, stream>>>(W_syn, bilWt, 512, 512);
    k_tr<<<dim3(2, 512), 256, 0, stream>>>(W_ant, bilWt + 512 * 512, 512, 512);
    k_tr<<<dim3(8, 512), 256, 0, stream>>>(gW1, gw1t, 2048, 512);
    k_bcat<<<48, 256, 0, stream>>>(bq, bk, bv, bs, bcat);
    k_bdual<<<4, 256, 0, stream>>>(syn_b, ant_b, bdual);

    const int mtiles = (Nn + 127) / 128;  // 157
    gemm_a32<<<dim3(mtiles, 4), 256, 0, stream>>>(x, 768, mixWt, mixer_b, h, h_bf, 512,
                                                  Nn, 512, 768, 1);

    for (int l = 0; l < L_LAYERS; ++l) {
        gemm_qkvs<<<dim3(mtiles, 16), 256, 0, stream>>>(h_bf, wcat + (size_t)l * 2048 * 512,
                                                        bcat + l * 2048, qvs, k8, Nn);
        k_attn<<<(Nn + 3) / 4, 256, 0, stream>>>(qvs, k8, srcS, offs, h, h_bf,
                                                 ln_g + l * 512, ln_b + l * 512, Nn);
    }

    // z = gelu(h @ [syn_W|ant_W] + b) -> zB bf16 + z8 fp8
    gemm_bb<<<dim3(mtiles, 8), 256, 0, stream>>>(h_bf, 512, dualWt, bdual, zB, z8, 1024,
                                                 Nn, 1024, 512, 1);
    gemm_bb<<<dim3(mtiles, 4), 256, 0, stream>>>(zB, 1024, bilWt, nullptr, tB, nullptr, 1024,
                                                 Nn, 512, 512, 0);
    gemm_bb<<<dim3(mtiles, 4), 256, 0, stream>>>(zB + 512, 1024, bilWt + 512 * 512, nullptr,
                                                 tB + 512, nullptr, 1024, Nn, 512, 512, 0);

    k_pairscore<<<(P + 3) / 4, 256, 0, stream>>>(zB, tB, pe, pe + P, ssyn, sant, P);

    k_zero<<<(P + 255) / 256, 256, 0, stream>>>((int*)gpart, P);
    gemm_gate<<<dim3((P + 63) / 64, 2), 256, 0, stream>>>(z8, pe, pe + P, P,
                                                          gw1t, gb1, gW2, gpart);
    k_final<<<(P + 255) / 256, 256, 0, stream>>>(gpart, gb2, ssyn, sant, out, P);
}

// Round 12
// 1805.305 us; speedup vs baseline: 1.2923x; 1.0387x over previous
//
#include <hip/hip_runtime.h>
#include <cstdint>

#define L_LAYERS 6

typedef __attribute__((ext_vector_type(8))) short bf16x8;
typedef __attribute__((ext_vector_type(4))) float f32x4;
typedef __attribute__((ext_vector_type(2))) float f32x2;

__device__ __forceinline__ float gelu1(float v) {
    return 0.5f * v * (1.0f + erff(v * 0.7071067811865475f));
}

__device__ __forceinline__ unsigned int f2bf2(float a, float b) {
    union { float f; unsigned u; } x, y;
    x.f = a; y.f = b;
    unsigned lo = (x.u + 0x7FFFu + ((x.u >> 16) & 1u)) >> 16;
    unsigned hi = (y.u + 0x7FFFu + ((y.u >> 16) & 1u)) & 0xFFFF0000u;
    return lo | hi;
}

__device__ __forceinline__ unsigned short f2bf1(float a) {
    union { float f; unsigned u; } x;
    x.f = a;
    return (unsigned short)((x.u + 0x7FFFu + ((x.u >> 16) & 1u)) >> 16);
}

__device__ __forceinline__ float2 bfp2(unsigned u) {
    union { unsigned u; float f; } a, b;
    a.u = u << 16;
    b.u = u & 0xFFFF0000u;
    return make_float2(a.f, b.f);
}

// async global->LDS, 16 bytes per lane (dest = wave-uniform base + lane*16)
__device__ __forceinline__ void gload16(const void* g, void* l) {
    __builtin_amdgcn_global_load_lds(
        (const __attribute__((address_space(1))) void*)g,
        (__attribute__((address_space(3))) void*)l, 16, 0, 0);
}

// ---------------- utility ----------------

__global__ void k_zero(int* __restrict__ p, int n) {
    int i = blockIdx.x * 256 + threadIdx.x;
    if (i < n) p[i] = 0;
}

// ---------------- edge sorting (counting sort by dst) ----------------

__global__ void k_hist(const int* __restrict__ dst, int* __restrict__ hist, int E) {
    int e = blockIdx.x * 256 + threadIdx.x;
    if (e < E) atomicAdd(&hist[dst[e]], 1);
}

__global__ __launch_bounds__(1024) void k_scan(const int* __restrict__ hist,
                                               int* __restrict__ off, int n) {
    __shared__ int buf[1024];
    __shared__ int carry;
    int tid = threadIdx.x;
    if (tid == 0) carry = 0;
    __syncthreads();
    for (int base = 0; base < n; base += 1024) {
        int v = (base + tid < n) ? hist[base + tid] : 0;
        buf[tid] = v;
        __syncthreads();
        int x = v;
        for (int o = 1; o < 1024; o <<= 1) {
            int t = (tid >= o) ? buf[tid - o] : 0;
            __syncthreads();
            x += t;
            buf[tid] = x;
            __syncthreads();
        }
        int c = carry;
        if (base + tid < n) off[base + tid] = c + x - v;   // exclusive
        __syncthreads();
        if (tid == 1023) carry = c + buf[1023];
        __syncthreads();
    }
    if (tid == 0) off[n] = carry;
}

__global__ void k_scatter(const int* __restrict__ src, const int* __restrict__ dst,
                          const int* __restrict__ off, int* __restrict__ cursor,
                          int* __restrict__ srcS, int E) {
    int e = blockIdx.x * 256 + threadIdx.x;
    if (e < E) {
        int d = dst[e];
        int pos = off[d] + atomicAdd(&cursor[d], 1);
        srcS[pos] = src[e];
    }
}

// ---------------- weight prep (transpose + cvt to bf16) ----------------

__global__ void k_wcat(const float* __restrict__ Wq, const float* __restrict__ Wk,
                       const float* __restrict__ Wv, const float* __restrict__ Ws,
                       short* __restrict__ Wt) {
    int idx = blockIdx.x * 256 + threadIdx.x;   // l*2^20 + n*512 + k
    int k = idx & 511;
    int nf = (idx >> 9) & 2047;
    int l = idx >> 20;
    int sel = nf >> 9, nn = nf & 511;
    const float* W = (sel == 0) ? Wq : (sel == 1) ? Wk : (sel == 2) ? Wv : Ws;
    float v = W[((size_t)l * 512 + k) * 512 + nn];
    Wt[idx] = (short)f2bf1(v);
}

__global__ void k_tr(const float* __restrict__ W, short* __restrict__ Wt, int K, int N) {
    int k = blockIdx.x * 256 + threadIdx.x;
    int n = blockIdx.y;
    if (k < K) Wt[(size_t)n * K + k] = (short)f2bf1(W[(size_t)k * N + n]);
}

__global__ void k_bcat(const float* __restrict__ bq, const float* __restrict__ bk,
                       const float* __restrict__ bv, const float* __restrict__ bs,
                       float* __restrict__ bcat) {
    int idx = blockIdx.x * 256 + threadIdx.x;
    if (idx >= L_LAYERS * 2048) return;
    int l = idx >> 11, n = idx & 2047;
    int sel = n >> 9, nn = n & 511;
    const float* b = (sel == 0) ? bq : (sel == 1) ? bk : (sel == 2) ? bv : bs;
    bcat[idx] = b[l * 512 + nn];
}

__global__ void k_bdual(const float* __restrict__ sb, const float* __restrict__ ab,
                        float* __restrict__ bd) {
    int idx = blockIdx.x * 256 + threadIdx.x;
    if (idx < 1024) bd[idx] = (idx < 512) ? sb[idx] : ab[idx - 512];
}

// ---------------- GEMM: A fp32 (mixer only) ----------------

__global__ __launch_bounds__(256) void gemm_a32(
    const float* __restrict__ A, int lda,
    const short* __restrict__ Bt,
    const float* __restrict__ bias,
    float* __restrict__ Cf, short* __restrict__ Cbf, int ldc,
    int M, int N, int K, int act) {
    __shared__ __align__(16) short As[128][40];
    __shared__ __align__(16) short Bs[128][40];
    const int tid = threadIdx.x;
    const int lane = tid & 63;
    const int wave = tid >> 6;
    const int wr = (wave >> 1) * 64;
    const int wc = (wave & 1) * 64;
    const int l16 = lane & 15;
    const int quad = lane >> 4;
    const int row0 = blockIdx.x * 128;
    const int col0 = blockIdx.y * 128;
    const int sr = tid >> 2;
    const int sk = (tid & 3) * 8;

    f32x4 acc[4][4];
#pragma unroll
    for (int i = 0; i < 4; ++i)
#pragma unroll
        for (int j = 0; j < 4; ++j)
            acc[i][j] = f32x4{0.f, 0.f, 0.f, 0.f};

    for (int kb = 0; kb < K; kb += 32) {
#pragma unroll
        for (int hh = 0; hh < 2; ++hh) {
            int r = sr + hh * 64;
            int gr = row0 + r;
            float4 a0, a1;
            if (gr < M) {
                const float* p = A + (size_t)gr * lda + kb + sk;
                a0 = *(const float4*)p;
                a1 = *(const float4*)(p + 4);
            } else {
                a0 = make_float4(0.f, 0.f, 0.f, 0.f);
                a1 = make_float4(0.f, 0.f, 0.f, 0.f);
            }
            uint4 av;
            av.x = f2bf2(a0.x, a0.y);
            av.y = f2bf2(a0.z, a0.w);
            av.z = f2bf2(a1.x, a1.y);
            av.w = f2bf2(a1.z, a1.w);
            *(uint4*)&As[r][sk] = av;
            const short* bp = Bt + (size_t)(col0 + r) * K + kb + sk;
            *(uint4*)&Bs[r][sk] = *(const uint4*)bp;
        }
        __syncthreads();
        bf16x8 af[4], bfr[4];
#pragma unroll
        for (int i = 0; i < 4; ++i)
            af[i] = *(const bf16x8*)&As[wr + i * 16 + l16][quad * 8];
#pragma unroll
        for (int j = 0; j < 4; ++j)
            bfr[j] = *(const bf16x8*)&Bs[wc + j * 16 + l16][quad * 8];
#pragma unroll
        for (int i = 0; i < 4; ++i)
#pragma unroll
            for (int j = 0; j < 4; ++j)
                acc[i][j] = __builtin_amdgcn_mfma_f32_16x16x32_bf16(af[i], bfr[j], acc[i][j], 0, 0, 0);
        __syncthreads();
    }
#pragma unroll
    for (int i = 0; i < 4; ++i) {
        int rbase = row0 + wr + i * 16 + quad * 4;
#pragma unroll
        for (int j = 0; j < 4; ++j) {
            int c = col0 + wc + j * 16 + l16;
            float bv = bias ? bias[c] : 0.0f;
#pragma unroll
            for (int rg = 0; rg < 4; ++rg) {
                int gr = rbase + rg;
                if (gr < M) {
                    float v = acc[i][j][rg] + bv;
                    if (act) v = gelu1(v);
                    Cf[(size_t)gr * ldc + c] = v;
                    if (Cbf) Cbf[(size_t)gr * ldc + c] = (short)f2bf1(v);
                }
            }
        }
    }
}

// ---------------- GEMM: A bf16, B bf16, m97-style global_load_lds staging ----------------
// Optional C8: also write fp8 e4m3 copy (row stride ldc).

__global__ __launch_bounds__(256) void gemm_bb(
    const short* __restrict__ A, int lda,
    const short* __restrict__ Bt,
    const float* __restrict__ bias,
    short* __restrict__ C, unsigned char* __restrict__ C8, int ldc,
    int M, int N, int K, int act) {
    __shared__ __align__(16) short As[128 * 32];
    __shared__ __align__(16) short Bs[128 * 32];
    const int tid = threadIdx.x;
    const int lane = tid & 63;
    const int wave = tid >> 6;
    const int wr = (wave >> 1) * 64;
    const int wc = (wave & 1) * 64;
    const int l16 = lane & 15;
    const int quad = lane >> 4;
    const int row0 = blockIdx.x * 128;
    const int col0 = blockIdx.y * 128;
    const int c0 = tid, c1 = tid + 256;
    const int r0 = c0 >> 2, kq0 = (c0 & 3) * 8;
    const int r1 = c1 >> 2, kq1 = (c1 & 3) * 8;
    int ga0 = row0 + r0; if (ga0 >= M) ga0 = M - 1;
    int ga1 = row0 + r1; if (ga1 >= M) ga1 = M - 1;
    const short* Ap0 = A + (size_t)ga0 * lda + kq0;
    const short* Ap1 = A + (size_t)ga1 * lda + kq1;
    const short* Bp0 = Bt + (size_t)(col0 + r0) * K + kq0;
    const short* Bp1 = Bt + (size_t)(col0 + r1) * K + kq1;

    f32x4 acc[4][4];
#pragma unroll
    for (int i = 0; i < 4; ++i)
#pragma unroll
        for (int j = 0; j < 4; ++j)
            acc[i][j] = f32x4{0.f, 0.f, 0.f, 0.f};

    for (int kb = 0; kb < K; kb += 32) {
        gload16(Ap0 + kb, &As[c0 * 8]);
        gload16(Ap1 + kb, &As[c1 * 8]);
        gload16(Bp0 + kb, &Bs[c0 * 8]);
        gload16(Bp1 + kb, &Bs[c1 * 8]);
        __syncthreads();
        bf16x8 af[4], bfr[4];
#pragma unroll
        for (int i = 0; i < 4; ++i)
            af[i] = *(const bf16x8*)&As[(wr + i * 16 + l16) * 32 + quad * 8];
#pragma unroll
        for (int j = 0; j < 4; ++j)
            bfr[j] = *(const bf16x8*)&Bs[(wc + j * 16 + l16) * 32 + quad * 8];
#pragma unroll
        for (int i = 0; i < 4; ++i)
#pragma unroll
            for (int j = 0; j < 4; ++j)
                acc[i][j] = __builtin_amdgcn_mfma_f32_16x16x32_bf16(af[i], bfr[j], acc[i][j], 0, 0, 0);
        __syncthreads();
    }
#pragma unroll
    for (int i = 0; i < 4; ++i) {
        int rbase = row0 + wr + i * 16 + quad * 4;
#pragma unroll
        for (int j = 0; j < 4; ++j) {
            int c = col0 + wc + j * 16 + l16;
            float bv = bias ? bias[c] : 0.0f;
#pragma unroll
            for (int rg = 0; rg < 4; ++rg) {
                int gr = rbase + rg;
                if (gr < M) {
                    float v = acc[i][j][rg] + bv;
                    if (act) v = gelu1(v);
                    C[(size_t)gr * ldc + c] = (short)f2bf1(v);
                    if (C8) {
                        int r8 = __builtin_amdgcn_cvt_pk_fp8_f32(v, v, 0, false);
                        C8[(size_t)gr * ldc + c] = (unsigned char)(r8 & 0xFF);
                    }
                }
            }
        }
    }
}

// ---------------- qkv GEMM, XCD-swizzled 1D grid, split-layout epilogue ----------------
// Linear id -> (xcd = id&7, t = id>>3); col_t = t&15, row_t = (t>>4)*8 + xcd.
// All 16 col-blocks of a row-tile run consecutively on one XCD -> A-tile L2-reused 16x.
// Output cols: [0,512) q -> qvs+0 ; [512,1024) k -> k8 fp8 ; [1024,1536) v -> qvs+512 ;
// [1536,2048) s -> qvs+1024. qvs row stride 1536.

__global__ __launch_bounds__(256) void gemm_qkvs(
    const short* __restrict__ A,      // h_bf [M][512]
    const short* __restrict__ Bt,     // layer weights [2048][512]
    const float* __restrict__ bias,   // [2048]
    short* __restrict__ qvs,          // [M][1536] bf16
    unsigned char* __restrict__ k8,   // [M][512] fp8
    int M, int mtiles) {
    const int K = 512;
    const int id = blockIdx.x;
    const int xcd = id & 7;
    const int t = id >> 3;
    const int col_t = t & 15;
    const int row_t = (t >> 4) * 8 + xcd;
    if (row_t >= mtiles) return;
    const int row0 = row_t * 128;
    const int col0 = col_t * 128;
    __shared__ __align__(16) short As[128 * 32];
    __shared__ __align__(16) short Bs[128 * 32];
    const int tid = threadIdx.x;
    const int lane = tid & 63;
    const int wave = tid >> 6;
    const int wr = (wave >> 1) * 64;
    const int wc = (wave & 1) * 64;
    const int l16 = lane & 15;
    const int quad = lane >> 4;
    const int c0 = tid, c1 = tid + 256;
    const int r0 = c0 >> 2, kq0 = (c0 & 3) * 8;
    const int r1 = c1 >> 2, kq1 = (c1 & 3) * 8;
    int ga0 = row0 + r0; if (ga0 >= M) ga0 = M - 1;
    int ga1 = row0 + r1; if (ga1 >= M) ga1 = M - 1;
    const short* Ap0 = A + (size_t)ga0 * K + kq0;
    const short* Ap1 = A + (size_t)ga1 * K + kq1;
    const short* Bp0 = Bt + (size_t)(col0 + r0) * K + kq0;
    const short* Bp1 = Bt + (size_t)(col0 + r1) * K + kq1;

    f32x4 acc[4][4];
#pragma unroll
    for (int i = 0; i < 4; ++i)
#pragma unroll
        for (int j = 0; j < 4; ++j)
            acc[i][j] = f32x4{0.f, 0.f, 0.f, 0.f};

    for (int kb = 0; kb < K; kb += 32) {
        gload16(Ap0 + kb, &As[c0 * 8]);
        gload16(Ap1 + kb, &As[c1 * 8]);
        gload16(Bp0 + kb, &Bs[c0 * 8]);
        gload16(Bp1 + kb, &Bs[c1 * 8]);
        __syncthreads();
        bf16x8 af[4], bfr[4];
#pragma unroll
        for (int i = 0; i < 4; ++i)
            af[i] = *(const bf16x8*)&As[(wr + i * 16 + l16) * 32 + quad * 8];
#pragma unroll
        for (int j = 0; j < 4; ++j)
            bfr[j] = *(const bf16x8*)&Bs[(wc + j * 16 + l16) * 32 + quad * 8];
#pragma unroll
        for (int i = 0; i < 4; ++i)
#pragma unroll
            for (int j = 0; j < 4; ++j)
                acc[i][j] = __builtin_amdgcn_mfma_f32_16x16x32_bf16(af[i], bfr[j], acc[i][j], 0, 0, 0);
        __syncthreads();
    }
#pragma unroll
    for (int i = 0; i < 4; ++i) {
        int rbase = row0 + wr + i * 16 + quad * 4;
#pragma unroll
        for (int j = 0; j < 4; ++j) {
            int c = col0 + wc + j * 16 + l16;
            int sec = c >> 9;           // uniform within a 64-col wave tile
            int cc = c & 511;
            float bv = bias[c];
#pragma unroll
            for (int rg = 0; rg < 4; ++rg) {
                int gr = rbase + rg;
                if (gr < M) {
                    float v = acc[i][j][rg] + bv;
                    if (sec == 1) {
                        int r8 = __builtin_amdgcn_cvt_pk_fp8_f32(v, v, 0, false);
                        k8[(size_t)gr * 512 + cc] = (unsigned char)(r8 & 0xFF);
                    } else {
                        int off = (sec == 0) ? cc : ((sec == 2) ? 512 + cc : 1024 + cc);
                        qvs[(size_t)gr * 1536 + off] = (short)f2bf1(v);
                    }
                }
            }
        }
    }
}

// ---------------- fused gate GEMM: fp8 z gather, XCD-swizzled 1D grid ----------------
// id -> (xcd = id&7, t = id>>3); col_t = t&1, row_t = (t>>1)*8 + xcd.
// Both col-blocks of a pair-group run consecutively on one XCD -> z8 rows L2-reused.

__global__ __launch_bounds__(256, 3) void gemm_gate(
    const unsigned char* __restrict__ z8,   // [Nn][1024] fp8
    const int* __restrict__ pi, const int* __restrict__ pj, int P,
    const short* __restrict__ Bt,    // gW1^T [512][2048]
    const float* __restrict__ gb1,
    const float* __restrict__ gW2,
    float* __restrict__ gpart, int ptiles) {
    __shared__ __align__(16) short Aab[64 * 32];
    __shared__ __align__(16) short Amu[64 * 32];
    __shared__ __align__(16) short Bab[256 * 32];
    __shared__ __align__(16) short Bmu[256 * 32];
    __shared__ int iArr[64];
    __shared__ int jArr[64];
    __shared__ float rowsum[64];
    const int id = blockIdx.x;
    const int xcd = id & 7;
    const int t = id >> 3;
    const int col_t = t & 1;
    const int row_t = (t >> 1) * 8 + xcd;
    if (row_t >= ptiles) return;
    const int row0 = row_t * 64;
    const int col0 = col_t * 256;
    const int tid = threadIdx.x;
    const int lane = tid & 63;
    const int wave = tid >> 6;
    const int wc = wave * 64;
    const int l16 = lane & 15;
    const int quad = lane >> 4;
    const int sr = tid >> 2;        // 0..63
    const int sk = (tid & 3) * 8;   // channel == byte offset for fp8

    if (tid < 64) {
        int p = row0 + tid;
        int ok = (p < P);
        iArr[tid] = ok ? pi[p] : 0;
        jArr[tid] = ok ? pj[p] : 0;
        rowsum[tid] = 0.0f;
    }
    __syncthreads();
    const unsigned char* zi = z8 + (size_t)iArr[sr] * 1024 + sk;
    const unsigned char* zj = z8 + (size_t)jArr[sr] * 1024 + sk;
    const short* bp0 = Bt + (size_t)(col0 + sr) * 2048 + sk;

    f32x4 acc[4][4];
#pragma unroll
    for (int i = 0; i < 4; ++i)
#pragma unroll
        for (int j = 0; j < 4; ++j)
            acc[i][j] = f32x4{0.f, 0.f, 0.f, 0.f};

    for (int part = 0; part < 2; ++part) {
        for (int c = 0; c < 512; c += 32) {
            const short* bp = bp0 + part * 1024 + c;
#pragma unroll
            for (int hh = 0; hh < 4; ++hh) {
                const short* q = bp + (size_t)hh * 64 * 2048;
                gload16(q, &Bab[hh * 2048 + tid * 8]);
                gload16(q + 512, &Bmu[hh * 2048 + tid * 8]);
            }
            uint2 xu = *(const uint2*)(zi + part * 512 + c);
            uint2 yu = *(const uint2*)(zj + part * 512 + c);
            f32x2 x0 = __builtin_amdgcn_cvt_pk_f32_fp8((int)xu.x, false);
            f32x2 x1 = __builtin_amdgcn_cvt_pk_f32_fp8((int)xu.x, true);
            f32x2 x2 = __builtin_amdgcn_cvt_pk_f32_fp8((int)xu.y, false);
            f32x2 x3 = __builtin_amdgcn_cvt_pk_f32_fp8((int)xu.y, true);
            f32x2 y0 = __builtin_amdgcn_cvt_pk_f32_fp8((int)yu.x, false);
            f32x2 y1 = __builtin_amdgcn_cvt_pk_f32_fp8((int)yu.x, true);
            f32x2 y2 = __builtin_amdgcn_cvt_pk_f32_fp8((int)yu.y, false);
            f32x2 y3 = __builtin_amdgcn_cvt_pk_f32_fp8((int)yu.y, true);
            uint4 aa, am;
            aa.x = f2bf2(fabsf(x0.x - y0.x), fabsf(x0.y - y0.y));
            aa.y = f2bf2(fabsf(x1.x - y1.x), fabsf(x1.y - y1.y));
            aa.z = f2bf2(fabsf(x2.x - y2.x), fabsf(x2.y - y2.y));
            aa.w = f2bf2(fabsf(x3.x - y3.x), fabsf(x3.y - y3.y));
            am.x = f2bf2(x0.x * y0.x, x0.y * y0.y);
            am.y = f2bf2(x1.x * y1.x, x1.y * y1.y);
            am.z = f2bf2(x2.x * y2.x, x2.y * y2.y);
            am.w = f2bf2(x3.x * y3.x, x3.y * y3.y);
            *(uint4*)&Aab[tid * 8] = aa;
            *(uint4*)&Amu[tid * 8] = am;
            __syncthreads();
            bf16x8 af[4];
#pragma unroll
            for (int i = 0; i < 4; ++i)
                af[i] = *(const bf16x8*)&Aab[(i * 16 + l16) * 32 + quad * 8];
#pragma unroll
            for (int j = 0; j < 4; ++j) {
                bf16x8 bf = *(const bf16x8*)&Bab[(wc + j * 16 + l16) * 32 + quad * 8];
#pragma unroll
                for (int i = 0; i < 4; ++i)
                    acc[i][j] = __builtin_amdgcn_mfma_f32_16x16x32_bf16(af[i], bf, acc[i][j], 0, 0, 0);
            }
#pragma unroll
            for (int i = 0; i < 4; ++i)
                af[i] = *(const bf16x8*)&Amu[(i * 16 + l16) * 32 + quad * 8];
#pragma unroll
            for (int j = 0; j < 4; ++j) {
                bf16x8 bf = *(const bf16x8*)&Bmu[(wc + j * 16 + l16) * 32 + quad * 8];
#pragma unroll
                for (int i = 0; i < 4; ++i)
                    acc[i][j] = __builtin_amdgcn_mfma_f32_16x16x32_bf16(af[i], bf, acc[i][j], 0, 0, 0);
            }
            __syncthreads();
        }
    }
#pragma unroll
    for (int i = 0; i < 4; ++i) {
#pragma unroll
        for (int rg = 0; rg < 4; ++rg) {
            float partial = 0.f;
#pragma unroll
            for (int j = 0; j < 4; ++j) {
                int cc = col0 + wc + j * 16 + l16;
                partial += gelu1(acc[i][j][rg] + gb1[cc]) * gW2[cc];
            }
            partial += __shfl_xor(partial, 1);
            partial += __shfl_xor(partial, 2);
            partial += __shfl_xor(partial, 4);
            partial += __shfl_xor(partial, 8);
            if (l16 == 0)
                atomicAdd(&rowsum[i * 16 + quad * 4 + rg], partial);
        }
    }
    __syncthreads();
    if (tid < 64 && (row0 + tid) < P)
        atomicAdd(&gpart[row0 + tid], rowsum[tid]);
}

// ---------------- fused per-layer attention: single-pass, fp8 k gather -------------

__global__ __launch_bounds__(256) void k_attn(const short* __restrict__ qvs,
                                              const unsigned char* __restrict__ k8,
                                              const int* __restrict__ srcS,
                                              const int* __restrict__ offs,
                                              float* __restrict__ h,
                                              short* __restrict__ h_bf,
                                              const float* __restrict__ lng,
                                              const float* __restrict__ lnb, int Nn) {
    const int tid = threadIdx.x;
    const int lane = tid & 63;
    const int wv = tid >> 6;
    const int n = blockIdx.x * 4 + wv;
    if (n >= Nn) return;
    const int st = offs[n], en = offs[n + 1];
    const size_t chOff = (size_t)lane * 8;

    uint4 qv = *(const uint4*)(qvs + (size_t)n * 1536 + chOff);
    float2 q0 = bfp2(qv.x), q1 = bfp2(qv.y), q2 = bfp2(qv.z), q3 = bfp2(qv.w);
    float acc[8];
#pragma unroll
    for (int i = 0; i < 8; ++i) acc[i] = 0.f;
    float m_l = -3.4e38f, l_l = 0.f;

    for (int e0 = st; e0 < en; e0 += 64) {
        int cnt = min(64, en - e0);
        int myS = (lane < cnt) ? srcS[e0 + lane] : 0;
        for (int ei = 0; ei < cnt; ++ei) {
            int s = __shfl(myS, ei);
            uint2 kq = *(const uint2*)(k8 + (size_t)s * 512 + chOff);
            uint4 vv = *(const uint4*)(qvs + (size_t)s * 1536 + 512 + chOff);
            f32x2 k0 = __builtin_amdgcn_cvt_pk_f32_fp8((int)kq.x, false);
            f32x2 k1 = __builtin_amdgcn_cvt_pk_f32_fp8((int)kq.x, true);
            f32x2 k2 = __builtin_amdgcn_cvt_pk_f32_fp8((int)kq.y, false);
            f32x2 k3 = __builtin_amdgcn_cvt_pk_f32_fp8((int)kq.y, true);
            float d = q0.x * k0.x + q0.y * k0.y + q1.x * k1.x + q1.y * k1.y +
                      q2.x * k2.x + q2.y * k2.y + q3.x * k3.x + q3.y * k3.y;
            d += __shfl_xor(d, 1);
            d += __shfl_xor(d, 2);
            d += __shfl_xor(d, 4);
            d += __shfl_xor(d, 8);
            float lg = d * 0.08838834764831845f;
            float m_new = fmaxf(m_l, lg);
            float sc = __expf(m_l - m_new);
            float p = __expf(lg - m_new);
            l_l = l_l * sc + p;
            m_l = m_new;
            float2 v0 = bfp2(vv.x), v1 = bfp2(vv.y), v2 = bfp2(vv.z), v3 = bfp2(vv.w);
            acc[0] = acc[0] * sc + p * v0.x; acc[1] = acc[1] * sc + p * v0.y;
            acc[2] = acc[2] * sc + p * v1.x; acc[3] = acc[3] * sc + p * v1.y;
            acc[4] = acc[4] * sc + p * v2.x; acc[5] = acc[5] * sc + p * v2.y;
            acc[6] = acc[6] * sc + p * v3.x; acc[7] = acc[7] * sc + p * v3.y;
        }
    }
    float rinv = (en > st) ? 1.0f / l_l : 0.f;
    uint4 su = *(const uint4*)(qvs + (size_t)n * 1536 + 1024 + chOff);
    float2 s0 = bfp2(su.x), s1 = bfp2(su.y), s2 = bfp2(su.z), s3 = bfp2(su.w);
    float sv[8] = {s0.x, s0.y, s1.x, s1.y, s2.x, s2.y, s3.x, s3.y};
    const float* hp = h + (size_t)n * 512 + chOff;
    float4 h0 = *(const float4*)hp;
    float4 h1 = *(const float4*)(hp + 4);
    float hv[8] = {h0.x, h0.y, h0.z, h0.w, h1.x, h1.y, h1.z, h1.w};
    float r[8];
    float sum = 0.f, ssq = 0.f;
#pragma unroll
    for (int i = 0; i < 8; ++i) {
        r[i] = hv[i] + gelu1(acc[i] * rinv + sv[i]);
        sum += r[i];
        ssq += r[i] * r[i];
    }
    for (int o = 32; o; o >>= 1) {
        sum += __shfl_xor(sum, o);
        ssq += __shfl_xor(ssq, o);
    }
    float mean = sum * (1.0f / 512.0f);
    float var = ssq * (1.0f / 512.0f) - mean * mean;
    float inv = rsqrtf(var + 1e-5f);
    const float* gp = lng + chOff;
    const float* bp = lnb + chOff;
    float4 g0 = *(const float4*)gp, g1 = *(const float4*)(gp + 4);
    float4 b0 = *(const float4*)bp, b1 = *(const float4*)(bp + 4);
    float ga[8] = {g0.x, g0.y, g0.z, g0.w, g1.x, g1.y, g1.z, g1.w};
    float ba[8] = {b0.x, b0.y, b0.z, b0.w, b1.x, b1.y, b1.z, b1.w};
    float o8[8];
#pragma unroll
    for (int i = 0; i < 8; ++i) o8[i] = (r[i] - mean) * inv * ga[i] + ba[i];
    float* hw = h + (size_t)n * 512 + chOff;
    *(float4*)hw = make_float4(o8[0], o8[1], o8[2], o8[3]);
    *(float4*)(hw + 4) = make_float4(o8[4], o8[5], o8[6], o8[7]);
    uint4 ob;
    ob.x = f2bf2(o8[0], o8[1]);
    ob.y = f2bf2(o8[2], o8[3]);
    ob.z = f2bf2(o8[4], o8[5]);
    ob.w = f2bf2(o8[6], o8[7]);
    *(uint4*)(h_bf + (size_t)n * 512 + chOff) = ob;
}

// ---------------- pair bilinear scores (bf16 z,t) ----------------

__global__ __launch_bounds__(256) void k_pairscore(const short* __restrict__ z,
                                                   const short* __restrict__ t,
                                                   const int* __restrict__ pi,
                                                   const int* __restrict__ pj,
                                                   float* __restrict__ ssyn,
                                                   float* __restrict__ sant, int P) {
    int p = blockIdx.x * 4 + (threadIdx.x >> 6);
    if (p >= P) return;
    int lane = threadIdx.x & 63;
    int i = pi[p], j = pj[p];
    uint4 a = *(const uint4*)(t + (size_t)i * 1024 + lane * 8);
    uint4 b = *(const uint4*)(z + (size_t)j * 1024 + lane * 8);
    float2 a0 = bfp2(a.x), a1 = bfp2(a.y), a2 = bfp2(a.z), a3 = bfp2(a.w);
    float2 b0 = bfp2(b.x), b1 = bfp2(b.y), b2 = bfp2(b.z), b3 = bfp2(b.w);
    float ds = a0.x * b0.x + a0.y * b0.y + a1.x * b1.x + a1.y * b1.y +
               a2.x * b2.x + a2.y * b2.y + a3.x * b3.x + a3.y * b3.y;
    uint4 c = *(const uint4*)(t + (size_t)i * 1024 + 512 + lane * 8);
    uint4 d = *(const uint4*)(z + (size_t)j * 1024 + 512 + lane * 8);
    float2 c0 = bfp2(c.x), c1 = bfp2(c.y), c2 = bfp2(c.z), c3 = bfp2(c.w);
    float2 d0 = bfp2(d.x), d1 = bfp2(d.y), d2 = bfp2(d.z), d3 = bfp2(d.w);
    float da = c0.x * d0.x + c0.y * d0.y + c1.x * d1.x + c1.y * d1.y +
               c2.x * d2.x + c2.y * d2.y + c3.x * d3.x + c3.y * d3.y;
    for (int o = 32; o; o >>= 1) {
        ds += __shfl_xor(ds, o);
        da += __shfl_xor(da, o);
    }
    if (lane == 0) { ssyn[p] = ds; sant[p] = da; }
}

// ---------------- final elementwise combine ----------------

__global__ void k_final(const float* __restrict__ gpart, const float* __restrict__ gb2,
                        const float* __restrict__ ssyn, const float* __restrict__ sant,
                        float* __restrict__ out, int P) {
    int p = blockIdx.x * 256 + threadIdx.x;
    if (p < P) {
        float s = 1.0f / (1.0f + __expf(-(gpart[p] + gb2[0])));
        out[p] = s * sant[p] - (1.0f - s) * ssyn[p];
    }
}

// ---------------- host ----------------

extern "C" void kernel_launch(void* const* d_in, const int* in_sizes, int n_in,
                              void* d_out, int out_size, void* d_ws, size_t ws_size,
                              hipStream_t stream) {
    const float* x = (const float*)d_in[0];
    const int* ei = (const int*)d_in[1];
    const int* pe = (const int*)d_in[2];
    const float* mixer_W = (const float*)d_in[3];
    const float* mixer_b = (const float*)d_in[4];
    const float* Wq = (const float*)d_in[5];
    const float* bq = (const float*)d_in[6];
    const float* Wk = (const float*)d_in[7];
    const float* bk = (const float*)d_in[8];
    const float* Wv = (const float*)d_in[9];
    const float* bv = (const float*)d_in[10];
    const float* Ws = (const float*)d_in[11];
    const float* bs = (const float*)d_in[12];
    const float* ln_g = (const float*)d_in[13];
    const float* ln_b = (const float*)d_in[14];
    const float* syn_W = (const float*)d_in[15];
    const float* syn_b = (const float*)d_in[16];
    const float* ant_W = (const float*)d_in[17];
    const float* ant_b = (const float*)d_in[18];
    const float* W_syn = (const float*)d_in[19];
    const float* W_ant = (const float*)d_in[20];
    const float* gW1 = (const float*)d_in[21];
    const float* gb1 = (const float*)d_in[22];
    const float* gW2 = (const float*)d_in[23];
    const float* gb2 = (const float*)d_in[24];
    float* out = (float*)d_out;

    const int Nn = in_sizes[0] / 768;  // 20000
    const int E = in_sizes[1] / 2;     // 320000
    const int P = in_sizes[2] / 2;     // 100000

    char* w = (char*)d_ws;
    auto alloc = [&](size_t bytes) -> char* {
        char* p = w;
        w += (bytes + 255) & ~(size_t)255;
        return p;
    };
    float* h = (float*)alloc((size_t)Nn * 512 * 4);
    short* h_bf = (short*)alloc((size_t)Nn * 512 * 2);
    // union region U: during layers = qvs [Nn][1536] bf16 + k8 [Nn][512] fp8;
    // after layers = zB [Nn][1024] bf16 | tB [Nn][1024] bf16
    char* U = alloc((size_t)Nn * 2048 * 2);
    short* qvs = (short*)U;
    unsigned char* k8 = (unsigned char*)(U + (size_t)Nn * 1536 * 2);
    short* zB = (short*)U;
    short* tB = (short*)(U + (size_t)Nn * 1024 * 2);
    unsigned char* z8 = (unsigned char*)alloc((size_t)Nn * 1024);   // fp8 z copy, 20 MB
    float* ssyn = (float*)alloc((size_t)P * 3 * 4);
    float* sant = ssyn + P;
    float* gpart = ssyn + 2 * P;
    int* srcS = (int*)alloc((size_t)E * 4);
    int* hist = (int*)alloc((size_t)Nn * 2 * 4);
    int* cursor = hist + Nn;
    int* offs = (int*)alloc((size_t)(Nn + 1) * 4);
    short* mixWt = (short*)alloc((size_t)512 * 768 * 2);
    short* wcat = (short*)alloc((size_t)L_LAYERS * 2048 * 512 * 2);
    short* dualWt = (short*)alloc((size_t)1024 * 512 * 2);
    short* bilWt = (short*)alloc((size_t)1024 * 512 * 2);
    short* gw1t = (short*)alloc((size_t)512 * 2048 * 2);
    float* bcat = (float*)alloc((size_t)L_LAYERS * 2048 * 4);
    float* bdual = (float*)alloc((size_t)1024 * 4);

    k_zero<<<(2 * Nn + 255) / 256, 256, 0, stream>>>(hist, 2 * Nn);
    k_hist<<<(E + 255) / 256, 256, 0, stream>>>(ei + E, hist, E);
    k_scan<<<1, 1024, 0, stream>>>(hist, offs, Nn);
    k_scatter<<<(E + 255) / 256, 256, 0, stream>>>(ei, ei + E, offs, cursor, srcS, E);

    k_wcat<<<(L_LAYERS * 2048 * 512) / 256, 256, 0, stream>>>(Wq, Wk, Wv, Ws, wcat);
    k_tr<<<dim3(3, 512), 256, 0, stream>>>(mixer_W, mixWt, 768, 512);
    k_tr<<<dim3(2, 512), 256, 0, stream>>>(syn_W, dualWt, 512, 512);
    k_tr<<<dim3(2, 512), 256, 0, stream>>>(ant_W, dualWt + 512 * 512, 512, 512);
    k_tr<<<dim3(2, 512), 256, 0, stream>>>(W_syn, bilWt, 512, 512);
    k_tr<<<dim3(2, 512), 256, 0, stream>>>(W_ant, bilWt + 512 * 512, 512, 512);
    k_tr<<<dim3(8, 512), 256, 0, stream>>>(gW1, gw1t, 2048, 512);
    k_bcat<<<48, 256, 0, stream>>>(bq, bk, bv, bs, bcat);
    k_bdual<<<4, 256, 0, stream>>>(syn_b, ant_b, bdual);

    const int mtiles = (Nn + 127) / 128;  // 157
    gemm_a32<<<dim3(mtiles, 4), 256, 0, stream>>>(x, 768, mixWt, mixer_b, h, h_bf, 512,
                                                  Nn, 512, 768, 1);

    // XCD-swizzled 1D grid: ceil(mtiles/8)*8 row slots x 16 col tiles
    const int qk_grid = ((mtiles + 7) / 8) * 8 * 16;   // 2560
    for (int l = 0; l < L_LAYERS; ++l) {
        gemm_qkvs<<<qk_grid, 256, 0, stream>>>(h_bf, wcat + (size_t)l * 2048 * 512,
                                               bcat + l * 2048, qvs, k8, Nn, mtiles);
        k_attn<<<(Nn + 3) / 4, 256, 0, stream>>>(qvs, k8, srcS, offs, h, h_bf,
                                                 ln_g + l * 512, ln_b + l * 512, Nn);
    }

    // z = gelu(h @ [syn_W|ant_W] + b) -> zB bf16 + z8 fp8
    gemm_bb<<<dim3(mtiles, 8), 256, 0, stream>>>(h_bf, 512, dualWt, bdual, zB, z8, 1024,
                                                 Nn, 1024, 512, 1);
    gemm_bb<<<dim3(mtiles, 4), 256, 0, stream>>>(zB, 1024, bilWt, nullptr, tB, nullptr, 1024,
                                                 Nn, 512, 512, 0);
    gemm_bb<<<dim3(mtiles, 4), 256, 0, stream>>>(zB + 512, 1024, bilWt + 512 * 512, nullptr,
                                                 tB + 512, nullptr, 1024, Nn, 512, 512, 0);

    k_pairscore<<<(P + 3) / 4, 256, 0, stream>>>(zB, tB, pe, pe + P, ssyn, sant, P);

    k_zero<<<(P + 255) / 256, 256, 0, stream>>>((int*)gpart, P);
    const int ptiles = (P + 63) / 64;                  // 1563
    const int gate_grid = ((ptiles + 7) / 8) * 8 * 2;  // 3136
    gemm_gate<<<gate_grid, 256, 0, stream>>>(z8, pe, pe + P, P,
                                             gw1t, gb1, gW2, gpart, ptiles);
    k_final<<<(P + 255) / 256, 256, 0, stream>>>(gpart, gb2, ssyn, sant, out, P);
}

// Round 13
// 1678.663 us; speedup vs baseline: 1.3898x; 1.0754x over previous
//
#include <hip/hip_runtime.h>
#include <cstdint>

#define L_LAYERS 6

typedef __attribute__((ext_vector_type(8))) short bf16x8;
typedef __attribute__((ext_vector_type(4))) float f32x4;
typedef __attribute__((ext_vector_type(2))) float f32x2;

__device__ __forceinline__ float gelu1(float v) {
    return 0.5f * v * (1.0f + erff(v * 0.7071067811865475f));
}

__device__ __forceinline__ unsigned int f2bf2(float a, float b) {
    union { float f; unsigned u; } x, y;
    x.f = a; y.f = b;
    unsigned lo = (x.u + 0x7FFFu + ((x.u >> 16) & 1u)) >> 16;
    unsigned hi = (y.u + 0x7FFFu + ((y.u >> 16) & 1u)) & 0xFFFF0000u;
    return lo | hi;
}

__device__ __forceinline__ unsigned short f2bf1(float a) {
    union { float f; unsigned u; } x;
    x.f = a;
    return (unsigned short)((x.u + 0x7FFFu + ((x.u >> 16) & 1u)) >> 16);
}

__device__ __forceinline__ float2 bfp2(unsigned u) {
    union { unsigned u; float f; } a, b;
    a.u = u << 16;
    b.u = u & 0xFFFF0000u;
    return make_float2(a.f, b.f);
}

// async global->LDS, 16 bytes per lane (dest = wave-uniform base + lane*16)
__device__ __forceinline__ void gload16(const void* g, void* l) {
    __builtin_amdgcn_global_load_lds(
        (const __attribute__((address_space(1))) void*)g,
        (__attribute__((address_space(3))) void*)l, 16, 0, 0);
}

// ---------------- utility ----------------

__global__ void k_zero(int* __restrict__ p, int n) {
    int i = blockIdx.x * 256 + threadIdx.x;
    if (i < n) p[i] = 0;
}

// ---------------- edge sorting (counting sort by dst) ----------------

__global__ void k_hist(const int* __restrict__ dst, int* __restrict__ hist, int E) {
    int e = blockIdx.x * 256 + threadIdx.x;
    if (e < E) atomicAdd(&hist[dst[e]], 1);
}

__global__ __launch_bounds__(1024) void k_scan(const int* __restrict__ hist,
                                               int* __restrict__ off, int n) {
    __shared__ int buf[1024];
    __shared__ int carry;
    int tid = threadIdx.x;
    if (tid == 0) carry = 0;
    __syncthreads();
    for (int base = 0; base < n; base += 1024) {
        int v = (base + tid < n) ? hist[base + tid] : 0;
        buf[tid] = v;
        __syncthreads();
        int x = v;
        for (int o = 1; o < 1024; o <<= 1) {
            int t = (tid >= o) ? buf[tid - o] : 0;
            __syncthreads();
            x += t;
            buf[tid] = x;
            __syncthreads();
        }
        int c = carry;
        if (base + tid < n) off[base + tid] = c + x - v;   // exclusive
        __syncthreads();
        if (tid == 1023) carry = c + buf[1023];
        __syncthreads();
    }
    if (tid == 0) off[n] = carry;
}

__global__ void k_scatter(const int* __restrict__ src, const int* __restrict__ dst,
                          const int* __restrict__ off, int* __restrict__ cursor,
                          int* __restrict__ srcS, int E) {
    int e = blockIdx.x * 256 + threadIdx.x;
    if (e < E) {
        int d = dst[e];
        int pos = off[d] + atomicAdd(&cursor[d], 1);
        srcS[pos] = src[e];
    }
}

// ---------------- weight prep (transpose + cvt to bf16) ----------------

__global__ void k_wcat(const float* __restrict__ Wq, const float* __restrict__ Wk,
                       const float* __restrict__ Wv, const float* __restrict__ Ws,
                       short* __restrict__ Wt) {
    int idx = blockIdx.x * 256 + threadIdx.x;   // l*2^20 + n*512 + k
    int k = idx & 511;
    int nf = (idx >> 9) & 2047;
    int l = idx >> 20;
    int sel = nf >> 9, nn = nf & 511;
    const float* W = (sel == 0) ? Wq : (sel == 1) ? Wk : (sel == 2) ? Wv : Ws;
    float v = W[((size_t)l * 512 + k) * 512 + nn];
    Wt[idx] = (short)f2bf1(v);
}

__global__ void k_tr(const float* __restrict__ W, short* __restrict__ Wt, int K, int N) {
    int k = blockIdx.x * 256 + threadIdx.x;
    int n = blockIdx.y;
    if (k < K) Wt[(size_t)n * K + k] = (short)f2bf1(W[(size_t)k * N + n]);
}

__global__ void k_bcat(const float* __restrict__ bq, const float* __restrict__ bk,
                       const float* __restrict__ bv, const float* __restrict__ bs,
                       float* __restrict__ bcat) {
    int idx = blockIdx.x * 256 + threadIdx.x;
    if (idx >= L_LAYERS * 2048) return;
    int l = idx >> 11, n = idx & 2047;
    int sel = n >> 9, nn = n & 511;
    const float* b = (sel == 0) ? bq : (sel == 1) ? bk : (sel == 2) ? bv : bs;
    bcat[idx] = b[l * 512 + nn];
}

__global__ void k_bdual(const float* __restrict__ sb, const float* __restrict__ ab,
                        float* __restrict__ bd) {
    int idx = blockIdx.x * 256 + threadIdx.x;
    if (idx < 1024) bd[idx] = (idx < 512) ? sb[idx] : ab[idx - 512];
}

// ---------------- GEMM: A fp32 (mixer only) ----------------

__global__ __launch_bounds__(256) void gemm_a32(
    const float* __restrict__ A, int lda,
    const short* __restrict__ Bt,
    const float* __restrict__ bias,
    float* __restrict__ Cf, short* __restrict__ Cbf, int ldc,
    int M, int N, int K, int act) {
    __shared__ __align__(16) short As[128][40];
    __shared__ __align__(16) short Bs[128][40];
    const int tid = threadIdx.x;
    const int lane = tid & 63;
    const int wave = tid >> 6;
    const int wr = (wave >> 1) * 64;
    const int wc = (wave & 1) * 64;
    const int l16 = lane & 15;
    const int quad = lane >> 4;
    const int row0 = blockIdx.x * 128;
    const int col0 = blockIdx.y * 128;
    const int sr = tid >> 2;
    const int sk = (tid & 3) * 8;

    f32x4 acc[4][4];
#pragma unroll
    for (int i = 0; i < 4; ++i)
#pragma unroll
        for (int j = 0; j < 4; ++j)
            acc[i][j] = f32x4{0.f, 0.f, 0.f, 0.f};

    for (int kb = 0; kb < K; kb += 32) {
#pragma unroll
        for (int hh = 0; hh < 2; ++hh) {
            int r = sr + hh * 64;
            int gr = row0 + r;
            float4 a0, a1;
            if (gr < M) {
                const float* p = A + (size_t)gr * lda + kb + sk;
                a0 = *(const float4*)p;
                a1 = *(const float4*)(p + 4);
            } else {
                a0 = make_float4(0.f, 0.f, 0.f, 0.f);
                a1 = make_float4(0.f, 0.f, 0.f, 0.f);
            }
            uint4 av;
            av.x = f2bf2(a0.x, a0.y);
            av.y = f2bf2(a0.z, a0.w);
            av.z = f2bf2(a1.x, a1.y);
            av.w = f2bf2(a1.z, a1.w);
            *(uint4*)&As[r][sk] = av;
            const short* bp = Bt + (size_t)(col0 + r) * K + kb + sk;
            *(uint4*)&Bs[r][sk] = *(const uint4*)bp;
        }
        __syncthreads();
        bf16x8 af[4], bfr[4];
#pragma unroll
        for (int i = 0; i < 4; ++i)
            af[i] = *(const bf16x8*)&As[wr + i * 16 + l16][quad * 8];
#pragma unroll
        for (int j = 0; j < 4; ++j)
            bfr[j] = *(const bf16x8*)&Bs[wc + j * 16 + l16][quad * 8];
#pragma unroll
        for (int i = 0; i < 4; ++i)
#pragma unroll
            for (int j = 0; j < 4; ++j)
                acc[i][j] = __builtin_amdgcn_mfma_f32_16x16x32_bf16(af[i], bfr[j], acc[i][j], 0, 0, 0);
        __syncthreads();
    }
#pragma unroll
    for (int i = 0; i < 4; ++i) {
        int rbase = row0 + wr + i * 16 + quad * 4;
#pragma unroll
        for (int j = 0; j < 4; ++j) {
            int c = col0 + wc + j * 16 + l16;
            float bv = bias ? bias[c] : 0.0f;
#pragma unroll
            for (int rg = 0; rg < 4; ++rg) {
                int gr = rbase + rg;
                if (gr < M) {
                    float v = acc[i][j][rg] + bv;
                    if (act) v = gelu1(v);
                    Cf[(size_t)gr * ldc + c] = v;
                    if (Cbf) Cbf[(size_t)gr * ldc + c] = (short)f2bf1(v);
                }
            }
        }
    }
}

// ---------------- GEMM: A bf16, B bf16, m97-style global_load_lds staging ----------------
// Optional C8: also write fp8 e4m3 copy (row stride ldc).

__global__ __launch_bounds__(256) void gemm_bb(
    const short* __restrict__ A, int lda,
    const short* __restrict__ Bt,
    const float* __restrict__ bias,
    short* __restrict__ C, unsigned char* __restrict__ C8, int ldc,
    int M, int N, int K, int act) {
    __shared__ __align__(16) short As[128 * 32];
    __shared__ __align__(16) short Bs[128 * 32];
    const int tid = threadIdx.x;
    const int lane = tid & 63;
    const int wave = tid >> 6;
    const int wr = (wave >> 1) * 64;
    const int wc = (wave & 1) * 64;
    const int l16 = lane & 15;
    const int quad = lane >> 4;
    const int row0 = blockIdx.x * 128;
    const int col0 = blockIdx.y * 128;
    const int c0 = tid, c1 = tid + 256;
    const int r0 = c0 >> 2, kq0 = (c0 & 3) * 8;
    const int r1 = c1 >> 2, kq1 = (c1 & 3) * 8;
    int ga0 = row0 + r0; if (ga0 >= M) ga0 = M - 1;
    int ga1 = row0 + r1; if (ga1 >= M) ga1 = M - 1;
    const short* Ap0 = A + (size_t)ga0 * lda + kq0;
    const short* Ap1 = A + (size_t)ga1 * lda + kq1;
    const short* Bp0 = Bt + (size_t)(col0 + r0) * K + kq0;
    const short* Bp1 = Bt + (size_t)(col0 + r1) * K + kq1;

    f32x4 acc[4][4];
#pragma unroll
    for (int i = 0; i < 4; ++i)
#pragma unroll
        for (int j = 0; j < 4; ++j)
            acc[i][j] = f32x4{0.f, 0.f, 0.f, 0.f};

    for (int kb = 0; kb < K; kb += 32) {
        gload16(Ap0 + kb, &As[c0 * 8]);
        gload16(Ap1 + kb, &As[c1 * 8]);
        gload16(Bp0 + kb, &Bs[c0 * 8]);
        gload16(Bp1 + kb, &Bs[c1 * 8]);
        __syncthreads();
        bf16x8 af[4], bfr[4];
#pragma unroll
        for (int i = 0; i < 4; ++i)
            af[i] = *(const bf16x8*)&As[(wr + i * 16 + l16) * 32 + quad * 8];
#pragma unroll
        for (int j = 0; j < 4; ++j)
            bfr[j] = *(const bf16x8*)&Bs[(wc + j * 16 + l16) * 32 + quad * 8];
#pragma unroll
        for (int i = 0; i < 4; ++i)
#pragma unroll
            for (int j = 0; j < 4; ++j)
                acc[i][j] = __builtin_amdgcn_mfma_f32_16x16x32_bf16(af[i], bfr[j], acc[i][j], 0, 0, 0);
        __syncthreads();
    }
#pragma unroll
    for (int i = 0; i < 4; ++i) {
        int rbase = row0 + wr + i * 16 + quad * 4;
#pragma unroll
        for (int j = 0; j < 4; ++j) {
            int c = col0 + wc + j * 16 + l16;
            float bv = bias ? bias[c] : 0.0f;
#pragma unroll
            for (int rg = 0; rg < 4; ++rg) {
                int gr = rbase + rg;
                if (gr < M) {
                    float v = acc[i][j][rg] + bv;
                    if (act) v = gelu1(v);
                    C[(size_t)gr * ldc + c] = (short)f2bf1(v);
                    if (C8) {
                        int r8 = __builtin_amdgcn_cvt_pk_fp8_f32(v, v, 0, false);
                        C8[(size_t)gr * ldc + c] = (unsigned char)(r8 & 0xFF);
                    }
                }
            }
        }
    }
}

// ---------------- qkv GEMM, XCD-swizzled 1D grid, split-layout epilogue ----------------
// Output cols: [0,512) q -> qvs+0 (bf16) ; [512,1024) k -> kv8+0 (fp8) ;
// [1024,1536) v -> kv8+512 (fp8) ; [1536,2048) s -> qvs+512 (bf16).
// qvs row stride 1024 (bf16), kv8 row stride 1024 (fp8).

__global__ __launch_bounds__(256) void gemm_qkvs(
    const short* __restrict__ A,      // h_bf [M][512]
    const short* __restrict__ Bt,     // layer weights [2048][512]
    const float* __restrict__ bias,   // [2048]
    short* __restrict__ qvs,          // [M][1024] bf16 (q|s)
    unsigned char* __restrict__ kv8,  // [M][1024] fp8 (k|v)
    int M, int mtiles) {
    const int K = 512;
    const int id = blockIdx.x;
    const int xcd = id & 7;
    const int t = id >> 3;
    const int col_t = t & 15;
    const int row_t = (t >> 4) * 8 + xcd;
    if (row_t >= mtiles) return;
    const int row0 = row_t * 128;
    const int col0 = col_t * 128;
    __shared__ __align__(16) short As[128 * 32];
    __shared__ __align__(16) short Bs[128 * 32];
    const int tid = threadIdx.x;
    const int lane = tid & 63;
    const int wave = tid >> 6;
    const int wr = (wave >> 1) * 64;
    const int wc = (wave & 1) * 64;
    const int l16 = lane & 15;
    const int quad = lane >> 4;
    const int c0 = tid, c1 = tid + 256;
    const int r0 = c0 >> 2, kq0 = (c0 & 3) * 8;
    const int r1 = c1 >> 2, kq1 = (c1 & 3) * 8;
    int ga0 = row0 + r0; if (ga0 >= M) ga0 = M - 1;
    int ga1 = row0 + r1; if (ga1 >= M) ga1 = M - 1;
    const short* Ap0 = A + (size_t)ga0 * K + kq0;
    const short* Ap1 = A + (size_t)ga1 * K + kq1;
    const short* Bp0 = Bt + (size_t)(col0 + r0) * K + kq0;
    const short* Bp1 = Bt + (size_t)(col0 + r1) * K + kq1;

    f32x4 acc[4][4];
#pragma unroll
    for (int i = 0; i < 4; ++i)
#pragma unroll
        for (int j = 0; j < 4; ++j)
            acc[i][j] = f32x4{0.f, 0.f, 0.f, 0.f};

    for (int kb = 0; kb < K; kb += 32) {
        gload16(Ap0 + kb, &As[c0 * 8]);
        gload16(Ap1 + kb, &As[c1 * 8]);
        gload16(Bp0 + kb, &Bs[c0 * 8]);
        gload16(Bp1 + kb, &Bs[c1 * 8]);
        __syncthreads();
        bf16x8 af[4], bfr[4];
#pragma unroll
        for (int i = 0; i < 4; ++i)
            af[i] = *(const bf16x8*)&As[(wr + i * 16 + l16) * 32 + quad * 8];
#pragma unroll
        for (int j = 0; j < 4; ++j)
            bfr[j] = *(const bf16x8*)&Bs[(wc + j * 16 + l16) * 32 + quad * 8];
#pragma unroll
        for (int i = 0; i < 4; ++i)
#pragma unroll
            for (int j = 0; j < 4; ++j)
                acc[i][j] = __builtin_amdgcn_mfma_f32_16x16x32_bf16(af[i], bfr[j], acc[i][j], 0, 0, 0);
        __syncthreads();
    }
#pragma unroll
    for (int i = 0; i < 4; ++i) {
        int rbase = row0 + wr + i * 16 + quad * 4;
#pragma unroll
        for (int j = 0; j < 4; ++j) {
            int c = col0 + wc + j * 16 + l16;
            int sec = c >> 9;           // uniform within a 64-col wave tile
            int cc = c & 511;
            float bv = bias[c];
#pragma unroll
            for (int rg = 0; rg < 4; ++rg) {
                int gr = rbase + rg;
                if (gr < M) {
                    float v = acc[i][j][rg] + bv;
                    if (sec == 1 || sec == 2) {
                        int r8 = __builtin_amdgcn_cvt_pk_fp8_f32(v, v, 0, false);
                        int off = (sec == 1) ? cc : 512 + cc;
                        kv8[(size_t)gr * 1024 + off] = (unsigned char)(r8 & 0xFF);
                    } else {
                        int off = (sec == 0) ? cc : 512 + cc;
                        qvs[(size_t)gr * 1024 + off] = (short)f2bf1(v);
                    }
                }
            }
        }
    }
}

// ---------------- fused gate GEMM: fp8 z gather, XCD-swizzled 1D grid ----------------

__global__ __launch_bounds__(256, 3) void gemm_gate(
    const unsigned char* __restrict__ z8,   // [Nn][1024] fp8
    const int* __restrict__ pi, const int* __restrict__ pj, int P,
    const short* __restrict__ Bt,    // gW1^T [512][2048]
    const float* __restrict__ gb1,
    const float* __restrict__ gW2,
    float* __restrict__ gpart, int ptiles) {
    __shared__ __align__(16) short Aab[64 * 32];
    __shared__ __align__(16) short Amu[64 * 32];
    __shared__ __align__(16) short Bab[256 * 32];
    __shared__ __align__(16) short Bmu[256 * 32];
    __shared__ int iArr[64];
    __shared__ int jArr[64];
    __shared__ float rowsum[64];
    const int id = blockIdx.x;
    const int xcd = id & 7;
    const int t = id >> 3;
    const int col_t = t & 1;
    const int row_t = (t >> 1) * 8 + xcd;
    if (row_t >= ptiles) return;
    const int row0 = row_t * 64;
    const int col0 = col_t * 256;
    const int tid = threadIdx.x;
    const int lane = tid & 63;
    const int wave = tid >> 6;
    const int wc = wave * 64;
    const int l16 = lane & 15;
    const int quad = lane >> 4;
    const int sr = tid >> 2;        // 0..63
    const int sk = (tid & 3) * 8;   // channel == byte offset for fp8

    if (tid < 64) {
        int p = row0 + tid;
        int ok = (p < P);
        iArr[tid] = ok ? pi[p] : 0;
        jArr[tid] = ok ? pj[p] : 0;
        rowsum[tid] = 0.0f;
    }
    __syncthreads();
    const unsigned char* zi = z8 + (size_t)iArr[sr] * 1024 + sk;
    const unsigned char* zj = z8 + (size_t)jArr[sr] * 1024 + sk;
    const short* bp0 = Bt + (size_t)(col0 + sr) * 2048 + sk;

    f32x4 acc[4][4];
#pragma unroll
    for (int i = 0; i < 4; ++i)
#pragma unroll
        for (int j = 0; j < 4; ++j)
            acc[i][j] = f32x4{0.f, 0.f, 0.f, 0.f};

    for (int part = 0; part < 2; ++part) {
        for (int c = 0; c < 512; c += 32) {
            const short* bp = bp0 + part * 1024 + c;
#pragma unroll
            for (int hh = 0; hh < 4; ++hh) {
                const short* q = bp + (size_t)hh * 64 * 2048;
                gload16(q, &Bab[hh * 2048 + tid * 8]);
                gload16(q + 512, &Bmu[hh * 2048 + tid * 8]);
            }
            uint2 xu = *(const uint2*)(zi + part * 512 + c);
            uint2 yu = *(const uint2*)(zj + part * 512 + c);
            f32x2 x0 = __builtin_amdgcn_cvt_pk_f32_fp8((int)xu.x, false);
            f32x2 x1 = __builtin_amdgcn_cvt_pk_f32_fp8((int)xu.x, true);
            f32x2 x2 = __builtin_amdgcn_cvt_pk_f32_fp8((int)xu.y, false);
            f32x2 x3 = __builtin_amdgcn_cvt_pk_f32_fp8((int)xu.y, true);
            f32x2 y0 = __builtin_amdgcn_cvt_pk_f32_fp8((int)yu.x, false);
            f32x2 y1 = __builtin_amdgcn_cvt_pk_f32_fp8((int)yu.x, true);
            f32x2 y2 = __builtin_amdgcn_cvt_pk_f32_fp8((int)yu.y, false);
            f32x2 y3 = __builtin_amdgcn_cvt_pk_f32_fp8((int)yu.y, true);
            uint4 aa, am;
            aa.x = f2bf2(fabsf(x0.x - y0.x), fabsf(x0.y - y0.y));
            aa.y = f2bf2(fabsf(x1.x - y1.x), fabsf(x1.y - y1.y));
            aa.z = f2bf2(fabsf(x2.x - y2.x), fabsf(x2.y - y2.y));
            aa.w = f2bf2(fabsf(x3.x - y3.x), fabsf(x3.y - y3.y));
            am.x = f2bf2(x0.x * y0.x, x0.y * y0.y);
            am.y = f2bf2(x1.x * y1.x, x1.y * y1.y);
            am.z = f2bf2(x2.x * y2.x, x2.y * y2.y);
            am.w = f2bf2(x3.x * y3.x, x3.y * y3.y);
            *(uint4*)&Aab[tid * 8] = aa;
            *(uint4*)&Amu[tid * 8] = am;
            __syncthreads();
            bf16x8 af[4];
#pragma unroll
            for (int i = 0; i < 4; ++i)
                af[i] = *(const bf16x8*)&Aab[(i * 16 + l16) * 32 + quad * 8];
#pragma unroll
            for (int j = 0; j < 4; ++j) {
                bf16x8 bf = *(const bf16x8*)&Bab[(wc + j * 16 + l16) * 32 + quad * 8];
#pragma unroll
                for (int i = 0; i < 4; ++i)
                    acc[i][j] = __builtin_amdgcn_mfma_f32_16x16x32_bf16(af[i], bf, acc[i][j], 0, 0, 0);
            }
#pragma unroll
            for (int i = 0; i < 4; ++i)
                af[i] = *(const bf16x8*)&Amu[(i * 16 + l16) * 32 + quad * 8];
#pragma unroll
            for (int j = 0; j < 4; ++j) {
                bf16x8 bf = *(const bf16x8*)&Bmu[(wc + j * 16 + l16) * 32 + quad * 8];
#pragma unroll
                for (int i = 0; i < 4; ++i)
                    acc[i][j] = __builtin_amdgcn_mfma_f32_16x16x32_bf16(af[i], bf, acc[i][j], 0, 0, 0);
            }
            __syncthreads();
        }
    }
#pragma unroll
    for (int i = 0; i < 4; ++i) {
#pragma unroll
        for (int rg = 0; rg < 4; ++rg) {
            float partial = 0.f;
#pragma unroll
            for (int j = 0; j < 4; ++j) {
                int cc = col0 + wc + j * 16 + l16;
                partial += gelu1(acc[i][j][rg] + gb1[cc]) * gW2[cc];
            }
            partial += __shfl_xor(partial, 1);
            partial += __shfl_xor(partial, 2);
            partial += __shfl_xor(partial, 4);
            partial += __shfl_xor(partial, 8);
            if (l16 == 0)
                atomicAdd(&rowsum[i * 16 + quad * 4 + rg], partial);
        }
    }
    __syncthreads();
    if (tid < 64 && (row0 + tid) < P)
        atomicAdd(&gpart[row0 + tid], rowsum[tid]);
}

// ---------------- fused per-layer attention: single-pass, fp8 k AND v gather ----------
// qvs bf16 [Nn][1024] (q|s), kv8 fp8 [Nn][1024] (k|v). Per edge: 8B k + 8B v per lane.

__global__ __launch_bounds__(256) void k_attn(const short* __restrict__ qvs,
                                              const unsigned char* __restrict__ kv8,
                                              const int* __restrict__ srcS,
                                              const int* __restrict__ offs,
                                              float* __restrict__ h,
                                              short* __restrict__ h_bf,
                                              const float* __restrict__ lng,
                                              const float* __restrict__ lnb, int Nn) {
    const int tid = threadIdx.x;
    const int lane = tid & 63;
    const int wv = tid >> 6;
    const int n = blockIdx.x * 4 + wv;
    if (n >= Nn) return;
    const int st = offs[n], en = offs[n + 1];
    const size_t chOff = (size_t)lane * 8;

    uint4 qv = *(const uint4*)(qvs + (size_t)n * 1024 + chOff);
    float2 q0 = bfp2(qv.x), q1 = bfp2(qv.y), q2 = bfp2(qv.z), q3 = bfp2(qv.w);
    float acc[8];
#pragma unroll
    for (int i = 0; i < 8; ++i) acc[i] = 0.f;
    float m_l = -3.4e38f, l_l = 0.f;

    for (int e0 = st; e0 < en; e0 += 64) {
        int cnt = min(64, en - e0);
        int myS = (lane < cnt) ? srcS[e0 + lane] : 0;
        for (int ei = 0; ei < cnt; ++ei) {
            int s = __shfl(myS, ei);
            const unsigned char* srow = kv8 + (size_t)s * 1024 + chOff;
            uint2 kq = *(const uint2*)srow;
            uint2 vq = *(const uint2*)(srow + 512);
            f32x2 k0 = __builtin_amdgcn_cvt_pk_f32_fp8((int)kq.x, false);
            f32x2 k1 = __builtin_amdgcn_cvt_pk_f32_fp8((int)kq.x, true);
            f32x2 k2 = __builtin_amdgcn_cvt_pk_f32_fp8((int)kq.y, false);
            f32x2 k3 = __builtin_amdgcn_cvt_pk_f32_fp8((int)kq.y, true);
            float d = q0.x * k0.x + q0.y * k0.y + q1.x * k1.x + q1.y * k1.y +
                      q2.x * k2.x + q2.y * k2.y + q3.x * k3.x + q3.y * k3.y;
            d += __shfl_xor(d, 1);
            d += __shfl_xor(d, 2);
            d += __shfl_xor(d, 4);
            d += __shfl_xor(d, 8);
            float lg = d * 0.08838834764831845f;
            float m_new = fmaxf(m_l, lg);
            float sc = __expf(m_l - m_new);
            float p = __expf(lg - m_new);
            l_l = l_l * sc + p;
            m_l = m_new;
            f32x2 v0 = __builtin_amdgcn_cvt_pk_f32_fp8((int)vq.x, false);
            f32x2 v1 = __builtin_amdgcn_cvt_pk_f32_fp8((int)vq.x, true);
            f32x2 v2 = __builtin_amdgcn_cvt_pk_f32_fp8((int)vq.y, false);
            f32x2 v3 = __builtin_amdgcn_cvt_pk_f32_fp8((int)vq.y, true);
            acc[0] = acc[0] * sc + p * v0.x; acc[1] = acc[1] * sc + p * v0.y;
            acc[2] = acc[2] * sc + p * v1.x; acc[3] = acc[3] * sc + p * v1.y;
            acc[4] = acc[4] * sc + p * v2.x; acc[5] = acc[5] * sc + p * v2.y;
            acc[6] = acc[6] * sc + p * v3.x; acc[7] = acc[7] * sc + p * v3.y;
        }
    }
    float rinv = (en > st) ? 1.0f / l_l : 0.f;
    uint4 su = *(const uint4*)(qvs + (size_t)n * 1024 + 512 + chOff);
    float2 s0 = bfp2(su.x), s1 = bfp2(su.y), s2 = bfp2(su.z), s3 = bfp2(su.w);
    float sv[8] = {s0.x, s0.y, s1.x, s1.y, s2.x, s2.y, s3.x, s3.y};
    const float* hp = h + (size_t)n * 512 + chOff;
    float4 h0 = *(const float4*)hp;
    float4 h1 = *(const float4*)(hp + 4);
    float hv[8] = {h0.x, h0.y, h0.z, h0.w, h1.x, h1.y, h1.z, h1.w};
    float r[8];
    float sum = 0.f, ssq = 0.f;
#pragma unroll
    for (int i = 0; i < 8; ++i) {
        r[i] = hv[i] + gelu1(acc[i] * rinv + sv[i]);
        sum += r[i];
        ssq += r[i] * r[i];
    }
    for (int o = 32; o; o >>= 1) {
        sum += __shfl_xor(sum, o);
        ssq += __shfl_xor(ssq, o);
    }
    float mean = sum * (1.0f / 512.0f);
    float var = ssq * (1.0f / 512.0f) - mean * mean;
    float inv = rsqrtf(var + 1e-5f);
    const float* gp = lng + chOff;
    const float* bp = lnb + chOff;
    float4 g0 = *(const float4*)gp, g1 = *(const float4*)(gp + 4);
    float4 b0 = *(const float4*)bp, b1 = *(const float4*)(bp + 4);
    float ga[8] = {g0.x, g0.y, g0.z, g0.w, g1.x, g1.y, g1.z, g1.w};
    float ba[8] = {b0.x, b0.y, b0.z, b0.w, b1.x, b1.y, b1.z, b1.w};
    float o8[8];
#pragma unroll
    for (int i = 0; i < 8; ++i) o8[i] = (r[i] - mean) * inv * ga[i] + ba[i];
    float* hw = h + (size_t)n * 512 + chOff;
    *(float4*)hw = make_float4(o8[0], o8[1], o8[2], o8[3]);
    *(float4*)(hw + 4) = make_float4(o8[4], o8[5], o8[6], o8[7]);
    uint4 ob;
    ob.x = f2bf2(o8[0], o8[1]);
    ob.y = f2bf2(o8[2], o8[3]);
    ob.z = f2bf2(o8[4], o8[5]);
    ob.w = f2bf2(o8[6], o8[7]);
    *(uint4*)(h_bf + (size_t)n * 512 + chOff) = ob;
}

// ---------------- pair bilinear scores (bf16 z,t) ----------------

__global__ __launch_bounds__(256) void k_pairscore(const short* __restrict__ z,
                                                   const short* __restrict__ t,
                                                   const int* __restrict__ pi,
                                                   const int* __restrict__ pj,
                                                   float* __restrict__ ssyn,
                                                   float* __restrict__ sant, int P) {
    int p = blockIdx.x * 4 + (threadIdx.x >> 6);
    if (p >= P) return;
    int lane = threadIdx.x & 63;
    int i = pi[p], j = pj[p];
    uint4 a = *(const uint4*)(t + (size_t)i * 1024 + lane * 8);
    uint4 b = *(const uint4*)(z + (size_t)j * 1024 + lane * 8);
    float2 a0 = bfp2(a.x), a1 = bfp2(a.y), a2 = bfp2(a.z), a3 = bfp2(a.w);
    float2 b0 = bfp2(b.x), b1 = bfp2(b.y), b2 = bfp2(b.z), b3 = bfp2(b.w);
    float ds = a0.x * b0.x + a0.y * b0.y + a1.x * b1.x + a1.y * b1.y +
               a2.x * b2.x + a2.y * b2.y + a3.x * b3.x + a3.y * b3.y;
    uint4 c = *(const uint4*)(t + (size_t)i * 1024 + 512 + lane * 8);
    uint4 d = *(const uint4*)(z + (size_t)j * 1024 + 512 + lane * 8);
    float2 c0 = bfp2(c.x), c1 = bfp2(c.y), c2 = bfp2(c.z), c3 = bfp2(c.w);
    float2 d0 = bfp2(d.x), d1 = bfp2(d.y), d2 = bfp2(d.z), d3 = bfp2(d.w);
    float da = c0.x * d0.x + c0.y * d0.y + c1.x * d1.x + c1.y * d1.y +
               c2.x * d2.x + c2.y * d2.y + c3.x * d3.x + c3.y * d3.y;
    for (int o = 32; o; o >>= 1) {
        ds += __shfl_xor(ds, o);
        da += __shfl_xor(da, o);
    }
    if (lane == 0) { ssyn[p] = ds; sant[p] = da; }
}

// ---------------- final elementwise combine ----------------

__global__ void k_final(const float* __restrict__ gpart, const float* __restrict__ gb2,
                        const float* __restrict__ ssyn, const float* __restrict__ sant,
                        float* __restrict__ out, int P) {
    int p = blockIdx.x * 256 + threadIdx.x;
    if (p < P) {
        float s = 1.0f / (1.0f + __expf(-(gpart[p] + gb2[0])));
        out[p] = s * sant[p] - (1.0f - s) * ssyn[p];
    }
}

// ---------------- host ----------------

extern "C" void kernel_launch(void* const* d_in, const int* in_sizes, int n_in,
                              void* d_out, int out_size, void* d_ws, size_t ws_size,
                              hipStream_t stream) {
    const float* x = (const float*)d_in[0];
    const int* ei = (const int*)d_in[1];
    const int* pe = (const int*)d_in[2];
    const float* mixer_W = (const float*)d_in[3];
    const float* mixer_b = (const float*)d_in[4];
    const float* Wq = (const float*)d_in[5];
    const float* bq = (const float*)d_in[6];
    const float* Wk = (const float*)d_in[7];
    const float* bk = (const float*)d_in[8];
    const float* Wv = (const float*)d_in[9];
    const float* bv = (const float*)d_in[10];
    const float* Ws = (const float*)d_in[11];
    const float* bs = (const float*)d_in[12];
    const float* ln_g = (const float*)d_in[13];
    const float* ln_b = (const float*)d_in[14];
    const float* syn_W = (const float*)d_in[15];
    const float* syn_b = (const float*)d_in[16];
    const float* ant_W = (const float*)d_in[17];
    const float* ant_b = (const float*)d_in[18];
    const float* W_syn = (const float*)d_in[19];
    const float* W_ant = (const float*)d_in[20];
    const float* gW1 = (const float*)d_in[21];
    const float* gb1 = (const float*)d_in[22];
    const float* gW2 = (const float*)d_in[23];
    const float* gb2 = (const float*)d_in[24];
    float* out = (float*)d_out;

    const int Nn = in_sizes[0] / 768;  // 20000
    const int E = in_sizes[1] / 2;     // 320000
    const int P = in_sizes[2] / 2;     // 100000

    char* w = (char*)d_ws;
    auto alloc = [&](size_t bytes) -> char* {
        char* p = w;
        w += (bytes + 255) & ~(size_t)255;
        return p;
    };
    float* h = (float*)alloc((size_t)Nn * 512 * 4);
    short* h_bf = (short*)alloc((size_t)Nn * 512 * 2);
    // union region U: during layers = qvs [Nn][1024] bf16 (q|s) + kv8 [Nn][1024] fp8 (k|v)
    // after layers = zB [Nn][1024] bf16 | tB [Nn][1024] bf16
    char* U = alloc((size_t)Nn * 2048 * 2);
    short* qvs = (short*)U;
    unsigned char* kv8 = (unsigned char*)(U + (size_t)Nn * 1024 * 2);
    short* zB = (short*)U;
    short* tB = (short*)(U + (size_t)Nn * 1024 * 2);
    unsigned char* z8 = (unsigned char*)alloc((size_t)Nn * 1024);   // fp8 z copy, 20 MB
    float* ssyn = (float*)alloc((size_t)P * 3 * 4);
    float* sant = ssyn + P;
    float* gpart = ssyn + 2 * P;
    int* srcS = (int*)alloc((size_t)E * 4);
    int* hist = (int*)alloc((size_t)Nn * 2 * 4);
    int* cursor = hist + Nn;
    int* offs = (int*)alloc((size_t)(Nn + 1) * 4);
    short* mixWt = (short*)alloc((size_t)512 * 768 * 2);
    short* wcat = (short*)alloc((size_t)L_LAYERS * 2048 * 512 * 2);
    short* dualWt = (short*)alloc((size_t)1024 * 512 * 2);
    short* bilWt = (short*)alloc((size_t)1024 * 512 * 2);
    short* gw1t = (short*)alloc((size_t)512 * 2048 * 2);
    float* bcat = (float*)alloc((size_t)L_LAYERS * 2048 * 4);
    float* bdual = (float*)alloc((size_t)1024 * 4);

    k_zero<<<(2 * Nn + 255) / 256, 256, 0, stream>>>(hist, 2 * Nn);
    k_hist<<<(E + 255) / 256, 256, 0, stream>>>(ei + E, hist, E);
    k_scan<<<1, 1024, 0, stream>>>(hist, offs, Nn);
    k_scatter<<<(E + 255) / 256, 256, 0, stream>>>(ei, ei + E, offs, cursor, srcS, E);

    k_wcat<<<(L_LAYERS * 2048 * 512) / 256, 256, 0, stream>>>(Wq, Wk, Wv, Ws, wcat);
    k_tr<<<dim3(3, 512), 256, 0, stream>>>(mixer_W, mixWt, 768, 512);
    k_tr<<<dim3(2, 512), 256, 0, stream>>>(syn_W, dualWt, 512, 512);
    k_tr<<<dim3(2, 512), 256, 0, stream>>>(ant_W, dualWt + 512 * 512, 512, 512);
    k_tr<<<dim3(2, 512), 256, 0, stream>>>(W_syn, bilWt, 512, 512);
    k_tr<<<dim3(2, 512), 256, 0, stream>>>(W_ant, bilWt + 512 * 512, 512, 512);
    k_tr<<<dim3(8, 512), 256, 0, stream>>>(gW1, gw1t, 2048, 512);
    k_bcat<<<48, 256, 0, stream>>>(bq, bk, bv, bs, bcat);
    k_bdual<<<4, 256, 0, stream>>>(syn_b, ant_b, bdual);

    const int mtiles = (Nn + 127) / 128;  // 157
    gemm_a32<<<dim3(mtiles, 4), 256, 0, stream>>>(x, 768, mixWt, mixer_b, h, h_bf, 512,
                                                  Nn, 512, 768, 1);

    // XCD-swizzled 1D grid: ceil(mtiles/8)*8 row slots x 16 col tiles
    const int qk_grid = ((mtiles + 7) / 8) * 8 * 16;   // 2560
    for (int l = 0; l < L_LAYERS; ++l) {
        gemm_qkvs<<<qk_grid, 256, 0, stream>>>(h_bf, wcat + (size_t)l * 2048 * 512,
                                               bcat + l * 2048, qvs, kv8, Nn, mtiles);
        k_attn<<<(Nn + 3) / 4, 256, 0, stream>>>(qvs, kv8, srcS, offs, h, h_bf,
                                                 ln_g + l * 512, ln_b + l * 512, Nn);
    }

    // z = gelu(h @ [syn_W|ant_W] + b) -> zB bf16 + z8 fp8
    gemm_bb<<<dim3(mtiles, 8), 256, 0, stream>>>(h_bf, 512, dualWt, bdual, zB, z8, 1024,
                                                 Nn, 1024, 512, 1);
    gemm_bb<<<dim3(mtiles, 4), 256, 0, stream>>>(zB, 1024, bilWt, nullptr, tB, nullptr, 1024,
                                                 Nn, 512, 512, 0);
    gemm_bb<<<dim3(mtiles, 4), 256, 0, stream>>>(zB + 512, 1024, bilWt + 512 * 512, nullptr,
                                                 tB + 512, nullptr, 1024, Nn, 512, 512, 0);

    k_pairscore<<<(P + 3) / 4, 256, 0, stream>>>(zB, tB, pe, pe + P, ssyn, sant, P);

    k_zero<<<(P + 255) / 256, 256, 0, stream>>>((int*)gpart, P);
    const int ptiles = (P + 63) / 64;                  // 1563
    const int gate_grid = ((ptiles + 7) / 8) * 8 * 2;  // 3136
    gemm_gate<<<gate_grid, 256, 0, stream>>>(z8, pe, pe + P, P,
                                             gw1t, gb1, gW2, gpart, ptiles);
    k_final<<<(P + 255) / 256, 256, 0, stream>>>(gpart, gb2, ssyn, sant, out, P);
}